// Round 14
// baseline (566.176 us; speedup 1.0000x reference)
//
#include <hip/hip_runtime.h>
#include <math.h>

#define S_ 16
#define M_ 256
#define NF_ 4096
#define OUT_ 256
#define ROWS_ (M_ + NF_)     // 4352
#define JITTER_ 1e-8f
#define MM_ (M_ * M_)        // 65536
#define BVS_ 131072          // 512*256 per-matrix stride in BV

typedef unsigned short u16;
typedef __attribute__((ext_vector_type(8))) short bf16x8;
typedef __attribute__((ext_vector_type(4))) float f32x4;

__device__ inline void cvt2(float x, u16& h, u16& l) {
    unsigned xb = __float_as_uint(x);
    unsigned hb = (xb + 0x7fffu + ((xb >> 16) & 1u)) >> 16;
    float fh = __uint_as_float(hb << 16);
    float rr = x - fh;
    unsigned rb = __float_as_uint(rr);
    unsigned lb = (rb + 0x7fffu + ((rb >> 16) & 1u)) >> 16;
    h = (u16)hb; l = (u16)lb;
}

// ---------------- small prep kernels ----------------

__global__ void max1_kernel(const float* __restrict__ x, int n, float* part) {
    __shared__ float red[256];
    int tid = threadIdx.x;
    float m = -3.4e38f;
    for (int i = blockIdx.x * blockDim.x + tid; i < n; i += gridDim.x * blockDim.x)
        m = fmaxf(m, x[i]);
    red[tid] = m; __syncthreads();
    for (int s = 128; s > 0; s >>= 1) {
        if (tid < s) red[tid] = fmaxf(red[tid], red[tid + s]);
        __syncthreads();
    }
    if (tid == 0) part[blockIdx.x] = red[0];
}

__global__ void max2_kernel(const float* part, float* ws) {
    __shared__ float red[256];
    int tid = threadIdx.x;
    red[tid] = part[tid]; __syncthreads();
    for (int s = 128; s > 0; s >>= 1) {
        if (tid < s) red[tid] = fmaxf(red[tid], red[tid + s]);
        __syncthreads();
    }
    if (tid == 0) { ws[0] = red[0]; ws[2] = JITTER_ * red[0]; }
}

__global__ void prep_kernel(const float* __restrict__ Lloc, const float* __restrict__ Lscale, float* ws) {
    __shared__ float red[256];
    int tid = threadIdx.x;
    red[tid] = Lloc[tid * M_ + tid];
    __syncthreads();
    for (int s = 128; s > 0; s >>= 1) {
        if (tid < s) red[tid] += red[tid + s];
        __syncthreads();
    }
    if (tid == 0) {
        float norm = red[0] / (float)M_;
        ws[1] = expf(Lscale[0]) / norm;
    }
}

// ---- plain split ----
__global__ void psplit_kernel(const float* __restrict__ src, u16* __restrict__ h,
                              u16* __restrict__ l, long n, const float* scaleptr) {
    float sc = scaleptr ? scaleptr[0] : 1.0f;
    long stride = (long)gridDim.x * blockDim.x * 4;
    for (long i = ((long)blockIdx.x * blockDim.x + threadIdx.x) * 4; i < n; i += stride) {
        float4 v = *(const float4*)(src + i);
        u16 h0,h1,h2,h3,l0,l1,l2,l3;
        cvt2(v.x*sc,h0,l0); cvt2(v.y*sc,h1,l1); cvt2(v.z*sc,h2,l2); cvt2(v.w*sc,h3,l3);
        ushort4 hv = {h0,h1,h2,h3}, lv = {l0,l1,l2,l3};
        *(ushort4*)(h + i) = hv;
        *(ushort4*)(l + i) = lv;
    }
}

// ---- fused Kuu split + jittered copy for Cholesky ----
__global__ void splitjit_kernel(const float* __restrict__ Kuu, const float* __restrict__ ws,
                                u16* __restrict__ h, u16* __restrict__ l,
                                float* __restrict__ dst) {
    float jit = ws[2];
    long i = ((long)blockIdx.x * blockDim.x + threadIdx.x) * 4;
    if (i < (long)S_ * MM_) {
        float4 v = *(const float4*)(Kuu + i);
        u16 h0,h1,h2,h3,l0,l1,l2,l3;
        cvt2(v.x,h0,l0); cvt2(v.y,h1,l1); cvt2(v.z,h2,l2); cvt2(v.w,h3,l3);
        ushort4 hv = {h0,h1,h2,h3}, lv = {l0,l1,l2,l3};
        *(ushort4*)(h + i) = hv;
        *(ushort4*)(l + i) = lv;
        int rc = (int)(i & 65535);
        int r = rc >> 8, c0 = rc & 255;
        if (r >= c0 && r < c0 + 4) ((float*)&v)[r - c0] += jit;
        *(float4*)(dst + i) = v;
    }
}

// ---- transpose split ----
__global__ void tsplit_kernel(const float* __restrict__ src, int ldS, long sS,
                              u16* __restrict__ h, u16* __restrict__ l, int ldD, long sD,
                              const float* scaleptr) {
    int b = blockIdx.z;
    src += (long)b * sS; h += (long)b * sD; l += (long)b * sD;
    __shared__ float T[32][33];
    int r0 = blockIdx.y * 32, c0 = blockIdx.x * 32;
    float sc = scaleptr ? scaleptr[0] : 1.0f;
    int tid = threadIdx.x;
    int lrow = tid >> 3, lc4 = (tid & 7) * 4;
    float4 v = *(const float4*)(src + (long)(r0 + lrow) * ldS + c0 + lc4);
    T[lrow][lc4 + 0] = v.x * sc; T[lrow][lc4 + 1] = v.y * sc;
    T[lrow][lc4 + 2] = v.z * sc; T[lrow][lc4 + 3] = v.w * sc;
    __syncthreads();
    int wcol = tid >> 3, wr4 = (tid & 7) * 4;
    u16 h0,h1,h2,h3,l0,l1,l2,l3;
    cvt2(T[wr4+0][wcol],h0,l0); cvt2(T[wr4+1][wcol],h1,l1);
    cvt2(T[wr4+2][wcol],h2,l2); cvt2(T[wr4+3][wcol],h3,l3);
    ushort4 hv = {h0,h1,h2,h3}, lv = {l0,l1,l2,l3};
    *(ushort4*)(h + (long)(c0 + wcol) * ldD + r0 + wr4) = hv;
    *(ushort4*)(l + (long)(c0 + wcol) * ldD + r0 + wr4) = lv;
}

// ---- fp32 transpose ----
__global__ void utrans_kernel(const float* __restrict__ src, int ldS, long sS,
                              float* __restrict__ dst, int ldD, long sD) {
    int b = blockIdx.z;
    src += (long)b * sS; dst += (long)b * sD;
    __shared__ float T[32][33];
    int r0 = blockIdx.y * 32, c0 = blockIdx.x * 32;
    int tid = threadIdx.x;
    int lrow = tid >> 3, lc4 = (tid & 7) * 4;
    float4 v = *(const float4*)(src + (long)(r0 + lrow) * ldS + c0 + lc4);
    T[lrow][lc4+0]=v.x; T[lrow][lc4+1]=v.y; T[lrow][lc4+2]=v.z; T[lrow][lc4+3]=v.w;
    __syncthreads();
    int wcol = tid >> 3, wr4 = (tid & 7) * 4;
    float4 o;
    o.x = T[wr4+0][wcol]; o.y = T[wr4+1][wcol]; o.z = T[wr4+2][wcol]; o.w = T[wr4+3][wcol];
    *(float4*)(dst + (long)(c0 + wcol) * ldD + r0 + wr4) = o;
}

// ---------------- batched blocked Cholesky (BK=16, 1024 threads, monolithic) ----------------

__global__ __launch_bounds__(1024) void chol_kernel(float* bufA, float* bufB) {
    int blk = blockIdx.x;                       // 0..31
    float* Ag = (blk < S_) ? (bufA + (long)blk * MM_) : (bufB + (long)(blk - S_) * MM_);
    __shared__ float P[33280];
    __shared__ float pan2[256 * 20];
    __shared__ float piv[16][18];
    float4* P4 = (float4*)P;
    int tid = threadIdx.x;
    int r = tid >> 2, s = tid & 3;
    int lane = tid & 63, wid = tid >> 6;
    int mg = r >> 2, tg = r & 3;
    int b4 = (mg + 1) * (2 * mg + tg);

    for (int i = wid; i < M_; i += 16) {
        int m = i >> 2, t4 = i & 3;
        int rb4 = (m + 1) * (2 * m + t4);
        if (lane <= m) P4[rb4 + lane] = ((const float4*)Ag)[i * 64 + lane];
    }
    __syncthreads();

    float preg[16];
    for (int p = 0; p < 16; p++) {
        int k0 = p << 4;
        int c0 = p << 2;
        #pragma unroll
        for (int rr = 0; rr < 4; rr++) {
            float4 v = make_float4(0.f, 0.f, 0.f, 0.f);
            if (r >= k0 && c0 + rr <= mg) v = P4[b4 + c0 + rr];
            preg[4 * rr + 0] = v.x; preg[4 * rr + 1] = v.y;
            preg[4 * rr + 2] = v.z; preg[4 * rr + 3] = v.w;
        }
        if (wid == p) {
            int dj = lane >> 2;
            float myinv = 0.f;
            #pragma unroll
            for (int j = 0; j < 16; j++) {
                float app = __shfl(preg[j], 4 * j, 64);
                float d = sqrtf(app);
                float inv = 1.0f / d;
                if (dj == j) { preg[j] = d; myinv = inv; }
                else if (dj > j) preg[j] *= inv;
                #pragma unroll
                for (int j2 = j + 1; j2 < 16; j2++) {
                    float Lj2 = __shfl(preg[j], 4 * j2, 64);
                    if (dj >= j2) preg[j2] -= preg[j] * Lj2;
                }
            }
            if (s == 0) {
                #pragma unroll
                for (int i = 0; i < 16; i++) piv[dj][i] = preg[i];
                piv[dj][16] = myinv;
            }
        }
        __syncthreads();
        if (r > k0 + 15) {
            float x[16];
            #pragma unroll
            for (int j = 0; j < 16; j++) {
                float acc = preg[j];
                #pragma unroll
                for (int i = 0; i < 16; i++)
                    if (i < j) acc -= x[i] * piv[j][i];
                x[j] = acc * piv[j][16];
            }
            #pragma unroll
            for (int j = 0; j < 16; j++) preg[j] = x[j];
        }
        if (r >= k0) {
            float4 pv = make_float4(preg[4 * s], preg[4 * s + 1],
                                    preg[4 * s + 2], preg[4 * s + 3]);
            *(float4*)&pan2[r * 20 + 4 * s] = pv;
            int c = c0 + s;
            if (c <= mg) P4[b4 + c] = pv;
        }
        __syncthreads();
        {
            int cs = tid >> 4;
            int j  = tid & 15;
            if (cs >= c0 + 4) {
                float4 q0[4], q1[4], q2[4], q3[4];
                #pragma unroll
                for (int e = 0; e < 4; e++) {
                    const float4* pr = (const float4*)&pan2[(4 * cs + e) * 20];
                    q0[e] = pr[0]; q1[e] = pr[1]; q2[e] = pr[2]; q3[e] = pr[3];
                }
                int rr = k0 + 16 + j;
                int rmin = 4 * cs;
                while (rr < rmin) rr += 16;
                for (; rr < 256; rr += 16) {
                    int mgr = rr >> 2, tgr = rr & 3;
                    int rb4 = (mgr + 1) * (2 * mgr + tgr);
                    const float4* ar = (const float4*)&pan2[rr * 20];
                    float4 a0 = ar[0], a1 = ar[1], a2 = ar[2], a3 = ar[3];
                    float rv[4];
                    *(float4*)rv = P4[rb4 + cs];
                    #pragma unroll
                    for (int e = 0; e < 4; e++) {
                        float acc;
                        acc  = a0.x*q0[e].x + a0.y*q0[e].y + a0.z*q0[e].z + a0.w*q0[e].w;
                        acc += a1.x*q1[e].x + a1.y*q1[e].y + a1.z*q1[e].z + a1.w*q1[e].w;
                        acc += a2.x*q2[e].x + a2.y*q2[e].y + a2.z*q2[e].z + a2.w*q2[e].w;
                        acc += a3.x*q3[e].x + a3.y*q3[e].y + a3.z*q3[e].z + a3.w*q3[e].w;
                        rv[e] -= acc;
                    }
                    P4[rb4 + cs] = *(float4*)rv;
                }
            }
        }
        __syncthreads();
    }

    for (int i = wid; i < M_; i += 16) {
        int m = i >> 2, t4 = i & 3;
        int rb4 = (m + 1) * (2 * m + t4);
        if (lane <= m) ((float4*)Ag)[i * 64 + lane] = P4[rb4 + lane];
    }
}

// ---------------- 64x64 diagonal-block triangular inverse ----------------
// Writes D pair (row-major), diag of Tt pair (transposed), diag of TKr into BV
// rows 0..255 (stride BVS_ per matrix).

__global__ __launch_bounds__(256) void tri64inv_kernel(const float* W0,
                                                       u16* invh, u16* invl,
                                                       u16* Tth, u16* Ttl,
                                                       u16* BVh, u16* BVl) {
    int p = blockIdx.x;        // 0..3
    int mat = blockIdx.y;      // 0..31
    const float* W = W0 + (long)mat * MM_;
    int d0 = p * 64;
    __shared__ float X[64 * 65];
    __shared__ float pan[64 * 20];
    int tid = threadIdx.x;
    int c = tid & 63, q = tid >> 6;
    for (int idx = tid; idx < 64 * 65; idx += 256) X[idx] = 0.f;
    __syncthreads();
    if (q == 0) X[c * 65 + c] = 1.0f;
    for (int pp = 0; pp < 4; pp++) {
        int t0 = pp << 4;
        for (int idx = tid; idx < 64 * 4; idx += 256) {
            int k = idx >> 2, e = idx & 3;
            if (k >= t0)
                ((float4*)(pan + k * 20))[e] =
                    *(const float4*)(W + (long)(d0 + k) * 256 + d0 + t0 + 4 * e);
        }
        __syncthreads();
        if (q == pp) {
            float xr[16];
            #pragma unroll
            for (int j = 0; j < 16; j++) {
                float xv = X[(t0 + j) * 65 + c];
                #pragma unroll
                for (int i = 0; i < 16; i++)
                    if (i < j) xv -= pan[(t0 + j) * 20 + i] * xr[i];
                xv *= (1.0f / pan[(t0 + j) * 20 + j]);
                xr[j] = xv;
                X[(t0 + j) * 65 + c] = xv;
            }
        }
        __syncthreads();
        int kbeg = q << 4; if (kbeg < t0 + 16) kbeg = t0 + 16;
        int kend = (q << 4) + 16;
        if (kbeg < kend) {
            float xr[16];
            #pragma unroll
            for (int j = 0; j < 16; j++) xr[j] = X[(t0 + j) * 65 + c];
            for (int kk = kbeg; kk < kend; kk++) {
                float rv = X[kk * 65 + c];
                const float4* pr = (const float4*)&pan[kk * 20];
                float4 a = pr[0], b = pr[1], d = pr[2], e = pr[3];
                rv -= a.x * xr[0] + a.y * xr[1] + a.z * xr[2] + a.w * xr[3];
                rv -= b.x * xr[4] + b.y * xr[5] + b.z * xr[6] + b.w * xr[7];
                rv -= d.x * xr[8] + d.y * xr[9] + d.z * xr[10] + d.w * xr[11];
                rv -= e.x * xr[12] + e.y * xr[13] + e.z * xr[14] + e.w * xr[15];
                X[kk * 65 + c] = rv;
            }
        }
        __syncthreads();
    }
    for (int idx = tid; idx < 4096; idx += 256) {
        int r = idx >> 6, k = idx & 63;
        u16 h, l; cvt2(X[r * 65 + k], h, l);
        long io = (long)mat * 16384 + (long)p * 4096 + idx;
        invh[io] = h; invl[io] = l;
        long ro = (long)mat * BVS_ + (long)(d0 + r) * 256 + d0 + k;
        BVh[ro] = h; BVl[ro] = l;
        long to = (long)mat * MM_ + (long)(d0 + k) * 256 + d0 + r;
        Tth[to] = h; Ttl[to] = l;
    }
}

// ---- pair-split strictly-lower panels of cholK into Lfull [256][256] pair ----
__global__ void lsplit_kernel(const float* __restrict__ W0,
                              u16* __restrict__ Lh, u16* __restrict__ Ll) {
    int p = blockIdx.x;        // 0..2
    int mat = blockIdx.y;      // 0..31
    const float* W = W0 + (long)mat * MM_;
    u16* dh = Lh + (long)mat * MM_;
    u16* dl = Ll + (long)mat * MM_;
    int d0 = 64 * p, nrows = 192 - d0;
    for (int idx = threadIdx.x; idx < nrows * 16; idx += 256) {
        int r = idx >> 4, c4 = idx & 15;
        long o = (long)(d0 + 64 + r) * 256 + d0 + 4 * c4;
        float4 v = *(const float4*)(W + o);
        u16 h0,h1,h2,h3,l0,l1,l2,l3;
        cvt2(v.x,h0,l0); cvt2(v.y,h1,l1); cvt2(v.z,h2,l2); cvt2(v.w,h3,l3);
        ushort4 hv = {h0,h1,h2,h3}, lv = {l0,l1,l2,l3};
        *(ushort4*)(dh + o) = hv;
        *(ushort4*)(dl + o) = lv;
    }
}

// ---------------- pair GEMM params ----------------

struct PG {
    const u16 *Ah, *Al, *Bh, *Bl;
    float* C; u16 *Ch, *Cl, *ChT, *ClT;
    const float* D;
    int M, N, K, lda, ldb, ldc, ldct, ldp;
    long sA, sB, sC, sP, sCt, sD;
    float alpha, dcoef;
};

// 64x64 tile, 4 waves, runtime K (multiple of 32)
template<int OF, int OP, int OPT, int ACCf, int Df, int ADDIf>
__global__ __launch_bounds__(256) void pgemm64_k(PG p) {
    int bz = blockIdx.z;
    const u16* Agh = p.Ah + (long)bz * p.sA;
    const u16* Agl = p.Al + (long)bz * p.sA;
    const u16* Bgh = p.Bh + (long)bz * p.sB;
    const u16* Bgl = p.Bl + (long)bz * p.sB;
    int bm = blockIdx.y * 64, bn = blockIdx.x * 64;
    __shared__ __align__(16) u16 sAh[64][40];
    __shared__ __align__(16) u16 sAl[64][40];
    __shared__ __align__(16) u16 sBh[64][40];
    __shared__ __align__(16) u16 sBl[64][40];
    int tid = threadIdx.x, lane = tid & 63, wid = tid >> 6;
    int wm = (wid >> 1) * 32, wn = (wid & 1) * 32;
    int fr = lane & 15, ko = (lane >> 4) * 8;
    int kb = tid & 3, rw = tid >> 2;
    f32x4 acc[2][2];
    #pragma unroll
    for (int m = 0; m < 2; m++)
        #pragma unroll
        for (int n = 0; n < 2; n++)
            acc[m][n] = (f32x4){0.f, 0.f, 0.f, 0.f};

    for (int k0 = 0; k0 < p.K; k0 += 32) {
        *(bf16x8*)&sAh[rw][kb * 8] = *(const bf16x8*)(Agh + (long)(bm + rw) * p.lda + k0 + kb * 8);
        *(bf16x8*)&sAl[rw][kb * 8] = *(const bf16x8*)(Agl + (long)(bm + rw) * p.lda + k0 + kb * 8);
        *(bf16x8*)&sBh[rw][kb * 8] = *(const bf16x8*)(Bgh + (long)(bn + rw) * p.ldb + k0 + kb * 8);
        *(bf16x8*)&sBl[rw][kb * 8] = *(const bf16x8*)(Bgl + (long)(bn + rw) * p.ldb + k0 + kb * 8);
        __syncthreads();
        bf16x8 ah[2], al[2], bh[2], bl[2];
        #pragma unroll
        for (int m = 0; m < 2; m++) {
            ah[m] = *(const bf16x8*)&sAh[wm + m * 16 + fr][ko];
            al[m] = *(const bf16x8*)&sAl[wm + m * 16 + fr][ko];
        }
        #pragma unroll
        for (int n = 0; n < 2; n++) {
            bh[n] = *(const bf16x8*)&sBh[wn + n * 16 + fr][ko];
            bl[n] = *(const bf16x8*)&sBl[wn + n * 16 + fr][ko];
        }
        #pragma unroll
        for (int m = 0; m < 2; m++)
            #pragma unroll
            for (int n = 0; n < 2; n++) {
                acc[m][n] = __builtin_amdgcn_mfma_f32_16x16x32_bf16(ah[m], bh[n], acc[m][n], 0, 0, 0);
                acc[m][n] = __builtin_amdgcn_mfma_f32_16x16x32_bf16(ah[m], bl[n], acc[m][n], 0, 0, 0);
                acc[m][n] = __builtin_amdgcn_mfma_f32_16x16x32_bf16(al[m], bh[n], acc[m][n], 0, 0, 0);
            }
        __syncthreads();
    }

    int rq = (lane >> 4) * 4;
    #pragma unroll
    for (int m = 0; m < 2; m++) {
        int row0 = bm + wm + m * 16 + rq;
        #pragma unroll
        for (int n = 0; n < 2; n++) {
            int col = bn + wn + n * 16 + fr;
            float v[4];
            #pragma unroll
            for (int i = 0; i < 4; i++) {
                int r = row0 + i;
                float val = p.alpha * acc[m][n][i];
                if (Df)   val += p.dcoef * p.D[(long)bz * p.sD + (long)r * p.ldc + col];
                if (ACCf) val += p.C[(long)bz * p.sC + (long)r * p.ldc + col];
                if (ADDIf && r == col) val += 1.0f;
                v[i] = val;
            }
            if (OF) {
                #pragma unroll
                for (int i = 0; i < 4; i++)
                    p.C[(long)bz * p.sC + (long)(row0 + i) * p.ldc + col] = v[i];
            }
            if (OP) {
                #pragma unroll
                for (int i = 0; i < 4; i++) {
                    u16 h, l; cvt2(v[i], h, l);
                    p.Ch[(long)bz * p.sP + (long)(row0 + i) * p.ldp + col] = h;
                    p.Cl[(long)bz * p.sP + (long)(row0 + i) * p.ldp + col] = l;
                }
            }
            if (OPT) {
                u16 h0,h1,h2,h3,l0,l1,l2,l3;
                cvt2(v[0],h0,l0); cvt2(v[1],h1,l1); cvt2(v[2],h2,l2); cvt2(v[3],h3,l3);
                ushort4 hv = {h0,h1,h2,h3}, lv = {l0,l1,l2,l3};
                *(ushort4*)&p.ChT[(long)bz * p.sCt + (long)col * p.ldct + row0] = hv;
                *(ushort4*)&p.ClT[(long)bz * p.sCt + (long)col * p.ldct + row0] = lv;
            }
        }
    }
}

// ---------------- fused Vf+Ef kernel ----------------
// out512 = KufT_tile(64 x K=256) @ BV^T, BV = [TKr(256); G3T(256)] pair.
// Cols 0..255 (waves 0-3): H, squared-rowsummed into LDS (Vf). Cols 256..511
// (waves 4-7): Ef; epilogue adds sqrt(Kff - Vf)*noise and writes out.

struct VE {
    const u16 *Ah, *Al, *Bh, *Bl;
    const float *kff, *noise;
    float* C;
    long sA, sB, sVf, sNoise, sC;
};

__global__ __launch_bounds__(512) void vfef_kernel(VE p) {
    int bz = blockIdx.z;
    const u16* Agh = p.Ah + (long)bz * p.sA;
    const u16* Agl = p.Al + (long)bz * p.sA;
    const u16* Bgh = p.Bh + (long)bz * p.sB;
    const u16* Bgl = p.Bl + (long)bz * p.sB;
    int bm = blockIdx.y * 64;
    __shared__ __align__(16) u16 sAh[64][40];
    __shared__ __align__(16) u16 sAl[64][40];
    __shared__ __align__(16) u16 sBh[512][40];
    __shared__ __align__(16) u16 sBl[512][40];
    __shared__ float rs[64];
    int tid = threadIdx.x, lane = tid & 63, wid = tid >> 6;   // 8 waves
    int wn = wid * 64;
    int fr = lane & 15, ko = (lane >> 4) * 8;
    int kb = tid & 3, rw = tid >> 2;   // rw 0..127
    if (tid < 64) rs[tid] = 0.f;
    f32x4 acc[4][4];
    #pragma unroll
    for (int m = 0; m < 4; m++)
        #pragma unroll
        for (int n = 0; n < 4; n++)
            acc[m][n] = (f32x4){0.f, 0.f, 0.f, 0.f};

    for (int k0 = 0; k0 < 256; k0 += 32) {
        if (tid < 256) {
            *(bf16x8*)&sAh[rw][kb * 8] = *(const bf16x8*)(Agh + (long)(bm + rw) * 256 + k0 + kb * 8);
            *(bf16x8*)&sAl[rw][kb * 8] = *(const bf16x8*)(Agl + (long)(bm + rw) * 256 + k0 + kb * 8);
        }
        #pragma unroll
        for (int t = 0; t < 4; t++) {
            *(bf16x8*)&sBh[rw + 128 * t][kb * 8] = *(const bf16x8*)(Bgh + (long)(rw + 128 * t) * 256 + k0 + kb * 8);
            *(bf16x8*)&sBl[rw + 128 * t][kb * 8] = *(const bf16x8*)(Bgl + (long)(rw + 128 * t) * 256 + k0 + kb * 8);
        }
        __syncthreads();
        bf16x8 ah[4], al[4], bh[4], bl[4];
        #pragma unroll
        for (int m = 0; m < 4; m++) {
            ah[m] = *(const bf16x8*)&sAh[m * 16 + fr][ko];
            al[m] = *(const bf16x8*)&sAl[m * 16 + fr][ko];
        }
        #pragma unroll
        for (int n = 0; n < 4; n++) {
            bh[n] = *(const bf16x8*)&sBh[wn + n * 16 + fr][ko];
            bl[n] = *(const bf16x8*)&sBl[wn + n * 16 + fr][ko];
        }
        #pragma unroll
        for (int m = 0; m < 4; m++)
            #pragma unroll
            for (int n = 0; n < 4; n++) {
                acc[m][n] = __builtin_amdgcn_mfma_f32_16x16x32_bf16(ah[m], bh[n], acc[m][n], 0, 0, 0);
                acc[m][n] = __builtin_amdgcn_mfma_f32_16x16x32_bf16(ah[m], bl[n], acc[m][n], 0, 0, 0);
                acc[m][n] = __builtin_amdgcn_mfma_f32_16x16x32_bf16(al[m], bh[n], acc[m][n], 0, 0, 0);
            }
        __syncthreads();
    }

    int rq = (lane >> 4) * 4;
    if (wid < 4) {
        // H half: Vf row-sums of squares
        #pragma unroll
        for (int m = 0; m < 4; m++) {
            #pragma unroll
            for (int i = 0; i < 4; i++) {
                float t = 0.f;
                #pragma unroll
                for (int n = 0; n < 4; n++) {
                    float v = acc[m][n][i];
                    t += v * v;
                }
                t += __shfl_xor(t, 1); t += __shfl_xor(t, 2);
                t += __shfl_xor(t, 4); t += __shfl_xor(t, 8);
                if (fr == 0) atomicAdd(&rs[m * 16 + rq + i], t);
            }
        }
    }
    __syncthreads();
    if (wid >= 4) {
        #pragma unroll
        for (int m = 0; m < 4; m++) {
            #pragma unroll
            for (int n = 0; n < 4; n++) {
                int col = wn - 256 + n * 16 + fr;
                #pragma unroll
                for (int i = 0; i < 4; i++) {
                    int rL = m * 16 + rq + i;
                    int rG = bm + rL;
                    float val = acc[m][n][i];
                    float kf = p.kff[(long)bz * p.sVf + rG];
                    val += sqrtf(fmaxf(kf - rs[rL], 0.f)) *
                           p.noise[(long)bz * p.sNoise + (long)rG * 256 + col];
                    p.C[(long)bz * p.sC + (long)rG * 256 + col] = val;
                }
            }
        }
    }
}

// ---------------- host ----------------

extern "C" void kernel_launch(void* const* d_in, const int* in_sizes, int n_in,
                              void* d_out, int out_size, void* d_ws, size_t ws_size,
                              hipStream_t stream) {
    const float* Kuu       = (const float*)d_in[0];
    const float* Kuf       = (const float*)d_in[1];
    const float* Kff       = (const float*)d_in[2];
    const float* Lloc      = (const float*)d_in[3];
    const float* Lscale    = (const float*)d_in[4];
    const float* u_param   = (const float*)d_in[5];
    const float* noise_inv = (const float*)d_in[6];
    const float* noise_L   = (const float*)d_in[7];
    const float* noise_f   = (const float*)d_in[8];
    float* out = (float*)d_out;
    float* ws  = (float*)d_ws;

    const long BIG = (long)S_ * MM_;     // 1,048,576 elements
    long off = 1024;
    float* part = ws + 16;

    #define PAIR(NAME, E) u16* NAME##h = (u16*)(ws + off); u16* NAME##l = NAME##h + (E); off += (E);
    PAIR(LS, 65536)
    PAIR(LtS, 65536)
    PAIR(upS, 65536)
    PAIR(W1S, 65536)
    float* UPT   = ws + off; off += 65536;
    PAIR(KuuS, BIG)
    PAIR(ninvS, BIG)
    PAIR(nLS, BIG)
    float* cholK = ws + off; off += 2 * BIG;   // 32 matrices contiguous
    float* choll = cholK + BIG;
    PAIR(KuuLS, BIG)
    PAIR(KuuLtS, BIG)
    PAIR(TtS, 2 * BIG)             // T^T pair, 32 matrices
    PAIR(BV, 4 * BIG)              // [TKr; G3T] 512x256 pair, 32 matrices
    PAIR(lKlS, BIG)
    PAIR(invS, 524288)             // 32 mats x 4 panels x 64x64 D pair
    PAIR(LfS, 2 * BIG)             // L strictly-lower pair -> later KuuInv pair
    PAIR(StTS, 393216)             // S^T scratch pair, 32 x 192x64
    #undef PAIR

    u16* TKth = TtSh;                u16* TKtl = TtSl;
    u16* Tlth = TtSh + (long)S_ * MM_; u16* Tltl = TtSl + (long)S_ * MM_;
    u16* RHSTh   = KuuSh;            u16* RHSTl   = KuuSl;
    u16* UTph    = nLSh;             u16* UTpl    = nLSl;
    float* RHS1T = (float*)KuuLSh;
    u16* Sigmah  = KuuLtSh;          u16* Sigmal  = KuuLtSl;
    u16* lKlh    = lKlSh;            u16* lKll    = lKlSl;
    float* UTf32 = (float*)TtSh;     // Tt region free after i/c2
    u16* Stmph   = Tlth;             u16* Stmpl   = Tltl;
    u16* KuuInvh = LfSh;             u16* KuuInvl = LfSl;   // alias after trinv loop

    long navail = (long)(ws_size / 4) - off;
    long nfc_l = navail / 4096;                 // only KufT pair per chunk
    int nfc = (int)((nfc_l / 128) * 128);
    if (nfc > NF_) nfc = NF_;
    if (nfc < 128) nfc = 128;
    long Ec = (long)S_ * nfc * 256;
    u16* KufTch = (u16*)(ws + off);      u16* KufTcl = KufTch + Ec;

    dim3 b256(256);

    hipMemsetAsync(TtSh, 0, (size_t)4 * 2 * BIG, stream);
    hipMemsetAsync(BVh, 0, (size_t)4 * 4 * BIG, stream);

    max1_kernel<<<256, b256, 0, stream>>>(Kuu, S_ * MM_, part);
    max2_kernel<<<1, b256, 0, stream>>>(part, ws);
    prep_kernel<<<1, b256, 0, stream>>>(Lloc, Lscale, ws);

    splitjit_kernel<<<1024, b256, 0, stream>>>(Kuu, ws, KuuSh, KuuSl, cholK);
    psplit_kernel<<<64, b256, 0, stream>>>(Lloc, LSh, LSl, 65536, ws + 1);
    tsplit_kernel<<<dim3(8, 8, 1), b256, 0, stream>>>(Lloc, 256, 0, LtSh, LtSl, 256, 0, ws + 1);
    psplit_kernel<<<64, b256, 0, stream>>>(u_param, upSh, upSl, 65536, nullptr);
    psplit_kernel<<<1024, b256, 0, stream>>>(noise_inv, ninvSh, ninvSl, BIG, nullptr);
    psplit_kernel<<<1024, b256, 0, stream>>>(noise_L, nLSh, nLSl, BIG, nullptr);

    PG q;
    auto clr = [&]() {
        q = PG{};
        q.lda = 256; q.ldb = 256; q.ldc = 256; q.ldct = 256; q.ldp = 256;
        q.alpha = 1.f; q.dcoef = 1.f;
        q.M = 256; q.N = 256; q.K = 256;
    };
    dim3 g64(4, 4, S_);
    dim3 g64b1(4, 4, 1);

    // a. KuuL = Kuu @ L -> pair + pairT
    clr(); q.Ah = KuuSh; q.Al = KuuSl; q.sA = MM_;
    q.Bh = LtSh; q.Bl = LtSl; q.sB = 0;
    q.Ch = KuuLSh; q.Cl = KuuLSl; q.sP = MM_;
    q.ChT = KuuLtSh; q.ClT = KuuLtSl; q.sCt = MM_;
    pgemm64_k<0,1,1,0,0,0><<<g64, b256, 0, stream>>>(q);

    // b. choll = KuuL^T @ L + I -> fp32
    clr(); q.Ah = KuuLtSh; q.Al = KuuLtSl; q.sA = MM_;
    q.Bh = LtSh; q.Bl = LtSl; q.sB = 0;
    q.C = choll; q.sC = MM_;
    pgemm64_k<1,0,0,0,0,1><<<g64, b256, 0, stream>>>(q);

    chol_kernel<<<32, dim3(1024), 0, stream>>>(cholK, choll);

    // ---- block-recursive triangular inverse via MFMA ----
    tri64inv_kernel<<<dim3(4, 32), b256, 0, stream>>>(cholK, invSh, invSl,
                                                      TtSh, TtSl, BVh, BVl);
    lsplit_kernel<<<dim3(3, 32), b256, 0, stream>>>(cholK, LfSh, LfSl);

    for (int i = 1; i < 4; i++) {
        clr(); q.M = 64; q.N = 64 * i; q.K = 64 * i;
        q.Ah = LfSh + (long)64 * i * 256; q.Al = LfSl + (long)64 * i * 256;
        q.lda = 256; q.sA = MM_;
        q.Bh = TtSh; q.Bl = TtSl; q.ldb = 256; q.sB = MM_;
        q.ChT = StTSh; q.ClT = StTSl; q.ldct = 64; q.sCt = 12288;
        pgemm64_k<0,0,1,0,0,0><<<dim3(i, 1, 32), b256, 0, stream>>>(q);
        clr(); q.M = 64; q.N = 64 * i; q.K = 64;
        q.Ah = invSh + (long)i * 4096; q.Al = invSl + (long)i * 4096;
        q.lda = 64; q.sA = 16384;
        q.Bh = StTSh; q.Bl = StTSl; q.ldb = 64; q.sB = 12288;
        q.alpha = -1.f;
        q.Ch = BVh + (long)64 * i * 256; q.Cl = BVl + (long)64 * i * 256;
        q.ldp = 256; q.sP = BVS_;
        q.ChT = TtSh + 64 * i; q.ClT = TtSl + 64 * i; q.ldct = 256; q.sCt = MM_;
        pgemm64_k<0,1,1,0,0,0><<<dim3(i, 1, 32), b256, 0, stream>>>(q);
    }

    // c2. KuuInv = TKt @ TKt^T (K set) -> pair (into LfS alias)
    clr(); q.Ah = TKth; q.Al = TKtl; q.sA = MM_;
    q.Bh = TKth; q.Bl = TKtl; q.sB = MM_;
    q.Ch = KuuInvh; q.Cl = KuuInvl; q.sP = MM_;
    pgemm64_k<0,1,0,0,0,0><<<g64, b256, 0, stream>>>(q);

    // d. lKlpIi = Tlt @ Tlt^T -> pair
    clr(); q.Ah = Tlth; q.Al = Tltl; q.sA = MM_;
    q.Bh = Tlth; q.Bl = Tltl; q.sB = MM_;
    q.Ch = lKlh; q.Cl = lKll; q.sP = MM_;
    pgemm64_k<0,1,0,0,0,0><<<g64, b256, 0, stream>>>(q);

    // e. Stmp = KuuL @ lKlpIi -> pair
    clr(); q.Ah = KuuLSh; q.Al = KuuLSl; q.sA = MM_;
    q.Bh = lKlh; q.Bl = lKll; q.sB = MM_;
    q.Ch = Stmph; q.Cl = Stmpl; q.sP = MM_;
    pgemm64_k<0,1,0,0,0,0><<<g64, b256, 0, stream>>>(q);

    // f. Sigma = Kuu - Stmp @ KuuL^T -> pair
    clr(); q.Ah = Stmph; q.Al = Stmpl; q.sA = MM_;
    q.Bh = KuuLSh; q.Bl = KuuLSl; q.sB = MM_;
    q.Ch = Sigmah; q.Cl = Sigmal; q.sP = MM_;
    q.D = Kuu; q.sD = MM_; q.alpha = -1.f;
    pgemm64_k<0,1,0,0,1,0><<<g64, b256, 0, stream>>>(q);

    // g. W1 = up @ L -> pair (batch 1)
    clr(); q.Ah = upSh; q.Al = upSl; q.sA = 0;
    q.Bh = LtSh; q.Bl = LtSl; q.sB = 0;
    q.Ch = W1Sh; q.Cl = W1Sl; q.sP = 0;
    pgemm64_k<0,1,0,0,0,0><<<g64b1, b256, 0, stream>>>(q);

    // h. UPT = W1 @ L^T -> fp32 (batch 1)
    clr(); q.Ah = W1Sh; q.Al = W1Sl; q.sA = 0;
    q.Bh = LSh; q.Bl = LSl; q.sB = 0;
    q.C = UPT; q.sC = 0;
    pgemm64_k<1,0,0,0,0,0><<<g64b1, b256, 0, stream>>>(q);

    // i. RHS1T = ninv @ TK + UPT -> fp32
    clr(); q.Ah = ninvSh; q.Al = ninvSl; q.sA = 65536;
    q.Bh = TKth; q.Bl = TKtl; q.sB = MM_;
    q.C = RHS1T; q.sC = MM_;
    q.D = UPT; q.sD = 0;
    pgemm64_k<1,0,0,0,1,0><<<g64, b256, 0, stream>>>(q);

    // j. RHST = nL @ L^T + RHS1T -> pair
    clr(); q.Ah = nLSh; q.Al = nLSl; q.sA = 65536;
    q.Bh = LSh; q.Bl = LSl; q.sB = 0;
    q.C = RHS1T; q.sC = MM_;
    q.Ch = RHSTh; q.Cl = RHSTl; q.sP = MM_;
    pgemm64_k<0,1,0,1,0,0><<<g64, b256, 0, stream>>>(q);

    // k. UT = RHST @ Sigma -> fp32 + pair (overwrites Tt region)
    clr(); q.Ah = RHSTh; q.Al = RHSTl; q.sA = MM_;
    q.Bh = Sigmah; q.Bl = Sigmal; q.sB = MM_;
    q.C = UTf32; q.sC = MM_;
    q.Ch = UTph; q.Cl = UTpl; q.sP = MM_;
    pgemm64_k<1,1,0,0,0,0><<<g64, b256, 0, stream>>>(q);

    // G3T = UTp @ KuuInv -> pair into BV rows 256..511
    clr(); q.Ah = UTph; q.Al = UTpl; q.sA = MM_;
    q.Bh = KuuInvh; q.Bl = KuuInvl; q.sB = MM_;
    q.Ch = BVh + 65536; q.Cl = BVl + 65536; q.ldp = 256; q.sP = BVS_;
    pgemm64_k<0,1,0,0,0,0><<<g64, b256, 0, stream>>>(q);

    // out rows 0..255
    utrans_kernel<<<dim3(8, 8, S_), b256, 0, stream>>>(UTf32, 256, MM_, out, OUT_, (long)ROWS_ * OUT_);

    for (int f0 = 0; f0 < NF_; f0 += nfc) {
        int w = NF_ - f0; if (w > nfc) w = nfc;
        tsplit_kernel<<<dim3(w / 32, 8, S_), b256, 0, stream>>>(
            Kuf + f0, NF_, (long)M_ * NF_, KufTch, KufTcl, 256, (long)w * 256, nullptr);
        VE v;
        v.Ah = KufTch; v.Al = KufTcl; v.sA = (long)w * 256;
        v.Bh = BVh; v.Bl = BVl; v.sB = BVS_;
        v.kff = Kff + f0; v.sVf = NF_;
        v.noise = noise_f + (long)f0 * OUT_; v.sNoise = (long)NF_ * OUT_;
        v.C = out + (long)(M_ + f0) * OUT_; v.sC = (long)ROWS_ * OUT_;
        vfef_kernel<<<dim3(1, w / 64, S_), dim3(512), 0, stream>>>(v);
    }
}

// Round 15
// 498.196 us; speedup vs baseline: 1.1365x; 1.1365x over previous
//
#include <hip/hip_runtime.h>
#include <math.h>

#define S_ 16
#define M_ 256
#define NF_ 4096
#define OUT_ 256
#define ROWS_ (M_ + NF_)     // 4352
#define JITTER_ 1e-8f
#define MM_ (M_ * M_)        // 65536

typedef unsigned short u16;
typedef __attribute__((ext_vector_type(8))) short bf16x8;
typedef __attribute__((ext_vector_type(4))) float f32x4;

__device__ inline void cvt2(float x, u16& h, u16& l) {
    unsigned xb = __float_as_uint(x);
    unsigned hb = (xb + 0x7fffu + ((xb >> 16) & 1u)) >> 16;
    float fh = __uint_as_float(hb << 16);
    float rr = x - fh;
    unsigned rb = __float_as_uint(rr);
    unsigned lb = (rb + 0x7fffu + ((rb >> 16) & 1u)) >> 16;
    h = (u16)hb; l = (u16)lb;
}

// ---------------- small prep kernels ----------------

__global__ void max1_kernel(const float* __restrict__ x, int n, float* part) {
    __shared__ float red[256];
    int tid = threadIdx.x;
    float m = -3.4e38f;
    for (int i = blockIdx.x * blockDim.x + tid; i < n; i += gridDim.x * blockDim.x)
        m = fmaxf(m, x[i]);
    red[tid] = m; __syncthreads();
    for (int s = 128; s > 0; s >>= 1) {
        if (tid < s) red[tid] = fmaxf(red[tid], red[tid + s]);
        __syncthreads();
    }
    if (tid == 0) part[blockIdx.x] = red[0];
}

__global__ void max2_kernel(const float* part, float* ws) {
    __shared__ float red[256];
    int tid = threadIdx.x;
    red[tid] = part[tid]; __syncthreads();
    for (int s = 128; s > 0; s >>= 1) {
        if (tid < s) red[tid] = fmaxf(red[tid], red[tid + s]);
        __syncthreads();
    }
    if (tid == 0) { ws[0] = red[0]; ws[2] = JITTER_ * red[0]; }
}

__global__ void prep_kernel(const float* __restrict__ Lloc, const float* __restrict__ Lscale, float* ws) {
    __shared__ float red[256];
    int tid = threadIdx.x;
    red[tid] = Lloc[tid * M_ + tid];
    __syncthreads();
    for (int s = 128; s > 0; s >>= 1) {
        if (tid < s) red[tid] += red[tid + s];
        __syncthreads();
    }
    if (tid == 0) {
        float norm = red[0] / (float)M_;
        ws[1] = expf(Lscale[0]) / norm;
    }
}

// ---- plain split ----
__global__ void psplit_kernel(const float* __restrict__ src, u16* __restrict__ h,
                              u16* __restrict__ l, long n, const float* scaleptr) {
    float sc = scaleptr ? scaleptr[0] : 1.0f;
    long stride = (long)gridDim.x * blockDim.x * 4;
    for (long i = ((long)blockIdx.x * blockDim.x + threadIdx.x) * 4; i < n; i += stride) {
        float4 v = *(const float4*)(src + i);
        u16 h0,h1,h2,h3,l0,l1,l2,l3;
        cvt2(v.x*sc,h0,l0); cvt2(v.y*sc,h1,l1); cvt2(v.z*sc,h2,l2); cvt2(v.w*sc,h3,l3);
        ushort4 hv = {h0,h1,h2,h3}, lv = {l0,l1,l2,l3};
        *(ushort4*)(h + i) = hv;
        *(ushort4*)(l + i) = lv;
    }
}

// ---- fused Kuu split + jittered copy for Cholesky ----
__global__ void splitjit_kernel(const float* __restrict__ Kuu, const float* __restrict__ ws,
                                u16* __restrict__ h, u16* __restrict__ l,
                                float* __restrict__ dst) {
    float jit = ws[2];
    long i = ((long)blockIdx.x * blockDim.x + threadIdx.x) * 4;
    if (i < (long)S_ * MM_) {
        float4 v = *(const float4*)(Kuu + i);
        u16 h0,h1,h2,h3,l0,l1,l2,l3;
        cvt2(v.x,h0,l0); cvt2(v.y,h1,l1); cvt2(v.z,h2,l2); cvt2(v.w,h3,l3);
        ushort4 hv = {h0,h1,h2,h3}, lv = {l0,l1,l2,l3};
        *(ushort4*)(h + i) = hv;
        *(ushort4*)(l + i) = lv;
        int rc = (int)(i & 65535);
        int r = rc >> 8, c0 = rc & 255;
        if (r >= c0 && r < c0 + 4) ((float*)&v)[r - c0] += jit;
        *(float4*)(dst + i) = v;
    }
}

// ---- transpose split ----
__global__ void tsplit_kernel(const float* __restrict__ src, int ldS, long sS,
                              u16* __restrict__ h, u16* __restrict__ l, int ldD, long sD,
                              const float* scaleptr) {
    int b = blockIdx.z;
    src += (long)b * sS; h += (long)b * sD; l += (long)b * sD;
    __shared__ float T[32][33];
    int r0 = blockIdx.y * 32, c0 = blockIdx.x * 32;
    float sc = scaleptr ? scaleptr[0] : 1.0f;
    int tid = threadIdx.x;
    int lrow = tid >> 3, lc4 = (tid & 7) * 4;
    float4 v = *(const float4*)(src + (long)(r0 + lrow) * ldS + c0 + lc4);
    T[lrow][lc4 + 0] = v.x * sc; T[lrow][lc4 + 1] = v.y * sc;
    T[lrow][lc4 + 2] = v.z * sc; T[lrow][lc4 + 3] = v.w * sc;
    __syncthreads();
    int wcol = tid >> 3, wr4 = (tid & 7) * 4;
    u16 h0,h1,h2,h3,l0,l1,l2,l3;
    cvt2(T[wr4+0][wcol],h0,l0); cvt2(T[wr4+1][wcol],h1,l1);
    cvt2(T[wr4+2][wcol],h2,l2); cvt2(T[wr4+3][wcol],h3,l3);
    ushort4 hv = {h0,h1,h2,h3}, lv = {l0,l1,l2,l3};
    *(ushort4*)(h + (long)(c0 + wcol) * ldD + r0 + wr4) = hv;
    *(ushort4*)(l + (long)(c0 + wcol) * ldD + r0 + wr4) = lv;
}

// ---- fp32 transpose ----
__global__ void utrans_kernel(const float* __restrict__ src, int ldS, long sS,
                              float* __restrict__ dst, int ldD, long sD) {
    int b = blockIdx.z;
    src += (long)b * sS; dst += (long)b * sD;
    __shared__ float T[32][33];
    int r0 = blockIdx.y * 32, c0 = blockIdx.x * 32;
    int tid = threadIdx.x;
    int lrow = tid >> 3, lc4 = (tid & 7) * 4;
    float4 v = *(const float4*)(src + (long)(r0 + lrow) * ldS + c0 + lc4);
    T[lrow][lc4+0]=v.x; T[lrow][lc4+1]=v.y; T[lrow][lc4+2]=v.z; T[lrow][lc4+3]=v.w;
    __syncthreads();
    int wcol = tid >> 3, wr4 = (tid & 7) * 4;
    float4 o;
    o.x = T[wr4+0][wcol]; o.y = T[wr4+1][wcol]; o.z = T[wr4+2][wcol]; o.w = T[wr4+3][wcol];
    *(float4*)(dst + (long)(c0 + wcol) * ldD + r0 + wr4) = o;
}

// ---------------- batched blocked Cholesky (BK=16, 1024 threads, monolithic) ----------------

__global__ __launch_bounds__(1024) void chol_kernel(float* bufA, float* bufB) {
    int blk = blockIdx.x;                       // 0..31
    float* Ag = (blk < S_) ? (bufA + (long)blk * MM_) : (bufB + (long)(blk - S_) * MM_);
    __shared__ float P[33280];
    __shared__ float pan2[256 * 20];
    __shared__ float piv[16][18];
    float4* P4 = (float4*)P;
    int tid = threadIdx.x;
    int r = tid >> 2, s = tid & 3;
    int lane = tid & 63, wid = tid >> 6;
    int mg = r >> 2, tg = r & 3;
    int b4 = (mg + 1) * (2 * mg + tg);

    for (int i = wid; i < M_; i += 16) {
        int m = i >> 2, t4 = i & 3;
        int rb4 = (m + 1) * (2 * m + t4);
        if (lane <= m) P4[rb4 + lane] = ((const float4*)Ag)[i * 64 + lane];
    }
    __syncthreads();

    float preg[16];
    for (int p = 0; p < 16; p++) {
        int k0 = p << 4;
        int c0 = p << 2;
        #pragma unroll
        for (int rr = 0; rr < 4; rr++) {
            float4 v = make_float4(0.f, 0.f, 0.f, 0.f);
            if (r >= k0 && c0 + rr <= mg) v = P4[b4 + c0 + rr];
            preg[4 * rr + 0] = v.x; preg[4 * rr + 1] = v.y;
            preg[4 * rr + 2] = v.z; preg[4 * rr + 3] = v.w;
        }
        if (wid == p) {
            int dj = lane >> 2;
            float myinv = 0.f;
            #pragma unroll
            for (int j = 0; j < 16; j++) {
                float app = __shfl(preg[j], 4 * j, 64);
                float d = sqrtf(app);
                float inv = 1.0f / d;
                if (dj == j) { preg[j] = d; myinv = inv; }
                else if (dj > j) preg[j] *= inv;
                #pragma unroll
                for (int j2 = j + 1; j2 < 16; j2++) {
                    float Lj2 = __shfl(preg[j], 4 * j2, 64);
                    if (dj >= j2) preg[j2] -= preg[j] * Lj2;
                }
            }
            if (s == 0) {
                #pragma unroll
                for (int i = 0; i < 16; i++) piv[dj][i] = preg[i];
                piv[dj][16] = myinv;
            }
        }
        __syncthreads();
        if (r > k0 + 15) {
            float x[16];
            #pragma unroll
            for (int j = 0; j < 16; j++) {
                float acc = preg[j];
                #pragma unroll
                for (int i = 0; i < 16; i++)
                    if (i < j) acc -= x[i] * piv[j][i];
                x[j] = acc * piv[j][16];
            }
            #pragma unroll
            for (int j = 0; j < 16; j++) preg[j] = x[j];
        }
        if (r >= k0) {
            float4 pv = make_float4(preg[4 * s], preg[4 * s + 1],
                                    preg[4 * s + 2], preg[4 * s + 3]);
            *(float4*)&pan2[r * 20 + 4 * s] = pv;
            int c = c0 + s;
            if (c <= mg) P4[b4 + c] = pv;
        }
        __syncthreads();
        {
            int cs = tid >> 4;
            int j  = tid & 15;
            if (cs >= c0 + 4) {
                float4 q0[4], q1[4], q2[4], q3[4];
                #pragma unroll
                for (int e = 0; e < 4; e++) {
                    const float4* pr = (const float4*)&pan2[(4 * cs + e) * 20];
                    q0[e] = pr[0]; q1[e] = pr[1]; q2[e] = pr[2]; q3[e] = pr[3];
                }
                int rr = k0 + 16 + j;
                int rmin = 4 * cs;
                while (rr < rmin) rr += 16;
                for (; rr < 256; rr += 16) {
                    int mgr = rr >> 2, tgr = rr & 3;
                    int rb4 = (mgr + 1) * (2 * mgr + tgr);
                    const float4* ar = (const float4*)&pan2[rr * 20];
                    float4 a0 = ar[0], a1 = ar[1], a2 = ar[2], a3 = ar[3];
                    float rv[4];
                    *(float4*)rv = P4[rb4 + cs];
                    #pragma unroll
                    for (int e = 0; e < 4; e++) {
                        float acc;
                        acc  = a0.x*q0[e].x + a0.y*q0[e].y + a0.z*q0[e].z + a0.w*q0[e].w;
                        acc += a1.x*q1[e].x + a1.y*q1[e].y + a1.z*q1[e].z + a1.w*q1[e].w;
                        acc += a2.x*q2[e].x + a2.y*q2[e].y + a2.z*q2[e].z + a2.w*q2[e].w;
                        acc += a3.x*q3[e].x + a3.y*q3[e].y + a3.z*q3[e].z + a3.w*q3[e].w;
                        rv[e] -= acc;
                    }
                    P4[rb4 + cs] = *(float4*)rv;
                }
            }
        }
        __syncthreads();
    }

    for (int i = wid; i < M_; i += 16) {
        int m = i >> 2, t4 = i & 3;
        int rb4 = (m + 1) * (2 * m + t4);
        if (lane <= m) ((float4*)Ag)[i * 64 + lane] = P4[rb4 + lane];
    }
}

// ---------------- 64x64 diagonal-block triangular inverse ----------------

__global__ __launch_bounds__(256) void tri64inv_kernel(const float* W0,
                                                       u16* invh, u16* invl,
                                                       u16* Tth, u16* Ttl,
                                                       u16* TKrh, u16* TKrl) {
    int p = blockIdx.x;        // 0..3
    int mat = blockIdx.y;      // 0..31
    const float* W = W0 + (long)mat * MM_;
    int d0 = p * 64;
    __shared__ float X[64 * 65];
    __shared__ float pan[64 * 20];
    int tid = threadIdx.x;
    int c = tid & 63, q = tid >> 6;
    for (int idx = tid; idx < 64 * 65; idx += 256) X[idx] = 0.f;
    __syncthreads();
    if (q == 0) X[c * 65 + c] = 1.0f;
    for (int pp = 0; pp < 4; pp++) {
        int t0 = pp << 4;
        for (int idx = tid; idx < 64 * 4; idx += 256) {
            int k = idx >> 2, e = idx & 3;
            if (k >= t0)
                ((float4*)(pan + k * 20))[e] =
                    *(const float4*)(W + (long)(d0 + k) * 256 + d0 + t0 + 4 * e);
        }
        __syncthreads();
        if (q == pp) {
            float xr[16];
            #pragma unroll
            for (int j = 0; j < 16; j++) {
                float xv = X[(t0 + j) * 65 + c];
                #pragma unroll
                for (int i = 0; i < 16; i++)
                    if (i < j) xv -= pan[(t0 + j) * 20 + i] * xr[i];
                xv *= (1.0f / pan[(t0 + j) * 20 + j]);
                xr[j] = xv;
                X[(t0 + j) * 65 + c] = xv;
            }
        }
        __syncthreads();
        int kbeg = q << 4; if (kbeg < t0 + 16) kbeg = t0 + 16;
        int kend = (q << 4) + 16;
        if (kbeg < kend) {
            float xr[16];
            #pragma unroll
            for (int j = 0; j < 16; j++) xr[j] = X[(t0 + j) * 65 + c];
            for (int kk = kbeg; kk < kend; kk++) {
                float rv = X[kk * 65 + c];
                const float4* pr = (const float4*)&pan[kk * 20];
                float4 a = pr[0], b = pr[1], d = pr[2], e = pr[3];
                rv -= a.x * xr[0] + a.y * xr[1] + a.z * xr[2] + a.w * xr[3];
                rv -= b.x * xr[4] + b.y * xr[5] + b.z * xr[6] + b.w * xr[7];
                rv -= d.x * xr[8] + d.y * xr[9] + d.z * xr[10] + d.w * xr[11];
                rv -= e.x * xr[12] + e.y * xr[13] + e.z * xr[14] + e.w * xr[15];
                X[kk * 65 + c] = rv;
            }
        }
        __syncthreads();
    }
    for (int idx = tid; idx < 4096; idx += 256) {
        int r = idx >> 6, k = idx & 63;
        u16 h, l; cvt2(X[r * 65 + k], h, l);
        long io = (long)mat * 16384 + (long)p * 4096 + idx;
        invh[io] = h; invl[io] = l;
        long ro = (long)mat * MM_ + (long)(d0 + r) * 256 + d0 + k;
        TKrh[ro] = h; TKrl[ro] = l;
        long to = (long)mat * MM_ + (long)(d0 + k) * 256 + d0 + r;
        Tth[to] = h; Ttl[to] = l;
    }
}

// ---- pair-split strictly-lower panels of cholK into Lfull [256][256] pair ----
__global__ void lsplit_kernel(const float* __restrict__ W0,
                              u16* __restrict__ Lh, u16* __restrict__ Ll) {
    int p = blockIdx.x;        // 0..2
    int mat = blockIdx.y;      // 0..31
    const float* W = W0 + (long)mat * MM_;
    u16* dh = Lh + (long)mat * MM_;
    u16* dl = Ll + (long)mat * MM_;
    int d0 = 64 * p, nrows = 192 - d0;
    for (int idx = threadIdx.x; idx < nrows * 16; idx += 256) {
        int r = idx >> 4, c4 = idx & 15;
        long o = (long)(d0 + 64 + r) * 256 + d0 + 4 * c4;
        float4 v = *(const float4*)(W + o);
        u16 h0,h1,h2,h3,l0,l1,l2,l3;
        cvt2(v.x,h0,l0); cvt2(v.y,h1,l1); cvt2(v.z,h2,l2); cvt2(v.w,h3,l3);
        ushort4 hv = {h0,h1,h2,h3}, lv = {l0,l1,l2,l3};
        *(ushort4*)(dh + o) = hv;
        *(ushort4*)(dl + o) = lv;
    }
}

// ---------------- pair GEMM: C = alpha * A @ B^T(storage) + epilogue ----------------

struct PG {
    const u16 *Ah, *Al, *Bh, *Bl;
    float* C; u16 *Ch, *Cl, *ChT, *ClT;
    const float* D; const float* noise;
    const float* kff; float* vfacc;
    int M, N, K, lda, ldb, ldc, ldct, ldp;
    long sA, sB, sC, sP, sCt, sD, sVf, sNoise;
    float alpha, dcoef;
};

// 128x128 tile, 4 waves (K = 256)
template<int OF, int OP, int OPT, int ACCf, int Df, int ADDIf, int EFf, int VFf>
__global__ __launch_bounds__(256) void pgemm_k(PG p) {
    int bz = blockIdx.z;
    const u16* Agh = p.Ah + (long)bz * p.sA;
    const u16* Agl = p.Al + (long)bz * p.sA;
    const u16* Bgh = p.Bh + (long)bz * p.sB;
    const u16* Bgl = p.Bl + (long)bz * p.sB;
    int bm = blockIdx.y * 128, bn = blockIdx.x * 128;
    __shared__ __align__(16) u16 sAh[128][40];
    __shared__ __align__(16) u16 sAl[128][40];
    __shared__ __align__(16) u16 sBh[128][40];
    __shared__ __align__(16) u16 sBl[128][40];
    int tid = threadIdx.x, lane = tid & 63, wid = tid >> 6;
    int wm = (wid >> 1) * 64, wn = (wid & 1) * 64;
    int fr = lane & 15, ko = (lane >> 4) * 8;
    int kb = tid & 3, rw = tid >> 2;
    f32x4 acc[4][4];
    #pragma unroll
    for (int m = 0; m < 4; m++)
        #pragma unroll
        for (int n = 0; n < 4; n++)
            acc[m][n] = (f32x4){0.f, 0.f, 0.f, 0.f};

    for (int k0 = 0; k0 < 256; k0 += 32) {
        #define STG(SRC, LD, BASE, DST) \
            *(bf16x8*)&DST[rw][kb * 8] = \
                *(const bf16x8*)(SRC + (long)(BASE + rw) * LD + k0 + kb * 8); \
            *(bf16x8*)&DST[rw + 64][kb * 8] = \
                *(const bf16x8*)(SRC + (long)(BASE + rw + 64) * LD + k0 + kb * 8);
        STG(Agh, p.lda, bm, sAh)
        STG(Agl, p.lda, bm, sAl)
        STG(Bgh, p.ldb, bn, sBh)
        STG(Bgl, p.ldb, bn, sBl)
        #undef STG
        __syncthreads();
        bf16x8 ah[4], al[4], bh[4], bl[4];
        #pragma unroll
        for (int m = 0; m < 4; m++) {
            ah[m] = *(const bf16x8*)&sAh[wm + m * 16 + fr][ko];
            al[m] = *(const bf16x8*)&sAl[wm + m * 16 + fr][ko];
        }
        #pragma unroll
        for (int n = 0; n < 4; n++) {
            bh[n] = *(const bf16x8*)&sBh[wn + n * 16 + fr][ko];
            bl[n] = *(const bf16x8*)&sBl[wn + n * 16 + fr][ko];
        }
        #pragma unroll
        for (int m = 0; m < 4; m++)
            #pragma unroll
            for (int n = 0; n < 4; n++) {
                acc[m][n] = __builtin_amdgcn_mfma_f32_16x16x32_bf16(ah[m], bh[n], acc[m][n], 0, 0, 0);
                acc[m][n] = __builtin_amdgcn_mfma_f32_16x16x32_bf16(ah[m], bl[n], acc[m][n], 0, 0, 0);
                acc[m][n] = __builtin_amdgcn_mfma_f32_16x16x32_bf16(al[m], bh[n], acc[m][n], 0, 0, 0);
            }
        __syncthreads();
    }

    int rq = (lane >> 4) * 4;
    float rs[4][4];
    if (VFf) {
        #pragma unroll
        for (int m = 0; m < 4; m++)
            #pragma unroll
            for (int i = 0; i < 4; i++) rs[m][i] = 0.f;
    }
    #pragma unroll
    for (int m = 0; m < 4; m++) {
        int row0 = bm + wm + m * 16 + rq;
        #pragma unroll
        for (int n = 0; n < 4; n++) {
            int col = bn + wn + n * 16 + fr;
            float v[4];
            #pragma unroll
            for (int i = 0; i < 4; i++) {
                int r = row0 + i;
                float val = p.alpha * acc[m][n][i];
                if (Df)   val += p.dcoef * p.D[(long)bz * p.sD + (long)r * p.ldc + col];
                if (ACCf) val += p.C[(long)bz * p.sC + (long)r * p.ldc + col];
                if (ADDIf && r == col) val += 1.0f;
                if (EFf) {
                    float kf = p.kff[(long)bz * p.sVf + r];
                    float vq = p.vfacc[(long)bz * p.sVf + r];
                    val += sqrtf(fmaxf(kf - vq, 0.f)) *
                           p.noise[(long)bz * p.sNoise + (long)r * 256 + col];
                }
                v[i] = val;
                if (VFf) rs[m][i] += val * val;
            }
            if (OF) {
                #pragma unroll
                for (int i = 0; i < 4; i++)
                    p.C[(long)bz * p.sC + (long)(row0 + i) * p.ldc + col] = v[i];
            }
            if (OP) {
                #pragma unroll
                for (int i = 0; i < 4; i++) {
                    u16 h, l; cvt2(v[i], h, l);
                    p.Ch[(long)bz * p.sP + (long)(row0 + i) * p.ldc + col] = h;
                    p.Cl[(long)bz * p.sP + (long)(row0 + i) * p.ldc + col] = l;
                }
            }
            if (OPT) {
                u16 h0,h1,h2,h3,l0,l1,l2,l3;
                cvt2(v[0],h0,l0); cvt2(v[1],h1,l1); cvt2(v[2],h2,l2); cvt2(v[3],h3,l3);
                ushort4 hv = {h0,h1,h2,h3}, lv = {l0,l1,l2,l3};
                *(ushort4*)&p.ChT[(long)bz * p.sCt + (long)col * p.ldct + row0] = hv;
                *(ushort4*)&p.ClT[(long)bz * p.sCt + (long)col * p.ldct + row0] = lv;
            }
        }
    }
    if (VFf) {
        #pragma unroll
        for (int m = 0; m < 4; m++) {
            int row0 = bm + wm + m * 16 + rq;
            #pragma unroll
            for (int i = 0; i < 4; i++) {
                float t = rs[m][i];
                t += __shfl_xor(t, 1); t += __shfl_xor(t, 2);
                t += __shfl_xor(t, 4); t += __shfl_xor(t, 8);
                if (fr == 0)
                    atomicAdd(&p.vfacc[(long)bz * p.sVf + row0 + i], t);
            }
        }
    }
}

// 64x64 tile, 4 waves, runtime K (multiple of 32)
template<int OF, int OP, int OPT, int ACCf, int Df, int ADDIf>
__global__ __launch_bounds__(256) void pgemm64_k(PG p) {
    int bz = blockIdx.z;
    const u16* Agh = p.Ah + (long)bz * p.sA;
    const u16* Agl = p.Al + (long)bz * p.sA;
    const u16* Bgh = p.Bh + (long)bz * p.sB;
    const u16* Bgl = p.Bl + (long)bz * p.sB;
    int bm = blockIdx.y * 64, bn = blockIdx.x * 64;
    __shared__ __align__(16) u16 sAh[64][40];
    __shared__ __align__(16) u16 sAl[64][40];
    __shared__ __align__(16) u16 sBh[64][40];
    __shared__ __align__(16) u16 sBl[64][40];
    int tid = threadIdx.x, lane = tid & 63, wid = tid >> 6;
    int wm = (wid >> 1) * 32, wn = (wid & 1) * 32;
    int fr = lane & 15, ko = (lane >> 4) * 8;
    int kb = tid & 3, rw = tid >> 2;
    f32x4 acc[2][2];
    #pragma unroll
    for (int m = 0; m < 2; m++)
        #pragma unroll
        for (int n = 0; n < 2; n++)
            acc[m][n] = (f32x4){0.f, 0.f, 0.f, 0.f};

    for (int k0 = 0; k0 < p.K; k0 += 32) {
        *(bf16x8*)&sAh[rw][kb * 8] = *(const bf16x8*)(Agh + (long)(bm + rw) * p.lda + k0 + kb * 8);
        *(bf16x8*)&sAl[rw][kb * 8] = *(const bf16x8*)(Agl + (long)(bm + rw) * p.lda + k0 + kb * 8);
        *(bf16x8*)&sBh[rw][kb * 8] = *(const bf16x8*)(Bgh + (long)(bn + rw) * p.ldb + k0 + kb * 8);
        *(bf16x8*)&sBl[rw][kb * 8] = *(const bf16x8*)(Bgl + (long)(bn + rw) * p.ldb + k0 + kb * 8);
        __syncthreads();
        bf16x8 ah[2], al[2], bh[2], bl[2];
        #pragma unroll
        for (int m = 0; m < 2; m++) {
            ah[m] = *(const bf16x8*)&sAh[wm + m * 16 + fr][ko];
            al[m] = *(const bf16x8*)&sAl[wm + m * 16 + fr][ko];
        }
        #pragma unroll
        for (int n = 0; n < 2; n++) {
            bh[n] = *(const bf16x8*)&sBh[wn + n * 16 + fr][ko];
            bl[n] = *(const bf16x8*)&sBl[wn + n * 16 + fr][ko];
        }
        #pragma unroll
        for (int m = 0; m < 2; m++)
            #pragma unroll
            for (int n = 0; n < 2; n++) {
                acc[m][n] = __builtin_amdgcn_mfma_f32_16x16x32_bf16(ah[m], bh[n], acc[m][n], 0, 0, 0);
                acc[m][n] = __builtin_amdgcn_mfma_f32_16x16x32_bf16(ah[m], bl[n], acc[m][n], 0, 0, 0);
                acc[m][n] = __builtin_amdgcn_mfma_f32_16x16x32_bf16(al[m], bh[n], acc[m][n], 0, 0, 0);
            }
        __syncthreads();
    }

    int rq = (lane >> 4) * 4;
    #pragma unroll
    for (int m = 0; m < 2; m++) {
        int row0 = bm + wm + m * 16 + rq;
        #pragma unroll
        for (int n = 0; n < 2; n++) {
            int col = bn + wn + n * 16 + fr;
            float v[4];
            #pragma unroll
            for (int i = 0; i < 4; i++) {
                int r = row0 + i;
                float val = p.alpha * acc[m][n][i];
                if (Df)   val += p.dcoef * p.D[(long)bz * p.sD + (long)r * p.ldc + col];
                if (ACCf) val += p.C[(long)bz * p.sC + (long)r * p.ldc + col];
                if (ADDIf && r == col) val += 1.0f;
                v[i] = val;
            }
            if (OF) {
                #pragma unroll
                for (int i = 0; i < 4; i++)
                    p.C[(long)bz * p.sC + (long)(row0 + i) * p.ldc + col] = v[i];
            }
            if (OP) {
                #pragma unroll
                for (int i = 0; i < 4; i++) {
                    u16 h, l; cvt2(v[i], h, l);
                    p.Ch[(long)bz * p.sP + (long)(row0 + i) * p.ldp + col] = h;
                    p.Cl[(long)bz * p.sP + (long)(row0 + i) * p.ldp + col] = l;
                }
            }
            if (OPT) {
                u16 h0,h1,h2,h3,l0,l1,l2,l3;
                cvt2(v[0],h0,l0); cvt2(v[1],h1,l1); cvt2(v[2],h2,l2); cvt2(v[3],h3,l3);
                ushort4 hv = {h0,h1,h2,h3}, lv = {l0,l1,l2,l3};
                *(ushort4*)&p.ChT[(long)bz * p.sCt + (long)col * p.ldct + row0] = hv;
                *(ushort4*)&p.ClT[(long)bz * p.sCt + (long)col * p.ldct + row0] = lv;
            }
        }
    }
}

// ---------------- host ----------------

extern "C" void kernel_launch(void* const* d_in, const int* in_sizes, int n_in,
                              void* d_out, int out_size, void* d_ws, size_t ws_size,
                              hipStream_t stream) {
    const float* Kuu       = (const float*)d_in[0];
    const float* Kuf       = (const float*)d_in[1];
    const float* Kff       = (const float*)d_in[2];
    const float* Lloc      = (const float*)d_in[3];
    const float* Lscale    = (const float*)d_in[4];
    const float* u_param   = (const float*)d_in[5];
    const float* noise_inv = (const float*)d_in[6];
    const float* noise_L   = (const float*)d_in[7];
    const float* noise_f   = (const float*)d_in[8];
    float* out = (float*)d_out;
    float* ws  = (float*)d_ws;

    const long BIG = (long)S_ * MM_;     // 1,048,576 elements
    long off = 1024;
    float* part = ws + 16;

    #define PAIR(NAME, E) u16* NAME##h = (u16*)(ws + off); u16* NAME##l = NAME##h + (E); off += (E);
    PAIR(LS, 65536)
    PAIR(LtS, 65536)
    PAIR(upS, 65536)
    PAIR(W1S, 65536)
    float* UPT   = ws + off; off += 65536;
    float* VfAcc = ws + off; off += 65536;
    PAIR(KuuS, BIG)
    PAIR(ninvS, BIG)
    PAIR(nLS, BIG)
    float* cholK = ws + off; off += 2 * BIG;   // 32 matrices contiguous
    float* choll = cholK + BIG;
    PAIR(KuuLS, BIG)
    PAIR(KuuLtS, BIG)
    PAIR(TtS, 2 * BIG)             // T^T pair, 32 matrices
    PAIR(TKrS, 2 * BIG)            // T row-major pair, 32 matrices
    PAIR(G2TS, BIG)
    PAIR(lKlS, BIG)
    PAIR(invS, 524288)             // 32 mats x 4 panels x 64x64 D pair
    PAIR(LfS, 2 * BIG)             // L strictly-lower pair, 32 matrices
    PAIR(StTS, 393216)             // S^T scratch pair, 32 x 192x64
    #undef PAIR

    u16* TKth = TtSh;                u16* TKtl = TtSl;
    u16* Tlth = TtSh + (long)S_ * MM_; u16* Tltl = TtSl + (long)S_ * MM_;
    u16* RHSTh   = KuuSh;            u16* RHSTl   = KuuSl;
    u16* UTph    = nLSh;             u16* UTpl    = nLSl;
    float* RHS1T = (float*)KuuLSh;
    u16* Sigmah  = KuuLtSh;          u16* Sigmal  = KuuLtSl;
    u16* lKlh    = lKlSh;            u16* lKll    = lKlSl;
    float* UTf32 = (float*)TtSh;     // Tt free after GEMM i
    u16* Stmph   = Tlth;             u16* Stmpl   = Tltl;

    long navail = (long)(ws_size / 4) - off;
    long nfc_l = navail / 8192;
    int nfc = (int)((nfc_l / 128) * 128);
    if (nfc > NF_) nfc = NF_;
    if (nfc < 128) nfc = 128;
    long Ec = (long)S_ * nfc * 256;
    u16* KufTch = (u16*)(ws + off);      u16* KufTcl = KufTch + Ec;
    u16* Hch    = (u16*)(ws + off + Ec); u16* Hcl    = Hch + Ec;

    dim3 b256(256);

    hipMemsetAsync(TtSh, 0, (size_t)4 * 2 * BIG, stream);
    hipMemsetAsync(TKrSh, 0, (size_t)4 * 2 * BIG, stream);
    hipMemsetAsync(VfAcc, 0, (size_t)S_ * NF_ * sizeof(float), stream);

    max1_kernel<<<256, b256, 0, stream>>>(Kuu, S_ * MM_, part);
    max2_kernel<<<1, b256, 0, stream>>>(part, ws);
    prep_kernel<<<1, b256, 0, stream>>>(Lloc, Lscale, ws);

    splitjit_kernel<<<1024, b256, 0, stream>>>(Kuu, ws, KuuSh, KuuSl, cholK);
    psplit_kernel<<<64, b256, 0, stream>>>(Lloc, LSh, LSl, 65536, ws + 1);
    tsplit_kernel<<<dim3(8, 8, 1), b256, 0, stream>>>(Lloc, 256, 0, LtSh, LtSl, 256, 0, ws + 1);
    psplit_kernel<<<64, b256, 0, stream>>>(u_param, upSh, upSl, 65536, nullptr);
    psplit_kernel<<<1024, b256, 0, stream>>>(noise_inv, ninvSh, ninvSl, BIG, nullptr);
    psplit_kernel<<<1024, b256, 0, stream>>>(noise_L, nLSh, nLSl, BIG, nullptr);

    PG q;
    auto clr = [&]() {
        q = PG{};
        q.lda = 256; q.ldb = 256; q.ldc = 256; q.ldct = 256; q.ldp = 256;
        q.alpha = 1.f; q.dcoef = 1.f;
        q.M = 256; q.N = 256; q.K = 256;
    };
    dim3 g64(4, 4, S_);
    dim3 g64b1(4, 4, 1);

    // a. KuuL = Kuu @ L -> pair + pairT
    clr(); q.Ah = KuuSh; q.Al = KuuSl; q.sA = MM_;
    q.Bh = LtSh; q.Bl = LtSl; q.sB = 0;
    q.Ch = KuuLSh; q.Cl = KuuLSl; q.sP = MM_;
    q.ChT = KuuLtSh; q.ClT = KuuLtSl; q.sCt = MM_;
    pgemm64_k<0,1,1,0,0,0><<<g64, b256, 0, stream>>>(q);

    // b. choll = KuuL^T @ L + I -> fp32
    clr(); q.Ah = KuuLtSh; q.Al = KuuLtSl; q.sA = MM_;
    q.Bh = LtSh; q.Bl = LtSl; q.sB = 0;
    q.C = choll; q.sC = MM_;
    pgemm64_k<1,0,0,0,0,1><<<g64, b256, 0, stream>>>(q);

    chol_kernel<<<32, dim3(1024), 0, stream>>>(cholK, choll);

    // ---- block-recursive triangular inverse via MFMA ----
    tri64inv_kernel<<<dim3(4, 32), b256, 0, stream>>>(cholK, invSh, invSl,
                                                      TtSh, TtSl, TKrSh, TKrSl);
    lsplit_kernel<<<dim3(3, 32), b256, 0, stream>>>(cholK, LfSh, LfSl);

    for (int i = 1; i < 4; i++) {
        clr(); q.M = 64; q.N = 64 * i; q.K = 64 * i;
        q.Ah = LfSh + (long)64 * i * 256; q.Al = LfSl + (long)64 * i * 256;
        q.lda = 256; q.sA = MM_;
        q.Bh = TtSh; q.Bl = TtSl; q.ldb = 256; q.sB = MM_;
        q.ChT = StTSh; q.ClT = StTSl; q.ldct = 64; q.sCt = 12288;
        pgemm64_k<0,0,1,0,0,0><<<dim3(i, 1, 32), b256, 0, stream>>>(q);
        clr(); q.M = 64; q.N = 64 * i; q.K = 64;
        q.Ah = invSh + (long)i * 4096; q.Al = invSl + (long)i * 4096;
        q.lda = 64; q.sA = 16384;
        q.Bh = StTSh; q.Bl = StTSl; q.ldb = 64; q.sB = 12288;
        q.alpha = -1.f;
        q.Ch = TKrSh + (long)64 * i * 256; q.Cl = TKrSl + (long)64 * i * 256;
        q.ldp = 256; q.sP = MM_;
        q.ChT = TtSh + 64 * i; q.ClT = TtSl + 64 * i; q.ldct = 256; q.sCt = MM_;
        pgemm64_k<0,1,1,0,0,0><<<dim3(i, 1, 32), b256, 0, stream>>>(q);
    }

    // d. lKlpIi = Tlt @ Tlt^T -> pair
    clr(); q.Ah = Tlth; q.Al = Tltl; q.sA = MM_;
    q.Bh = Tlth; q.Bl = Tltl; q.sB = MM_;
    q.Ch = lKlh; q.Cl = lKll; q.sP = MM_;
    pgemm64_k<0,1,0,0,0,0><<<g64, b256, 0, stream>>>(q);

    // e. Stmp = KuuL @ lKlpIi -> pair
    clr(); q.Ah = KuuLSh; q.Al = KuuLSl; q.sA = MM_;
    q.Bh = lKlh; q.Bl = lKll; q.sB = MM_;
    q.Ch = Stmph; q.Cl = Stmpl; q.sP = MM_;
    pgemm64_k<0,1,0,0,0,0><<<g64, b256, 0, stream>>>(q);

    // f. Sigma = Kuu - Stmp @ KuuL^T -> pair
    clr(); q.Ah = Stmph; q.Al = Stmpl; q.sA = MM_;
    q.Bh = KuuLSh; q.Bl = KuuLSl; q.sB = MM_;
    q.Ch = Sigmah; q.Cl = Sigmal; q.sP = MM_;
    q.D = Kuu; q.sD = MM_; q.alpha = -1.f;
    pgemm64_k<0,1,0,0,1,0><<<g64, b256, 0, stream>>>(q);

    // g. W1 = up @ L -> pair (batch 1)
    clr(); q.Ah = upSh; q.Al = upSl; q.sA = 0;
    q.Bh = LtSh; q.Bl = LtSl; q.sB = 0;
    q.Ch = W1Sh; q.Cl = W1Sl; q.sP = 0;
    pgemm64_k<0,1,0,0,0,0><<<g64b1, b256, 0, stream>>>(q);

    // h. UPT = W1 @ L^T -> fp32 (batch 1)
    clr(); q.Ah = W1Sh; q.Al = W1Sl; q.sA = 0;
    q.Bh = LSh; q.Bl = LSl; q.sB = 0;
    q.C = UPT; q.sC = 0;
    pgemm64_k<1,0,0,0,0,0><<<g64b1, b256, 0, stream>>>(q);

    // i. RHS1T = ninv @ TK + UPT -> fp32
    clr(); q.Ah = ninvSh; q.Al = ninvSl; q.sA = 65536;
    q.Bh = TKth; q.Bl = TKtl; q.sB = MM_;
    q.C = RHS1T; q.sC = MM_;
    q.D = UPT; q.sD = 0;
    pgemm64_k<1,0,0,0,1,0><<<g64, b256, 0, stream>>>(q);

    // j. RHST = nL @ L^T + RHS1T -> pair
    clr(); q.Ah = nLSh; q.Al = nLSl; q.sA = 65536;
    q.Bh = LSh; q.Bl = LSl; q.sB = 0;
    q.C = RHS1T; q.sC = MM_;
    q.Ch = RHSTh; q.Cl = RHSTl; q.sP = MM_;
    pgemm64_k<0,1,0,1,0,0><<<g64, b256, 0, stream>>>(q);

    // k. UT = RHST @ Sigma -> fp32 + pair
    clr(); q.Ah = RHSTh; q.Al = RHSTl; q.sA = MM_;
    q.Bh = Sigmah; q.Bl = Sigmal; q.sB = MM_;
    q.C = UTf32; q.sC = MM_;
    q.Ch = UTph; q.Cl = UTpl; q.sP = MM_;
    pgemm64_k<1,1,0,0,0,0><<<g64, b256, 0, stream>>>(q);

    // G2 = TK @ u -> G2^T pair
    clr(); q.Ah = TKrSh; q.Al = TKrSl; q.sA = MM_;
    q.Bh = UTph; q.Bl = UTpl; q.sB = MM_;
    q.ChT = G2TSh; q.ClT = G2TSl; q.sCt = MM_;
    pgemm64_k<0,0,1,0,0,0><<<g64, b256, 0, stream>>>(q);

    // out rows 0..255
    utrans_kernel<<<dim3(8, 8, S_), b256, 0, stream>>>(UTf32, 256, MM_, out, OUT_, (long)ROWS_ * OUT_);

    for (int f0 = 0; f0 < NF_; f0 += nfc) {
        int w = NF_ - f0; if (w > nfc) w = nfc;
        tsplit_kernel<<<dim3(w / 32, 8, S_), b256, 0, stream>>>(
            Kuf + f0, NF_, (long)M_ * NF_, KufTch, KufTcl, 256, (long)w * 256, nullptr);
        // H' = KufT @ TK^T -> pair, + VfAcc row sums of squares
        clr(); q.M = w; q.N = 256;
        q.Ah = KufTch; q.Al = KufTcl; q.sA = (long)w * 256;
        q.Bh = TKrSh; q.Bl = TKrSl; q.sB = MM_;
        q.Ch = Hch; q.Cl = Hcl; q.sP = (long)w * 256;
        q.vfacc = VfAcc + f0; q.sVf = NF_;
        pgemm_k<0,1,0,0,0,0,0,1><<<dim3(2, w / 128, S_), b256, 0, stream>>>(q);
        // out_f = H' @ G2 + sqrt(Kff - VfAcc)*noise_f
        clr(); q.M = w; q.N = 256;
        q.Ah = Hch; q.Al = Hcl; q.sA = (long)w * 256;
        q.Bh = G2TSh; q.Bl = G2TSl; q.sB = MM_;
        q.C = out + (long)(M_ + f0) * OUT_; q.sC = (long)ROWS_ * OUT_;
        q.kff = Kff + f0; q.vfacc = VfAcc + f0; q.sVf = NF_;
        q.noise = noise_f + (long)f0 * OUT_; q.sNoise = (long)NF_ * OUT_;
        pgemm_k<1,0,0,0,0,0,1,0><<<dim3(2, w / 128, S_), b256, 0, stream>>>(q);
    }
}

// Round 16
// 495.367 us; speedup vs baseline: 1.1429x; 1.0057x over previous
//
#include <hip/hip_runtime.h>
#include <math.h>

#define S_ 16
#define M_ 256
#define NF_ 4096
#define OUT_ 256
#define ROWS_ (M_ + NF_)     // 4352
#define JITTER_ 1e-8f
#define MM_ (M_ * M_)        // 65536

typedef unsigned short u16;
typedef __attribute__((ext_vector_type(8))) short bf16x8;
typedef __attribute__((ext_vector_type(4))) float f32x4;

__device__ inline void cvt2(float x, u16& h, u16& l) {
    unsigned xb = __float_as_uint(x);
    unsigned hb = (xb + 0x7fffu + ((xb >> 16) & 1u)) >> 16;
    float fh = __uint_as_float(hb << 16);
    float rr = x - fh;
    unsigned rb = __float_as_uint(rr);
    unsigned lb = (rb + 0x7fffu + ((rb >> 16) & 1u)) >> 16;
    h = (u16)hb; l = (u16)lb;
}

// ---------------- small prep kernels ----------------

__global__ void max1_kernel(const float* __restrict__ x, int n, float* part) {
    __shared__ float red[256];
    int tid = threadIdx.x;
    float m = -3.4e38f;
    for (int i = blockIdx.x * blockDim.x + tid; i < n; i += gridDim.x * blockDim.x)
        m = fmaxf(m, x[i]);
    red[tid] = m; __syncthreads();
    for (int s = 128; s > 0; s >>= 1) {
        if (tid < s) red[tid] = fmaxf(red[tid], red[tid + s]);
        __syncthreads();
    }
    if (tid == 0) part[blockIdx.x] = red[0];
}

__global__ void max2_kernel(const float* part, float* ws) {
    __shared__ float red[256];
    int tid = threadIdx.x;
    red[tid] = part[tid]; __syncthreads();
    for (int s = 128; s > 0; s >>= 1) {
        if (tid < s) red[tid] = fmaxf(red[tid], red[tid + s]);
        __syncthreads();
    }
    if (tid == 0) { ws[0] = red[0]; ws[2] = JITTER_ * red[0]; }
}

__global__ void prep_kernel(const float* __restrict__ Lloc, const float* __restrict__ Lscale, float* ws) {
    __shared__ float red[256];
    int tid = threadIdx.x;
    red[tid] = Lloc[tid * M_ + tid];
    __syncthreads();
    for (int s = 128; s > 0; s >>= 1) {
        if (tid < s) red[tid] += red[tid + s];
        __syncthreads();
    }
    if (tid == 0) {
        float norm = red[0] / (float)M_;
        ws[1] = expf(Lscale[0]) / norm;
    }
}

// ---- plain split ----
__global__ void psplit_kernel(const float* __restrict__ src, u16* __restrict__ h,
                              u16* __restrict__ l, long n, const float* scaleptr) {
    float sc = scaleptr ? scaleptr[0] : 1.0f;
    long stride = (long)gridDim.x * blockDim.x * 4;
    for (long i = ((long)blockIdx.x * blockDim.x + threadIdx.x) * 4; i < n; i += stride) {
        float4 v = *(const float4*)(src + i);
        u16 h0,h1,h2,h3,l0,l1,l2,l3;
        cvt2(v.x*sc,h0,l0); cvt2(v.y*sc,h1,l1); cvt2(v.z*sc,h2,l2); cvt2(v.w*sc,h3,l3);
        ushort4 hv = {h0,h1,h2,h3}, lv = {l0,l1,l2,l3};
        *(ushort4*)(h + i) = hv;
        *(ushort4*)(l + i) = lv;
    }
}

// ---- fused Kuu split + jittered copy for Cholesky ----
__global__ void splitjit_kernel(const float* __restrict__ Kuu, const float* __restrict__ ws,
                                u16* __restrict__ h, u16* __restrict__ l,
                                float* __restrict__ dst) {
    float jit = ws[2];
    long i = ((long)blockIdx.x * blockDim.x + threadIdx.x) * 4;
    if (i < (long)S_ * MM_) {
        float4 v = *(const float4*)(Kuu + i);
        u16 h0,h1,h2,h3,l0,l1,l2,l3;
        cvt2(v.x,h0,l0); cvt2(v.y,h1,l1); cvt2(v.z,h2,l2); cvt2(v.w,h3,l3);
        ushort4 hv = {h0,h1,h2,h3}, lv = {l0,l1,l2,l3};
        *(ushort4*)(h + i) = hv;
        *(ushort4*)(l + i) = lv;
        int rc = (int)(i & 65535);
        int r = rc >> 8, c0 = rc & 255;
        if (r >= c0 && r < c0 + 4) ((float*)&v)[r - c0] += jit;
        *(float4*)(dst + i) = v;
    }
}

// ---- transpose split ----
__global__ void tsplit_kernel(const float* __restrict__ src, int ldS, long sS,
                              u16* __restrict__ h, u16* __restrict__ l, int ldD, long sD,
                              const float* scaleptr) {
    int b = blockIdx.z;
    src += (long)b * sS; h += (long)b * sD; l += (long)b * sD;
    __shared__ float T[32][33];
    int r0 = blockIdx.y * 32, c0 = blockIdx.x * 32;
    float sc = scaleptr ? scaleptr[0] : 1.0f;
    int tid = threadIdx.x;
    int lrow = tid >> 3, lc4 = (tid & 7) * 4;
    float4 v = *(const float4*)(src + (long)(r0 + lrow) * ldS + c0 + lc4);
    T[lrow][lc4 + 0] = v.x * sc; T[lrow][lc4 + 1] = v.y * sc;
    T[lrow][lc4 + 2] = v.z * sc; T[lrow][lc4 + 3] = v.w * sc;
    __syncthreads();
    int wcol = tid >> 3, wr4 = (tid & 7) * 4;
    u16 h0,h1,h2,h3,l0,l1,l2,l3;
    cvt2(T[wr4+0][wcol],h0,l0); cvt2(T[wr4+1][wcol],h1,l1);
    cvt2(T[wr4+2][wcol],h2,l2); cvt2(T[wr4+3][wcol],h3,l3);
    ushort4 hv = {h0,h1,h2,h3}, lv = {l0,l1,l2,l3};
    *(ushort4*)(h + (long)(c0 + wcol) * ldD + r0 + wr4) = hv;
    *(ushort4*)(l + (long)(c0 + wcol) * ldD + r0 + wr4) = lv;
}

// ---- fp32 transpose ----
__global__ void utrans_kernel(const float* __restrict__ src, int ldS, long sS,
                              float* __restrict__ dst, int ldD, long sD) {
    int b = blockIdx.z;
    src += (long)b * sS; dst += (long)b * sD;
    __shared__ float T[32][33];
    int r0 = blockIdx.y * 32, c0 = blockIdx.x * 32;
    int tid = threadIdx.x;
    int lrow = tid >> 3, lc4 = (tid & 7) * 4;
    float4 v = *(const float4*)(src + (long)(r0 + lrow) * ldS + c0 + lc4);
    T[lrow][lc4+0]=v.x; T[lrow][lc4+1]=v.y; T[lrow][lc4+2]=v.z; T[lrow][lc4+3]=v.w;
    __syncthreads();
    int wcol = tid >> 3, wr4 = (tid & 7) * 4;
    float4 o;
    o.x = T[wr4+0][wcol]; o.y = T[wr4+1][wcol]; o.z = T[wr4+2][wcol]; o.w = T[wr4+3][wcol];
    *(float4*)(dst + (long)(c0 + wcol) * ldD + r0 + wr4) = o;
}

// ---------------- batched blocked Cholesky (BK=16, 1024 threads, monolithic) ----------------

__global__ __launch_bounds__(1024) void chol_kernel(float* bufA, float* bufB) {
    int blk = blockIdx.x;                       // 0..31
    float* Ag = (blk < S_) ? (bufA + (long)blk * MM_) : (bufB + (long)(blk - S_) * MM_);
    __shared__ float P[33280];
    __shared__ float pan2[256 * 20];
    __shared__ float piv[16][18];
    float4* P4 = (float4*)P;
    int tid = threadIdx.x;
    int r = tid >> 2, s = tid & 3;
    int lane = tid & 63, wid = tid >> 6;
    int mg = r >> 2, tg = r & 3;
    int b4 = (mg + 1) * (2 * mg + tg);

    for (int i = wid; i < M_; i += 16) {
        int m = i >> 2, t4 = i & 3;
        int rb4 = (m + 1) * (2 * m + t4);
        if (lane <= m) P4[rb4 + lane] = ((const float4*)Ag)[i * 64 + lane];
    }
    __syncthreads();

    float preg[16];
    for (int p = 0; p < 16; p++) {
        int k0 = p << 4;
        int c0 = p << 2;
        #pragma unroll
        for (int rr = 0; rr < 4; rr++) {
            float4 v = make_float4(0.f, 0.f, 0.f, 0.f);
            if (r >= k0 && c0 + rr <= mg) v = P4[b4 + c0 + rr];
            preg[4 * rr + 0] = v.x; preg[4 * rr + 1] = v.y;
            preg[4 * rr + 2] = v.z; preg[4 * rr + 3] = v.w;
        }
        if (wid == p) {
            int dj = lane >> 2;
            float myinv = 0.f;
            #pragma unroll
            for (int j = 0; j < 16; j++) {
                float app = __shfl(preg[j], 4 * j, 64);
                float d = sqrtf(app);
                float inv = 1.0f / d;
                if (dj == j) { preg[j] = d; myinv = inv; }
                else if (dj > j) preg[j] *= inv;
                #pragma unroll
                for (int j2 = j + 1; j2 < 16; j2++) {
                    float Lj2 = __shfl(preg[j], 4 * j2, 64);
                    if (dj >= j2) preg[j2] -= preg[j] * Lj2;
                }
            }
            if (s == 0) {
                #pragma unroll
                for (int i = 0; i < 16; i++) piv[dj][i] = preg[i];
                piv[dj][16] = myinv;
            }
        }
        __syncthreads();
        if (r > k0 + 15) {
            float x[16];
            #pragma unroll
            for (int j = 0; j < 16; j++) {
                float acc = preg[j];
                #pragma unroll
                for (int i = 0; i < 16; i++)
                    if (i < j) acc -= x[i] * piv[j][i];
                x[j] = acc * piv[j][16];
            }
            #pragma unroll
            for (int j = 0; j < 16; j++) preg[j] = x[j];
        }
        if (r >= k0) {
            float4 pv = make_float4(preg[4 * s], preg[4 * s + 1],
                                    preg[4 * s + 2], preg[4 * s + 3]);
            *(float4*)&pan2[r * 20 + 4 * s] = pv;
            int c = c0 + s;
            if (c <= mg) P4[b4 + c] = pv;
        }
        __syncthreads();
        {
            int cs = tid >> 4;
            int j  = tid & 15;
            if (cs >= c0 + 4) {
                float4 q0[4], q1[4], q2[4], q3[4];
                #pragma unroll
                for (int e = 0; e < 4; e++) {
                    const float4* pr = (const float4*)&pan2[(4 * cs + e) * 20];
                    q0[e] = pr[0]; q1[e] = pr[1]; q2[e] = pr[2]; q3[e] = pr[3];
                }
                int rr = k0 + 16 + j;
                int rmin = 4 * cs;
                while (rr < rmin) rr += 16;
                for (; rr < 256; rr += 16) {
                    int mgr = rr >> 2, tgr = rr & 3;
                    int rb4 = (mgr + 1) * (2 * mgr + tgr);
                    const float4* ar = (const float4*)&pan2[rr * 20];
                    float4 a0 = ar[0], a1 = ar[1], a2 = ar[2], a3 = ar[3];
                    float rv[4];
                    *(float4*)rv = P4[rb4 + cs];
                    #pragma unroll
                    for (int e = 0; e < 4; e++) {
                        float acc;
                        acc  = a0.x*q0[e].x + a0.y*q0[e].y + a0.z*q0[e].z + a0.w*q0[e].w;
                        acc += a1.x*q1[e].x + a1.y*q1[e].y + a1.z*q1[e].z + a1.w*q1[e].w;
                        acc += a2.x*q2[e].x + a2.y*q2[e].y + a2.z*q2[e].z + a2.w*q2[e].w;
                        acc += a3.x*q3[e].x + a3.y*q3[e].y + a3.z*q3[e].z + a3.w*q3[e].w;
                        rv[e] -= acc;
                    }
                    P4[rb4 + cs] = *(float4*)rv;
                }
            }
        }
        __syncthreads();
    }

    for (int i = wid; i < M_; i += 16) {
        int m = i >> 2, t4 = i & 3;
        int rb4 = (m + 1) * (2 * m + t4);
        if (lane <= m) ((float4*)Ag)[i * 64 + lane] = P4[rb4 + lane];
    }
}

// ---------------- 64x64 diagonal-block triangular inverse ----------------

__global__ __launch_bounds__(256) void tri64inv_kernel(const float* W0,
                                                       u16* invh, u16* invl,
                                                       u16* Tth, u16* Ttl,
                                                       u16* TKrh, u16* TKrl) {
    int p = blockIdx.x;        // 0..3
    int mat = blockIdx.y;      // 0..31
    const float* W = W0 + (long)mat * MM_;
    int d0 = p * 64;
    __shared__ float X[64 * 65];
    __shared__ float pan[64 * 20];
    int tid = threadIdx.x;
    int c = tid & 63, q = tid >> 6;
    for (int idx = tid; idx < 64 * 65; idx += 256) X[idx] = 0.f;
    __syncthreads();
    if (q == 0) X[c * 65 + c] = 1.0f;
    for (int pp = 0; pp < 4; pp++) {
        int t0 = pp << 4;
        for (int idx = tid; idx < 64 * 4; idx += 256) {
            int k = idx >> 2, e = idx & 3;
            if (k >= t0)
                ((float4*)(pan + k * 20))[e] =
                    *(const float4*)(W + (long)(d0 + k) * 256 + d0 + t0 + 4 * e);
        }
        __syncthreads();
        if (q == pp) {
            float xr[16];
            #pragma unroll
            for (int j = 0; j < 16; j++) {
                float xv = X[(t0 + j) * 65 + c];
                #pragma unroll
                for (int i = 0; i < 16; i++)
                    if (i < j) xv -= pan[(t0 + j) * 20 + i] * xr[i];
                xv *= (1.0f / pan[(t0 + j) * 20 + j]);
                xr[j] = xv;
                X[(t0 + j) * 65 + c] = xv;
            }
        }
        __syncthreads();
        int kbeg = q << 4; if (kbeg < t0 + 16) kbeg = t0 + 16;
        int kend = (q << 4) + 16;
        if (kbeg < kend) {
            float xr[16];
            #pragma unroll
            for (int j = 0; j < 16; j++) xr[j] = X[(t0 + j) * 65 + c];
            for (int kk = kbeg; kk < kend; kk++) {
                float rv = X[kk * 65 + c];
                const float4* pr = (const float4*)&pan[kk * 20];
                float4 a = pr[0], b = pr[1], d = pr[2], e = pr[3];
                rv -= a.x * xr[0] + a.y * xr[1] + a.z * xr[2] + a.w * xr[3];
                rv -= b.x * xr[4] + b.y * xr[5] + b.z * xr[6] + b.w * xr[7];
                rv -= d.x * xr[8] + d.y * xr[9] + d.z * xr[10] + d.w * xr[11];
                rv -= e.x * xr[12] + e.y * xr[13] + e.z * xr[14] + e.w * xr[15];
                X[kk * 65 + c] = rv;
            }
        }
        __syncthreads();
    }
    for (int idx = tid; idx < 4096; idx += 256) {
        int r = idx >> 6, k = idx & 63;
        u16 h, l; cvt2(X[r * 65 + k], h, l);
        long io = (long)mat * 16384 + (long)p * 4096 + idx;
        invh[io] = h; invl[io] = l;
        long ro = (long)mat * MM_ + (long)(d0 + r) * 256 + d0 + k;
        TKrh[ro] = h; TKrl[ro] = l;
        long to = (long)mat * MM_ + (long)(d0 + k) * 256 + d0 + r;
        Tth[to] = h; Ttl[to] = l;
    }
}

// ---- pair-split strictly-lower panels of cholK into Lfull [256][256] pair ----
__global__ void lsplit_kernel(const float* __restrict__ W0,
                              u16* __restrict__ Lh, u16* __restrict__ Ll) {
    int p = blockIdx.x;        // 0..2
    int mat = blockIdx.y;      // 0..31
    const float* W = W0 + (long)mat * MM_;
    u16* dh = Lh + (long)mat * MM_;
    u16* dl = Ll + (long)mat * MM_;
    int d0 = 64 * p, nrows = 192 - d0;
    for (int idx = threadIdx.x; idx < nrows * 16; idx += 256) {
        int r = idx >> 4, c4 = idx & 15;
        long o = (long)(d0 + 64 + r) * 256 + d0 + 4 * c4;
        float4 v = *(const float4*)(W + o);
        u16 h0,h1,h2,h3,l0,l1,l2,l3;
        cvt2(v.x,h0,l0); cvt2(v.y,h1,l1); cvt2(v.z,h2,l2); cvt2(v.w,h3,l3);
        ushort4 hv = {h0,h1,h2,h3}, lv = {l0,l1,l2,l3};
        *(ushort4*)(dh + o) = hv;
        *(ushort4*)(dl + o) = lv;
    }
}

// ---------------- pair GEMM: C = alpha * A @ B^T(storage) + epilogue ----------------

struct PG {
    const u16 *Ah, *Al, *Bh, *Bl;
    float* C; u16 *Ch, *Cl, *ChT, *ClT;
    const float* D; const float* noise;
    const float* kff; float* vfacc;
    int M, N, K, lda, ldb, ldc, ldct, ldp;
    long sA, sB, sC, sP, sCt, sD, sVf, sNoise;
    float alpha, dcoef;
};

// 128x128 tile, 4 waves (K = 256)
template<int OF, int OP, int OPT, int ACCf, int Df, int ADDIf, int EFf, int VFf>
__global__ __launch_bounds__(256) void pgemm_k(PG p) {
    int bz = blockIdx.z;
    const u16* Agh = p.Ah + (long)bz * p.sA;
    const u16* Agl = p.Al + (long)bz * p.sA;
    const u16* Bgh = p.Bh + (long)bz * p.sB;
    const u16* Bgl = p.Bl + (long)bz * p.sB;
    int bm = blockIdx.y * 128, bn = blockIdx.x * 128;
    __shared__ __align__(16) u16 sAh[128][40];
    __shared__ __align__(16) u16 sAl[128][40];
    __shared__ __align__(16) u16 sBh[128][40];
    __shared__ __align__(16) u16 sBl[128][40];
    int tid = threadIdx.x, lane = tid & 63, wid = tid >> 6;
    int wm = (wid >> 1) * 64, wn = (wid & 1) * 64;
    int fr = lane & 15, ko = (lane >> 4) * 8;
    int kb = tid & 3, rw = tid >> 2;
    f32x4 acc[4][4];
    #pragma unroll
    for (int m = 0; m < 4; m++)
        #pragma unroll
        for (int n = 0; n < 4; n++)
            acc[m][n] = (f32x4){0.f, 0.f, 0.f, 0.f};

    for (int k0 = 0; k0 < 256; k0 += 32) {
        #define STG(SRC, LD, BASE, DST) \
            *(bf16x8*)&DST[rw][kb * 8] = \
                *(const bf16x8*)(SRC + (long)(BASE + rw) * LD + k0 + kb * 8); \
            *(bf16x8*)&DST[rw + 64][kb * 8] = \
                *(const bf16x8*)(SRC + (long)(BASE + rw + 64) * LD + k0 + kb * 8);
        STG(Agh, p.lda, bm, sAh)
        STG(Agl, p.lda, bm, sAl)
        STG(Bgh, p.ldb, bn, sBh)
        STG(Bgl, p.ldb, bn, sBl)
        #undef STG
        __syncthreads();
        bf16x8 ah[4], al[4], bh[4], bl[4];
        #pragma unroll
        for (int m = 0; m < 4; m++) {
            ah[m] = *(const bf16x8*)&sAh[wm + m * 16 + fr][ko];
            al[m] = *(const bf16x8*)&sAl[wm + m * 16 + fr][ko];
        }
        #pragma unroll
        for (int n = 0; n < 4; n++) {
            bh[n] = *(const bf16x8*)&sBh[wn + n * 16 + fr][ko];
            bl[n] = *(const bf16x8*)&sBl[wn + n * 16 + fr][ko];
        }
        #pragma unroll
        for (int m = 0; m < 4; m++)
            #pragma unroll
            for (int n = 0; n < 4; n++) {
                acc[m][n] = __builtin_amdgcn_mfma_f32_16x16x32_bf16(ah[m], bh[n], acc[m][n], 0, 0, 0);
                acc[m][n] = __builtin_amdgcn_mfma_f32_16x16x32_bf16(ah[m], bl[n], acc[m][n], 0, 0, 0);
                acc[m][n] = __builtin_amdgcn_mfma_f32_16x16x32_bf16(al[m], bh[n], acc[m][n], 0, 0, 0);
            }
        __syncthreads();
    }

    int rq = (lane >> 4) * 4;
    float rs[4][4];
    if (VFf) {
        #pragma unroll
        for (int m = 0; m < 4; m++)
            #pragma unroll
            for (int i = 0; i < 4; i++) rs[m][i] = 0.f;
    }
    #pragma unroll
    for (int m = 0; m < 4; m++) {
        int row0 = bm + wm + m * 16 + rq;
        #pragma unroll
        for (int n = 0; n < 4; n++) {
            int col = bn + wn + n * 16 + fr;
            float v[4];
            #pragma unroll
            for (int i = 0; i < 4; i++) {
                int r = row0 + i;
                float val = p.alpha * acc[m][n][i];
                if (Df)   val += p.dcoef * p.D[(long)bz * p.sD + (long)r * p.ldc + col];
                if (ACCf) val += p.C[(long)bz * p.sC + (long)r * p.ldc + col];
                if (ADDIf && r == col) val += 1.0f;
                if (EFf) {
                    float kf = p.kff[(long)bz * p.sVf + r];
                    float vq = p.vfacc[(long)bz * p.sVf + r];
                    val += sqrtf(fmaxf(kf - vq, 0.f)) *
                           p.noise[(long)bz * p.sNoise + (long)r * 256 + col];
                }
                v[i] = val;
                if (VFf) rs[m][i] += val * val;
            }
            if (OF) {
                #pragma unroll
                for (int i = 0; i < 4; i++)
                    p.C[(long)bz * p.sC + (long)(row0 + i) * p.ldc + col] = v[i];
            }
            if (OP) {
                #pragma unroll
                for (int i = 0; i < 4; i++) {
                    u16 h, l; cvt2(v[i], h, l);
                    p.Ch[(long)bz * p.sP + (long)(row0 + i) * p.ldc + col] = h;
                    p.Cl[(long)bz * p.sP + (long)(row0 + i) * p.ldc + col] = l;
                }
            }
            if (OPT) {
                u16 h0,h1,h2,h3,l0,l1,l2,l3;
                cvt2(v[0],h0,l0); cvt2(v[1],h1,l1); cvt2(v[2],h2,l2); cvt2(v[3],h3,l3);
                ushort4 hv = {h0,h1,h2,h3}, lv = {l0,l1,l2,l3};
                *(ushort4*)&p.ChT[(long)bz * p.sCt + (long)col * p.ldct + row0] = hv;
                *(ushort4*)&p.ClT[(long)bz * p.sCt + (long)col * p.ldct + row0] = lv;
            }
        }
    }
    if (VFf) {
        #pragma unroll
        for (int m = 0; m < 4; m++) {
            int row0 = bm + wm + m * 16 + rq;
            #pragma unroll
            for (int i = 0; i < 4; i++) {
                float t = rs[m][i];
                t += __shfl_xor(t, 1); t += __shfl_xor(t, 2);
                t += __shfl_xor(t, 4); t += __shfl_xor(t, 8);
                if (fr == 0)
                    atomicAdd(&p.vfacc[(long)bz * p.sVf + row0 + i], t);
            }
        }
    }
}

// 64x64 tile, 4 waves, runtime K (multiple of 32)
template<int OF, int OP, int OPT, int ACCf, int Df, int ADDIf>
__global__ __launch_bounds__(256) void pgemm64_k(PG p) {
    int bz = blockIdx.z;
    const u16* Agh = p.Ah + (long)bz * p.sA;
    const u16* Agl = p.Al + (long)bz * p.sA;
    const u16* Bgh = p.Bh + (long)bz * p.sB;
    const u16* Bgl = p.Bl + (long)bz * p.sB;
    int bm = blockIdx.y * 64, bn = blockIdx.x * 64;
    __shared__ __align__(16) u16 sAh[64][40];
    __shared__ __align__(16) u16 sAl[64][40];
    __shared__ __align__(16) u16 sBh[64][40];
    __shared__ __align__(16) u16 sBl[64][40];
    int tid = threadIdx.x, lane = tid & 63, wid = tid >> 6;
    int wm = (wid >> 1) * 32, wn = (wid & 1) * 32;
    int fr = lane & 15, ko = (lane >> 4) * 8;
    int kb = tid & 3, rw = tid >> 2;
    f32x4 acc[2][2];
    #pragma unroll
    for (int m = 0; m < 2; m++)
        #pragma unroll
        for (int n = 0; n < 2; n++)
            acc[m][n] = (f32x4){0.f, 0.f, 0.f, 0.f};

    for (int k0 = 0; k0 < p.K; k0 += 32) {
        *(bf16x8*)&sAh[rw][kb * 8] = *(const bf16x8*)(Agh + (long)(bm + rw) * p.lda + k0 + kb * 8);
        *(bf16x8*)&sAl[rw][kb * 8] = *(const bf16x8*)(Agl + (long)(bm + rw) * p.lda + k0 + kb * 8);
        *(bf16x8*)&sBh[rw][kb * 8] = *(const bf16x8*)(Bgh + (long)(bn + rw) * p.ldb + k0 + kb * 8);
        *(bf16x8*)&sBl[rw][kb * 8] = *(const bf16x8*)(Bgl + (long)(bn + rw) * p.ldb + k0 + kb * 8);
        __syncthreads();
        bf16x8 ah[2], al[2], bh[2], bl[2];
        #pragma unroll
        for (int m = 0; m < 2; m++) {
            ah[m] = *(const bf16x8*)&sAh[wm + m * 16 + fr][ko];
            al[m] = *(const bf16x8*)&sAl[wm + m * 16 + fr][ko];
        }
        #pragma unroll
        for (int n = 0; n < 2; n++) {
            bh[n] = *(const bf16x8*)&sBh[wn + n * 16 + fr][ko];
            bl[n] = *(const bf16x8*)&sBl[wn + n * 16 + fr][ko];
        }
        #pragma unroll
        for (int m = 0; m < 2; m++)
            #pragma unroll
            for (int n = 0; n < 2; n++) {
                acc[m][n] = __builtin_amdgcn_mfma_f32_16x16x32_bf16(ah[m], bh[n], acc[m][n], 0, 0, 0);
                acc[m][n] = __builtin_amdgcn_mfma_f32_16x16x32_bf16(ah[m], bl[n], acc[m][n], 0, 0, 0);
                acc[m][n] = __builtin_amdgcn_mfma_f32_16x16x32_bf16(al[m], bh[n], acc[m][n], 0, 0, 0);
            }
        __syncthreads();
    }

    int rq = (lane >> 4) * 4;
    #pragma unroll
    for (int m = 0; m < 2; m++) {
        int row0 = bm + wm + m * 16 + rq;
        #pragma unroll
        for (int n = 0; n < 2; n++) {
            int col = bn + wn + n * 16 + fr;
            float v[4];
            #pragma unroll
            for (int i = 0; i < 4; i++) {
                int r = row0 + i;
                float val = p.alpha * acc[m][n][i];
                if (Df)   val += p.dcoef * p.D[(long)bz * p.sD + (long)r * p.ldc + col];
                if (ACCf) val += p.C[(long)bz * p.sC + (long)r * p.ldc + col];
                if (ADDIf && r == col) val += 1.0f;
                v[i] = val;
            }
            if (OF) {
                #pragma unroll
                for (int i = 0; i < 4; i++)
                    p.C[(long)bz * p.sC + (long)(row0 + i) * p.ldc + col] = v[i];
            }
            if (OP) {
                #pragma unroll
                for (int i = 0; i < 4; i++) {
                    u16 h, l; cvt2(v[i], h, l);
                    p.Ch[(long)bz * p.sP + (long)(row0 + i) * p.ldp + col] = h;
                    p.Cl[(long)bz * p.sP + (long)(row0 + i) * p.ldp + col] = l;
                }
            }
            if (OPT) {
                u16 h0,h1,h2,h3,l0,l1,l2,l3;
                cvt2(v[0],h0,l0); cvt2(v[1],h1,l1); cvt2(v[2],h2,l2); cvt2(v[3],h3,l3);
                ushort4 hv = {h0,h1,h2,h3}, lv = {l0,l1,l2,l3};
                *(ushort4*)&p.ChT[(long)bz * p.sCt + (long)col * p.ldct + row0] = hv;
                *(ushort4*)&p.ClT[(long)bz * p.sCt + (long)col * p.ldct + row0] = lv;
            }
        }
    }
}

// ---------------- host ----------------

extern "C" void kernel_launch(void* const* d_in, const int* in_sizes, int n_in,
                              void* d_out, int out_size, void* d_ws, size_t ws_size,
                              hipStream_t stream) {
    const float* Kuu       = (const float*)d_in[0];
    const float* Kuf       = (const float*)d_in[1];
    const float* Kff       = (const float*)d_in[2];
    const float* Lloc      = (const float*)d_in[3];
    const float* Lscale    = (const float*)d_in[4];
    const float* u_param   = (const float*)d_in[5];
    const float* noise_inv = (const float*)d_in[6];
    const float* noise_L   = (const float*)d_in[7];
    const float* noise_f   = (const float*)d_in[8];
    float* out = (float*)d_out;
    float* ws  = (float*)d_ws;

    const long BIG = (long)S_ * MM_;     // 1,048,576 elements
    long off = 1024;
    float* part = ws + 16;

    #define PAIR(NAME, E) u16* NAME##h = (u16*)(ws + off); u16* NAME##l = NAME##h + (E); off += (E);
    PAIR(LS, 65536)
    PAIR(LtS, 65536)
    PAIR(upS, 65536)
    PAIR(W1S, 65536)
    float* UPT   = ws + off; off += 65536;
    float* VfAcc = ws + off; off += 65536;
    PAIR(KuuS, BIG)
    PAIR(ninvS, BIG)
    PAIR(nLS, BIG)
    float* cholK = ws + off; off += 2 * BIG;   // 32 matrices contiguous
    float* choll = cholK + BIG;
    PAIR(KuuLS, BIG)
    PAIR(KuuLtS, BIG)
    PAIR(TtS, 2 * BIG)             // T^T pair, 32 matrices
    PAIR(TKrS, 2 * BIG)            // T row-major pair, 32 matrices
    PAIR(G3TS, BIG)                // (KuuInv @ U)^T pair
    PAIR(lKlS, BIG)
    PAIR(invS, 524288)             // 32 mats x 4 panels x 64x64 D pair
    PAIR(LfS, 2 * BIG)             // L strictly-lower pair -> later KuuInv pair
    PAIR(StTS, 393216)             // S^T scratch pair, 32 x 192x64
    #undef PAIR

    u16* TKth = TtSh;                u16* TKtl = TtSl;
    u16* Tlth = TtSh + (long)S_ * MM_; u16* Tltl = TtSl + (long)S_ * MM_;
    u16* RHSTh   = KuuSh;            u16* RHSTl   = KuuSl;
    u16* UTph    = nLSh;             u16* UTpl    = nLSl;
    float* RHS1T = (float*)KuuLSh;
    u16* Sigmah  = KuuLtSh;          u16* Sigmal  = KuuLtSl;
    u16* lKlh    = lKlSh;            u16* lKll    = lKlSl;
    float* UTf32 = (float*)TtSh;     // Tt region free after trinv-loop consumers
    u16* Stmph   = Tlth;             u16* Stmpl   = Tltl;
    u16* KuuInvh = LfSh;             u16* KuuInvl = LfSl;   // alias after trinv loop

    long navail = (long)(ws_size / 4) - off;
    long nfc_l = navail / 4096;                 // only KufT pair per chunk
    int nfc = (int)((nfc_l / 128) * 128);
    if (nfc > NF_) nfc = NF_;
    if (nfc < 128) nfc = 128;
    long Ec = (long)S_ * nfc * 256;
    u16* KufTch = (u16*)(ws + off);      u16* KufTcl = KufTch + Ec;

    dim3 b256(256);

    hipMemsetAsync(TtSh, 0, (size_t)4 * 2 * BIG, stream);
    hipMemsetAsync(TKrSh, 0, (size_t)4 * 2 * BIG, stream);
    hipMemsetAsync(VfAcc, 0, (size_t)S_ * NF_ * sizeof(float), stream);

    max1_kernel<<<256, b256, 0, stream>>>(Kuu, S_ * MM_, part);
    max2_kernel<<<1, b256, 0, stream>>>(part, ws);
    prep_kernel<<<1, b256, 0, stream>>>(Lloc, Lscale, ws);

    splitjit_kernel<<<1024, b256, 0, stream>>>(Kuu, ws, KuuSh, KuuSl, cholK);
    psplit_kernel<<<64, b256, 0, stream>>>(Lloc, LSh, LSl, 65536, ws + 1);
    tsplit_kernel<<<dim3(8, 8, 1), b256, 0, stream>>>(Lloc, 256, 0, LtSh, LtSl, 256, 0, ws + 1);
    psplit_kernel<<<64, b256, 0, stream>>>(u_param, upSh, upSl, 65536, nullptr);
    psplit_kernel<<<1024, b256, 0, stream>>>(noise_inv, ninvSh, ninvSl, BIG, nullptr);
    psplit_kernel<<<1024, b256, 0, stream>>>(noise_L, nLSh, nLSl, BIG, nullptr);

    PG q;
    auto clr = [&]() {
        q = PG{};
        q.lda = 256; q.ldb = 256; q.ldc = 256; q.ldct = 256; q.ldp = 256;
        q.alpha = 1.f; q.dcoef = 1.f;
        q.M = 256; q.N = 256; q.K = 256;
    };
    dim3 g64(4, 4, S_);
    dim3 g64b1(4, 4, 1);

    // a. KuuL = Kuu @ L -> pair + pairT
    clr(); q.Ah = KuuSh; q.Al = KuuSl; q.sA = MM_;
    q.Bh = LtSh; q.Bl = LtSl; q.sB = 0;
    q.Ch = KuuLSh; q.Cl = KuuLSl; q.sP = MM_;
    q.ChT = KuuLtSh; q.ClT = KuuLtSl; q.sCt = MM_;
    pgemm64_k<0,1,1,0,0,0><<<g64, b256, 0, stream>>>(q);

    // b. choll = KuuL^T @ L + I -> fp32
    clr(); q.Ah = KuuLtSh; q.Al = KuuLtSl; q.sA = MM_;
    q.Bh = LtSh; q.Bl = LtSl; q.sB = 0;
    q.C = choll; q.sC = MM_;
    pgemm64_k<1,0,0,0,0,1><<<g64, b256, 0, stream>>>(q);

    chol_kernel<<<32, dim3(1024), 0, stream>>>(cholK, choll);

    // ---- block-recursive triangular inverse via MFMA ----
    tri64inv_kernel<<<dim3(4, 32), b256, 0, stream>>>(cholK, invSh, invSl,
                                                      TtSh, TtSl, TKrSh, TKrSl);
    lsplit_kernel<<<dim3(3, 32), b256, 0, stream>>>(cholK, LfSh, LfSl);

    for (int i = 1; i < 4; i++) {
        clr(); q.M = 64; q.N = 64 * i; q.K = 64 * i;
        q.Ah = LfSh + (long)64 * i * 256; q.Al = LfSl + (long)64 * i * 256;
        q.lda = 256; q.sA = MM_;
        q.Bh = TtSh; q.Bl = TtSl; q.ldb = 256; q.sB = MM_;
        q.ChT = StTSh; q.ClT = StTSl; q.ldct = 64; q.sCt = 12288;
        pgemm64_k<0,0,1,0,0,0><<<dim3(i, 1, 32), b256, 0, stream>>>(q);
        clr(); q.M = 64; q.N = 64 * i; q.K = 64;
        q.Ah = invSh + (long)i * 4096; q.Al = invSl + (long)i * 4096;
        q.lda = 64; q.sA = 16384;
        q.Bh = StTSh; q.Bl = StTSl; q.ldb = 64; q.sB = 12288;
        q.alpha = -1.f;
        q.Ch = TKrSh + (long)64 * i * 256; q.Cl = TKrSl + (long)64 * i * 256;
        q.ldp = 256; q.sP = MM_;
        q.ChT = TtSh + 64 * i; q.ClT = TtSl + 64 * i; q.ldct = 256; q.sCt = MM_;
        pgemm64_k<0,1,1,0,0,0><<<dim3(i, 1, 32), b256, 0, stream>>>(q);
    }

    // c2. KuuInv = TKt @ TKt^T (K set) -> pair (into LfS alias, free after loop)
    clr(); q.Ah = TKth; q.Al = TKtl; q.sA = MM_;
    q.Bh = TKth; q.Bl = TKtl; q.sB = MM_;
    q.Ch = KuuInvh; q.Cl = KuuInvl; q.sP = MM_;
    pgemm64_k<0,1,0,0,0,0><<<g64, b256, 0, stream>>>(q);

    // d. lKlpIi = Tlt @ Tlt^T -> pair
    clr(); q.Ah = Tlth; q.Al = Tltl; q.sA = MM_;
    q.Bh = Tlth; q.Bl = Tltl; q.sB = MM_;
    q.Ch = lKlh; q.Cl = lKll; q.sP = MM_;
    pgemm64_k<0,1,0,0,0,0><<<g64, b256, 0, stream>>>(q);

    // e. Stmp = KuuL @ lKlpIi -> pair
    clr(); q.Ah = KuuLSh; q.Al = KuuLSl; q.sA = MM_;
    q.Bh = lKlh; q.Bl = lKll; q.sB = MM_;
    q.Ch = Stmph; q.Cl = Stmpl; q.sP = MM_;
    pgemm64_k<0,1,0,0,0,0><<<g64, b256, 0, stream>>>(q);

    // f. Sigma = Kuu - Stmp @ KuuL^T -> pair
    clr(); q.Ah = Stmph; q.Al = Stmpl; q.sA = MM_;
    q.Bh = KuuLSh; q.Bl = KuuLSl; q.sB = MM_;
    q.Ch = Sigmah; q.Cl = Sigmal; q.sP = MM_;
    q.D = Kuu; q.sD = MM_; q.alpha = -1.f;
    pgemm64_k<0,1,0,0,1,0><<<g64, b256, 0, stream>>>(q);

    // g. W1 = up @ L -> pair (batch 1)
    clr(); q.Ah = upSh; q.Al = upSl; q.sA = 0;
    q.Bh = LtSh; q.Bl = LtSl; q.sB = 0;
    q.Ch = W1Sh; q.Cl = W1Sl; q.sP = 0;
    pgemm64_k<0,1,0,0,0,0><<<g64b1, b256, 0, stream>>>(q);

    // h. UPT = W1 @ L^T -> fp32 (batch 1)
    clr(); q.Ah = W1Sh; q.Al = W1Sl; q.sA = 0;
    q.Bh = LSh; q.Bl = LSl; q.sB = 0;
    q.C = UPT; q.sC = 0;
    pgemm64_k<1,0,0,0,0,0><<<g64b1, b256, 0, stream>>>(q);

    // i. RHS1T = ninv @ TK + UPT -> fp32
    clr(); q.Ah = ninvSh; q.Al = ninvSl; q.sA = 65536;
    q.Bh = TKth; q.Bl = TKtl; q.sB = MM_;
    q.C = RHS1T; q.sC = MM_;
    q.D = UPT; q.sD = 0;
    pgemm64_k<1,0,0,0,1,0><<<g64, b256, 0, stream>>>(q);

    // j. RHST = nL @ L^T + RHS1T -> pair
    clr(); q.Ah = nLSh; q.Al = nLSl; q.sA = 65536;
    q.Bh = LSh; q.Bl = LSl; q.sB = 0;
    q.C = RHS1T; q.sC = MM_;
    q.Ch = RHSTh; q.Cl = RHSTl; q.sP = MM_;
    pgemm64_k<0,1,0,1,0,0><<<g64, b256, 0, stream>>>(q);

    // k. UT = RHST @ Sigma -> fp32 + pair (overwrites Tt region)
    clr(); q.Ah = RHSTh; q.Al = RHSTl; q.sA = MM_;
    q.Bh = Sigmah; q.Bl = Sigmal; q.sB = MM_;
    q.C = UTf32; q.sC = MM_;
    q.Ch = UTph; q.Cl = UTpl; q.sP = MM_;
    pgemm64_k<1,1,0,0,0,0><<<g64, b256, 0, stream>>>(q);

    // G3T = UTp @ KuuInv -> pair  (G3 = KuuInv @ U, stored [o][m])
    clr(); q.Ah = UTph; q.Al = UTpl; q.sA = MM_;
    q.Bh = KuuInvh; q.Bl = KuuInvl; q.sB = MM_;
    q.Ch = G3TSh; q.Cl = G3TSl; q.sP = MM_;
    pgemm64_k<0,1,0,0,0,0><<<g64, b256, 0, stream>>>(q);

    // out rows 0..255
    utrans_kernel<<<dim3(8, 8, S_), b256, 0, stream>>>(UTf32, 256, MM_, out, OUT_, (long)ROWS_ * OUT_);

    for (int f0 = 0; f0 < NF_; f0 += nfc) {
        int w = NF_ - f0; if (w > nfc) w = nfc;
        tsplit_kernel<<<dim3(w / 32, 8, S_), b256, 0, stream>>>(
            Kuf + f0, NF_, (long)M_ * NF_, KufTch, KufTcl, 256, (long)w * 256, nullptr);
        // Vf-GEMM: H' = KufT @ TK^T, no output, only VfAcc row sums of squares
        clr(); q.M = w; q.N = 256;
        q.Ah = KufTch; q.Al = KufTcl; q.sA = (long)w * 256;
        q.Bh = TKrSh; q.Bl = TKrSl; q.sB = MM_;
        q.vfacc = VfAcc + f0; q.sVf = NF_;
        pgemm_k<0,0,0,0,0,0,0,1><<<dim3(2, w / 128, S_), b256, 0, stream>>>(q);
        // Ef-GEMM: out_f = KufT @ G3T^T + sqrt(Kff - VfAcc)*noise_f
        clr(); q.M = w; q.N = 256;
        q.Ah = KufTch; q.Al = KufTcl; q.sA = (long)w * 256;
        q.Bh = G3TSh; q.Bl = G3TSl; q.sB = MM_;
        q.C = out + (long)(M_ + f0) * OUT_; q.sC = (long)ROWS_ * OUT_;
        q.kff = Kff + f0; q.vfacc = VfAcc + f0; q.sVf = NF_;
        q.noise = noise_f + (long)f0 * OUT_; q.sNoise = (long)NF_ * OUT_;
        pgemm_k<1,0,0,0,0,0,1,0><<<dim3(2, w / 128, S_), b256, 0, stream>>>(q);
    }
}

// Round 17
// 441.112 us; speedup vs baseline: 1.2835x; 1.1230x over previous
//
#include <hip/hip_runtime.h>
#include <math.h>

#define S_ 16
#define M_ 256
#define NF_ 4096
#define OUT_ 256
#define ROWS_ (M_ + NF_)     // 4352
#define JITTER_ 1e-8f
#define MM_ (M_ * M_)        // 65536

typedef unsigned short u16;
typedef __attribute__((ext_vector_type(8))) short bf16x8;
typedef __attribute__((ext_vector_type(4))) float f32x4;

__device__ __forceinline__ void cvt2(float x, u16& h, u16& l) {
    unsigned xb = __float_as_uint(x);
    unsigned hb = (xb + 0x7fffu + ((xb >> 16) & 1u)) >> 16;
    float fh = __uint_as_float(hb << 16);
    float rr = x - fh;
    unsigned rb = __float_as_uint(rr);
    unsigned lb = (rb + 0x7fffu + ((rb >> 16) & 1u)) >> 16;
    h = (u16)hb; l = (u16)lb;
}

// ---------------- small prep kernels ----------------

__global__ void max1_kernel(const float* __restrict__ x, int n, float* part) {
    __shared__ float red[256];
    int tid = threadIdx.x;
    float m = -3.4e38f;
    for (int i = blockIdx.x * blockDim.x + tid; i < n; i += gridDim.x * blockDim.x)
        m = fmaxf(m, x[i]);
    red[tid] = m; __syncthreads();
    for (int s = 128; s > 0; s >>= 1) {
        if (tid < s) red[tid] = fmaxf(red[tid], red[tid + s]);
        __syncthreads();
    }
    if (tid == 0) part[blockIdx.x] = red[0];
}

// block 0: global max -> ws[0], ws[2]=jit ; block 1: L scale -> ws[1]
__global__ void max2prep_kernel(const float* part, const float* __restrict__ Lloc,
                                const float* __restrict__ Lscale, float* ws) {
    __shared__ float red[256];
    int tid = threadIdx.x;
    if (blockIdx.x == 0) {
        red[tid] = part[tid]; __syncthreads();
        for (int s = 128; s > 0; s >>= 1) {
            if (tid < s) red[tid] = fmaxf(red[tid], red[tid + s]);
            __syncthreads();
        }
        if (tid == 0) { ws[0] = red[0]; ws[2] = JITTER_ * red[0]; }
    } else {
        red[tid] = Lloc[tid * M_ + tid];
        __syncthreads();
        for (int s = 128; s > 0; s >>= 1) {
            if (tid < s) red[tid] += red[tid + s];
            __syncthreads();
        }
        if (tid == 0) {
            float norm = red[0] / (float)M_;
            ws[1] = expf(Lscale[0]) / norm;
        }
    }
}

// ---- plain split ----
__global__ void psplit_kernel(const float* __restrict__ src, u16* __restrict__ h,
                              u16* __restrict__ l, long n, const float* scaleptr) {
    float sc = scaleptr ? scaleptr[0] : 1.0f;
    long stride = (long)gridDim.x * blockDim.x * 4;
    for (long i = ((long)blockIdx.x * blockDim.x + threadIdx.x) * 4; i < n; i += stride) {
        float4 v = *(const float4*)(src + i);
        u16 h0,h1,h2,h3,l0,l1,l2,l3;
        cvt2(v.x*sc,h0,l0); cvt2(v.y*sc,h1,l1); cvt2(v.z*sc,h2,l2); cvt2(v.w*sc,h3,l3);
        ushort4 hv = {h0,h1,h2,h3}, lv = {l0,l1,l2,l3};
        *(ushort4*)(h + i) = hv;
        *(ushort4*)(l + i) = lv;
    }
}

// ---- fused Kuu split + jittered copy for Cholesky ----
__global__ void splitjit_kernel(const float* __restrict__ Kuu, const float* __restrict__ ws,
                                u16* __restrict__ h, u16* __restrict__ l,
                                float* __restrict__ dst) {
    float jit = ws[2];
    long i = ((long)blockIdx.x * blockDim.x + threadIdx.x) * 4;
    if (i < (long)S_ * MM_) {
        float4 v = *(const float4*)(Kuu + i);
        u16 h0,h1,h2,h3,l0,l1,l2,l3;
        cvt2(v.x,h0,l0); cvt2(v.y,h1,l1); cvt2(v.z,h2,l2); cvt2(v.w,h3,l3);
        ushort4 hv = {h0,h1,h2,h3}, lv = {l0,l1,l2,l3};
        *(ushort4*)(h + i) = hv;
        *(ushort4*)(l + i) = lv;
        int rc = (int)(i & 65535);
        int r = rc >> 8, c0 = rc & 255;
        if (r >= c0 && r < c0 + 4) ((float*)&v)[r - c0] += jit;
        *(float4*)(dst + i) = v;
    }
}

// ---- transpose split (used for L^T and tail chunks beyond chunk 0) ----
__global__ void tsplit_kernel(const float* __restrict__ src, int ldS, long sS,
                              u16* __restrict__ h, u16* __restrict__ l, int ldD, long sD,
                              const float* scaleptr) {
    int b = blockIdx.z;
    src += (long)b * sS; h += (long)b * sD; l += (long)b * sD;
    __shared__ float T[32][33];
    int r0 = blockIdx.y * 32, c0 = blockIdx.x * 32;
    float sc = scaleptr ? scaleptr[0] : 1.0f;
    int tid = threadIdx.x;
    int lrow = tid >> 3, lc4 = (tid & 7) * 4;
    float4 v = *(const float4*)(src + (long)(r0 + lrow) * ldS + c0 + lc4);
    T[lrow][lc4 + 0] = v.x * sc; T[lrow][lc4 + 1] = v.y * sc;
    T[lrow][lc4 + 2] = v.z * sc; T[lrow][lc4 + 3] = v.w * sc;
    __syncthreads();
    int wcol = tid >> 3, wr4 = (tid & 7) * 4;
    u16 h0,h1,h2,h3,l0,l1,l2,l3;
    cvt2(T[wr4+0][wcol],h0,l0); cvt2(T[wr4+1][wcol],h1,l1);
    cvt2(T[wr4+2][wcol],h2,l2); cvt2(T[wr4+3][wcol],h3,l3);
    ushort4 hv = {h0,h1,h2,h3}, lv = {l0,l1,l2,l3};
    *(ushort4*)(h + (long)(c0 + wcol) * ldD + r0 + wr4) = hv;
    *(ushort4*)(l + (long)(c0 + wcol) * ldD + r0 + wr4) = lv;
}

__device__ __forceinline__ void psplit_dev(const float* __restrict__ src, u16* __restrict__ h,
                                           u16* __restrict__ l, long n, long b0, long stp) {
    for (long i = b0 * 4; i < n; i += stp * 4) {
        float4 v = *(const float4*)(src + i);
        u16 h0,h1,h2,h3,l0,l1,l2,l3;
        cvt2(v.x,h0,l0); cvt2(v.y,h1,l1); cvt2(v.z,h2,l2); cvt2(v.w,h3,l3);
        ushort4 hv = {h0,h1,h2,h3}, lv = {l0,l1,l2,l3};
        *(ushort4*)(h + i) = hv;
        *(ushort4*)(l + i) = lv;
    }
}

// ---------------- MEGA: chol (blocks 0..31) + independent prep (blocks 32+) ----------------

struct MAux {
    const float* Kuf; u16 *KTh, *KTl; int w0;
    const float* ninv; u16 *nih, *nil;
    const float* nLp;  u16 *nLh2, *nLl2;
    const float* up;   u16 *uph2, *upl2;
    float* z1; long z1n;       // Tt+TKr zero region (floats)
    float* z2; long z2n;       // VfAcc
};

__global__ __launch_bounds__(1024) void megachol_kernel(float* bufA, float* bufB, MAux ax) {
    __shared__ float P[33280];
    __shared__ float pan2[256 * 20];
    __shared__ float piv[16][18];

    if (blockIdx.x < 32) {
        // -------- chol body (unchanged, blk = blockIdx.x) --------
        int blk = blockIdx.x;
        float* Ag = (blk < S_) ? (bufA + (long)blk * MM_) : (bufB + (long)(blk - S_) * MM_);
        float4* P4 = (float4*)P;
        int tid = threadIdx.x;
        int r = tid >> 2, s = tid & 3;
        int lane = tid & 63, wid = tid >> 6;
        int mg = r >> 2, tg = r & 3;
        int b4 = (mg + 1) * (2 * mg + tg);

        for (int i = wid; i < M_; i += 16) {
            int m = i >> 2, t4 = i & 3;
            int rb4 = (m + 1) * (2 * m + t4);
            if (lane <= m) P4[rb4 + lane] = ((const float4*)Ag)[i * 64 + lane];
        }
        __syncthreads();

        float preg[16];
        for (int p = 0; p < 16; p++) {
            int k0 = p << 4;
            int c0 = p << 2;
            #pragma unroll
            for (int rr = 0; rr < 4; rr++) {
                float4 v = make_float4(0.f, 0.f, 0.f, 0.f);
                if (r >= k0 && c0 + rr <= mg) v = P4[b4 + c0 + rr];
                preg[4 * rr + 0] = v.x; preg[4 * rr + 1] = v.y;
                preg[4 * rr + 2] = v.z; preg[4 * rr + 3] = v.w;
            }
            if (wid == p) {
                int dj = lane >> 2;
                float myinv = 0.f;
                #pragma unroll
                for (int j = 0; j < 16; j++) {
                    float app = __shfl(preg[j], 4 * j, 64);
                    float d = sqrtf(app);
                    float inv = 1.0f / d;
                    if (dj == j) { preg[j] = d; myinv = inv; }
                    else if (dj > j) preg[j] *= inv;
                    #pragma unroll
                    for (int j2 = j + 1; j2 < 16; j2++) {
                        float Lj2 = __shfl(preg[j], 4 * j2, 64);
                        if (dj >= j2) preg[j2] -= preg[j] * Lj2;
                    }
                }
                if (s == 0) {
                    #pragma unroll
                    for (int i = 0; i < 16; i++) piv[dj][i] = preg[i];
                    piv[dj][16] = myinv;
                }
            }
            __syncthreads();
            if (r > k0 + 15) {
                float x[16];
                #pragma unroll
                for (int j = 0; j < 16; j++) {
                    float acc = preg[j];
                    #pragma unroll
                    for (int i = 0; i < 16; i++)
                        if (i < j) acc -= x[i] * piv[j][i];
                    x[j] = acc * piv[j][16];
                }
                #pragma unroll
                for (int j = 0; j < 16; j++) preg[j] = x[j];
            }
            if (r >= k0) {
                float4 pv = make_float4(preg[4 * s], preg[4 * s + 1],
                                        preg[4 * s + 2], preg[4 * s + 3]);
                *(float4*)&pan2[r * 20 + 4 * s] = pv;
                int c = c0 + s;
                if (c <= mg) P4[b4 + c] = pv;
            }
            __syncthreads();
            {
                int cs = tid >> 4;
                int j  = tid & 15;
                if (cs >= c0 + 4) {
                    float4 q0[4], q1[4], q2[4], q3[4];
                    #pragma unroll
                    for (int e = 0; e < 4; e++) {
                        const float4* pr = (const float4*)&pan2[(4 * cs + e) * 20];
                        q0[e] = pr[0]; q1[e] = pr[1]; q2[e] = pr[2]; q3[e] = pr[3];
                    }
                    int rr = k0 + 16 + j;
                    int rmin = 4 * cs;
                    while (rr < rmin) rr += 16;
                    for (; rr < 256; rr += 16) {
                        int mgr = rr >> 2, tgr = rr & 3;
                        int rb4 = (mgr + 1) * (2 * mgr + tgr);
                        const float4* ar = (const float4*)&pan2[rr * 20];
                        float4 a0 = ar[0], a1 = ar[1], a2 = ar[2], a3 = ar[3];
                        float rv[4];
                        *(float4*)rv = P4[rb4 + cs];
                        #pragma unroll
                        for (int e = 0; e < 4; e++) {
                            float acc;
                            acc  = a0.x*q0[e].x + a0.y*q0[e].y + a0.z*q0[e].z + a0.w*q0[e].w;
                            acc += a1.x*q1[e].x + a1.y*q1[e].y + a1.z*q1[e].z + a1.w*q1[e].w;
                            acc += a2.x*q2[e].x + a2.y*q2[e].y + a2.z*q2[e].z + a2.w*q2[e].w;
                            acc += a3.x*q3[e].x + a3.y*q3[e].y + a3.z*q3[e].z + a3.w*q3[e].w;
                            rv[e] -= acc;
                        }
                        P4[rb4 + cs] = *(float4*)rv;
                    }
                }
            }
            __syncthreads();
        }

        for (int i = wid; i < M_; i += 16) {
            int m = i >> 2, t4 = i & 3;
            int rb4 = (m + 1) * (2 * m + t4);
            if (lane <= m) ((float4*)Ag)[i * 64 + lane] = P4[rb4 + lane];
        }
        return;
    }

    // -------- aux path: independent prep work on idle CUs --------
    int ab = blockIdx.x - 32, NA = gridDim.x - 32;
    int tid = threadIdx.x;
    long b0 = (long)ab * 1024 + tid, stp = (long)NA * 1024;
    float4 z = make_float4(0.f, 0.f, 0.f, 0.f);
    long n4 = ax.z1n >> 2;
    for (long i = b0; i < n4; i += stp) ((float4*)ax.z1)[i] = z;
    long m4 = ax.z2n >> 2;
    for (long i = b0; i < m4; i += stp) ((float4*)ax.z2)[i] = z;
    psplit_dev(ax.ninv, ax.nih, ax.nil, (long)S_ * MM_, b0, stp);
    psplit_dev(ax.nLp, ax.nLh2, ax.nLl2, (long)S_ * MM_, b0, stp);
    psplit_dev(ax.up, ax.uph2, ax.upl2, 65536, b0, stp);

    // tsplit of Kuf chunk 0: tiles decoded (cx, cy, batch), 4 tiles/block (one per 256-thr group)
    int grp = tid >> 8, t = tid & 255;
    float* Tls = P + grp * 1056;            // 32*33 floats per group
    int nx = ax.w0 >> 5;
    int ntile = nx * 8 * S_;
    int per = NA * 4;
    int iters = (ntile + per - 1) / per;
    long sS = (long)M_ * NF_, sD = (long)ax.w0 * 256;
    for (int it = 0; it < iters; it++) {
        int tile = ab * 4 + grp + it * per;
        bool ok = tile < ntile;
        int r0 = 0, c0 = 0, b = 0;
        if (ok) {
            int cx = tile % nx; int rest = tile / nx;
            int cy = rest & 7; b = rest >> 3;
            r0 = cy * 32; c0 = cx * 32;
        }
        if (ok) {
            int lrow = t >> 3, lc4 = (t & 7) * 4;
            float4 v = *(const float4*)(ax.Kuf + (long)b * sS + (long)(r0 + lrow) * NF_ + c0 + lc4);
            Tls[lrow * 33 + lc4 + 0] = v.x; Tls[lrow * 33 + lc4 + 1] = v.y;
            Tls[lrow * 33 + lc4 + 2] = v.z; Tls[lrow * 33 + lc4 + 3] = v.w;
        }
        __syncthreads();
        if (ok) {
            int wcol = t >> 3, wr4 = (t & 7) * 4;
            u16 h0,h1,h2,h3,l0,l1,l2,l3;
            cvt2(Tls[(wr4+0)*33+wcol],h0,l0); cvt2(Tls[(wr4+1)*33+wcol],h1,l1);
            cvt2(Tls[(wr4+2)*33+wcol],h2,l2); cvt2(Tls[(wr4+3)*33+wcol],h3,l3);
            ushort4 hv = {h0,h1,h2,h3}, lv = {l0,l1,l2,l3};
            long o = (long)b * sD + (long)(c0 + wcol) * 256 + r0 + wr4;
            *(ushort4*)(ax.KTh + o) = hv;
            *(ushort4*)(ax.KTl + o) = lv;
        }
        __syncthreads();
    }
}

// ---------------- 64x64 diagonal-block triangular inverse ----------------

__global__ __launch_bounds__(256) void tri64inv_kernel(const float* W0,
                                                       u16* invh, u16* invl,
                                                       u16* Tth, u16* Ttl,
                                                       u16* TKrh, u16* TKrl) {
    int p = blockIdx.x;        // 0..3
    int mat = blockIdx.y;      // 0..31
    const float* W = W0 + (long)mat * MM_;
    int d0 = p * 64;
    __shared__ float X[64 * 65];
    __shared__ float pan[64 * 20];
    int tid = threadIdx.x;
    int c = tid & 63, q = tid >> 6;
    for (int idx = tid; idx < 64 * 65; idx += 256) X[idx] = 0.f;
    __syncthreads();
    if (q == 0) X[c * 65 + c] = 1.0f;
    for (int pp = 0; pp < 4; pp++) {
        int t0 = pp << 4;
        for (int idx = tid; idx < 64 * 4; idx += 256) {
            int k = idx >> 2, e = idx & 3;
            if (k >= t0)
                ((float4*)(pan + k * 20))[e] =
                    *(const float4*)(W + (long)(d0 + k) * 256 + d0 + t0 + 4 * e);
        }
        __syncthreads();
        if (q == pp) {
            float xr[16];
            #pragma unroll
            for (int j = 0; j < 16; j++) {
                float xv = X[(t0 + j) * 65 + c];
                #pragma unroll
                for (int i = 0; i < 16; i++)
                    if (i < j) xv -= pan[(t0 + j) * 20 + i] * xr[i];
                xv *= (1.0f / pan[(t0 + j) * 20 + j]);
                xr[j] = xv;
                X[(t0 + j) * 65 + c] = xv;
            }
        }
        __syncthreads();
        int kbeg = q << 4; if (kbeg < t0 + 16) kbeg = t0 + 16;
        int kend = (q << 4) + 16;
        if (kbeg < kend) {
            float xr[16];
            #pragma unroll
            for (int j = 0; j < 16; j++) xr[j] = X[(t0 + j) * 65 + c];
            for (int kk = kbeg; kk < kend; kk++) {
                float rv = X[kk * 65 + c];
                const float4* pr = (const float4*)&pan[kk * 20];
                float4 a = pr[0], b = pr[1], d = pr[2], e = pr[3];
                rv -= a.x * xr[0] + a.y * xr[1] + a.z * xr[2] + a.w * xr[3];
                rv -= b.x * xr[4] + b.y * xr[5] + b.z * xr[6] + b.w * xr[7];
                rv -= d.x * xr[8] + d.y * xr[9] + d.z * xr[10] + d.w * xr[11];
                rv -= e.x * xr[12] + e.y * xr[13] + e.z * xr[14] + e.w * xr[15];
                X[kk * 65 + c] = rv;
            }
        }
        __syncthreads();
    }
    for (int idx = tid; idx < 4096; idx += 256) {
        int r = idx >> 6, k = idx & 63;
        u16 h, l; cvt2(X[r * 65 + k], h, l);
        long io = (long)mat * 16384 + (long)p * 4096 + idx;
        invh[io] = h; invl[io] = l;
        long ro = (long)mat * MM_ + (long)(d0 + r) * 256 + d0 + k;
        TKrh[ro] = h; TKrl[ro] = l;
        long to = (long)mat * MM_ + (long)(d0 + k) * 256 + d0 + r;
        Tth[to] = h; Ttl[to] = l;
    }
}

// ---- pair-split strictly-lower panels of cholK into Lfull [256][256] pair ----
__global__ void lsplit_kernel(const float* __restrict__ W0,
                              u16* __restrict__ Lh, u16* __restrict__ Ll) {
    int p = blockIdx.x;        // 0..2
    int mat = blockIdx.y;      // 0..31
    const float* W = W0 + (long)mat * MM_;
    u16* dh = Lh + (long)mat * MM_;
    u16* dl = Ll + (long)mat * MM_;
    int d0 = 64 * p, nrows = 192 - d0;
    for (int idx = threadIdx.x; idx < nrows * 16; idx += 256) {
        int r = idx >> 4, c4 = idx & 15;
        long o = (long)(d0 + 64 + r) * 256 + d0 + 4 * c4;
        float4 v = *(const float4*)(W + o);
        u16 h0,h1,h2,h3,l0,l1,l2,l3;
        cvt2(v.x,h0,l0); cvt2(v.y,h1,l1); cvt2(v.z,h2,l2); cvt2(v.w,h3,l3);
        ushort4 hv = {h0,h1,h2,h3}, lv = {l0,l1,l2,l3};
        *(ushort4*)(dh + o) = hv;
        *(ushort4*)(dl + o) = lv;
    }
}

// ---------------- pair GEMM: C = alpha * A @ B^T(storage) + epilogue ----------------

struct PG {
    const u16 *Ah, *Al, *Bh, *Bl;
    float* C; u16 *Ch, *Cl, *ChT, *ClT;
    float* CF;                      // transposed fp32 out
    const float* D; const float* noise;
    const float* kff; float* vfacc;
    int M, N, K, lda, ldb, ldc, ldct, ldp;
    long sA, sB, sC, sP, sCt, sD, sVf, sNoise, sCF;
    float alpha, dcoef;
};

// 128x128 tile, 4 waves (K = 256)
template<int OF, int OP, int OPT, int ACCf, int Df, int ADDIf, int EFf, int VFf>
__global__ __launch_bounds__(256) void pgemm_k(PG p) {
    int bz = blockIdx.z;
    const u16* Agh = p.Ah + (long)bz * p.sA;
    const u16* Agl = p.Al + (long)bz * p.sA;
    const u16* Bgh = p.Bh + (long)bz * p.sB;
    const u16* Bgl = p.Bl + (long)bz * p.sB;
    int bm = blockIdx.y * 128, bn = blockIdx.x * 128;
    __shared__ __align__(16) u16 sAh[128][40];
    __shared__ __align__(16) u16 sAl[128][40];
    __shared__ __align__(16) u16 sBh[128][40];
    __shared__ __align__(16) u16 sBl[128][40];
    int tid = threadIdx.x, lane = tid & 63, wid = tid >> 6;
    int wm = (wid >> 1) * 64, wn = (wid & 1) * 64;
    int fr = lane & 15, ko = (lane >> 4) * 8;
    int kb = tid & 3, rw = tid >> 2;
    f32x4 acc[4][4];
    #pragma unroll
    for (int m = 0; m < 4; m++)
        #pragma unroll
        for (int n = 0; n < 4; n++)
            acc[m][n] = (f32x4){0.f, 0.f, 0.f, 0.f};

    for (int k0 = 0; k0 < 256; k0 += 32) {
        #define STG(SRC, LD, BASE, DST) \
            *(bf16x8*)&DST[rw][kb * 8] = \
                *(const bf16x8*)(SRC + (long)(BASE + rw) * LD + k0 + kb * 8); \
            *(bf16x8*)&DST[rw + 64][kb * 8] = \
                *(const bf16x8*)(SRC + (long)(BASE + rw + 64) * LD + k0 + kb * 8);
        STG(Agh, p.lda, bm, sAh)
        STG(Agl, p.lda, bm, sAl)
        STG(Bgh, p.ldb, bn, sBh)
        STG(Bgl, p.ldb, bn, sBl)
        #undef STG
        __syncthreads();
        bf16x8 ah[4], al[4], bh[4], bl[4];
        #pragma unroll
        for (int m = 0; m < 4; m++) {
            ah[m] = *(const bf16x8*)&sAh[wm + m * 16 + fr][ko];
            al[m] = *(const bf16x8*)&sAl[wm + m * 16 + fr][ko];
        }
        #pragma unroll
        for (int n = 0; n < 4; n++) {
            bh[n] = *(const bf16x8*)&sBh[wn + n * 16 + fr][ko];
            bl[n] = *(const bf16x8*)&sBl[wn + n * 16 + fr][ko];
        }
        #pragma unroll
        for (int m = 0; m < 4; m++)
            #pragma unroll
            for (int n = 0; n < 4; n++) {
                acc[m][n] = __builtin_amdgcn_mfma_f32_16x16x32_bf16(ah[m], bh[n], acc[m][n], 0, 0, 0);
                acc[m][n] = __builtin_amdgcn_mfma_f32_16x16x32_bf16(ah[m], bl[n], acc[m][n], 0, 0, 0);
                acc[m][n] = __builtin_amdgcn_mfma_f32_16x16x32_bf16(al[m], bh[n], acc[m][n], 0, 0, 0);
            }
        __syncthreads();
    }

    int rq = (lane >> 4) * 4;
    float rs[4][4];
    if (VFf) {
        #pragma unroll
        for (int m = 0; m < 4; m++)
            #pragma unroll
            for (int i = 0; i < 4; i++) rs[m][i] = 0.f;
    }
    #pragma unroll
    for (int m = 0; m < 4; m++) {
        int row0 = bm + wm + m * 16 + rq;
        #pragma unroll
        for (int n = 0; n < 4; n++) {
            int col = bn + wn + n * 16 + fr;
            float v[4];
            #pragma unroll
            for (int i = 0; i < 4; i++) {
                int r = row0 + i;
                float val = p.alpha * acc[m][n][i];
                if (Df)   val += p.dcoef * p.D[(long)bz * p.sD + (long)r * p.ldc + col];
                if (ACCf) val += p.C[(long)bz * p.sC + (long)r * p.ldc + col];
                if (ADDIf && r == col) val += 1.0f;
                if (EFf) {
                    float kf = p.kff[(long)bz * p.sVf + r];
                    float vq = p.vfacc[(long)bz * p.sVf + r];
                    val += sqrtf(fmaxf(kf - vq, 0.f)) *
                           p.noise[(long)bz * p.sNoise + (long)r * 256 + col];
                }
                v[i] = val;
                if (VFf) rs[m][i] += val * val;
            }
            if (OF) {
                #pragma unroll
                for (int i = 0; i < 4; i++)
                    p.C[(long)bz * p.sC + (long)(row0 + i) * p.ldc + col] = v[i];
            }
            if (OP) {
                #pragma unroll
                for (int i = 0; i < 4; i++) {
                    u16 h, l; cvt2(v[i], h, l);
                    p.Ch[(long)bz * p.sP + (long)(row0 + i) * p.ldc + col] = h;
                    p.Cl[(long)bz * p.sP + (long)(row0 + i) * p.ldc + col] = l;
                }
            }
            if (OPT) {
                u16 h0,h1,h2,h3,l0,l1,l2,l3;
                cvt2(v[0],h0,l0); cvt2(v[1],h1,l1); cvt2(v[2],h2,l2); cvt2(v[3],h3,l3);
                ushort4 hv = {h0,h1,h2,h3}, lv = {l0,l1,l2,l3};
                *(ushort4*)&p.ChT[(long)bz * p.sCt + (long)col * p.ldct + row0] = hv;
                *(ushort4*)&p.ClT[(long)bz * p.sCt + (long)col * p.ldct + row0] = lv;
            }
        }
    }
    if (VFf) {
        #pragma unroll
        for (int m = 0; m < 4; m++) {
            int row0 = bm + wm + m * 16 + rq;
            #pragma unroll
            for (int i = 0; i < 4; i++) {
                float t = rs[m][i];
                t += __shfl_xor(t, 1); t += __shfl_xor(t, 2);
                t += __shfl_xor(t, 4); t += __shfl_xor(t, 8);
                if (fr == 0)
                    atomicAdd(&p.vfacc[(long)bz * p.sVf + row0 + i], t);
            }
        }
    }
}

// 64x64 tile, 4 waves, runtime K (multiple of 32); OFT = transposed fp32 out
template<int OF, int OP, int OPT, int OFT, int ACCf, int Df, int ADDIf>
__global__ __launch_bounds__(256) void pgemm64_k(PG p) {
    int bz = blockIdx.z;
    const u16* Agh = p.Ah + (long)bz * p.sA;
    const u16* Agl = p.Al + (long)bz * p.sA;
    const u16* Bgh = p.Bh + (long)bz * p.sB;
    const u16* Bgl = p.Bl + (long)bz * p.sB;
    int bm = blockIdx.y * 64, bn = blockIdx.x * 64;
    __shared__ __align__(16) u16 sAh[64][40];
    __shared__ __align__(16) u16 sAl[64][40];
    __shared__ __align__(16) u16 sBh[64][40];
    __shared__ __align__(16) u16 sBl[64][40];
    int tid = threadIdx.x, lane = tid & 63, wid = tid >> 6;
    int wm = (wid >> 1) * 32, wn = (wid & 1) * 32;
    int fr = lane & 15, ko = (lane >> 4) * 8;
    int kb = tid & 3, rw = tid >> 2;
    f32x4 acc[2][2];
    #pragma unroll
    for (int m = 0; m < 2; m++)
        #pragma unroll
        for (int n = 0; n < 2; n++)
            acc[m][n] = (f32x4){0.f, 0.f, 0.f, 0.f};

    for (int k0 = 0; k0 < p.K; k0 += 32) {
        *(bf16x8*)&sAh[rw][kb * 8] = *(const bf16x8*)(Agh + (long)(bm + rw) * p.lda + k0 + kb * 8);
        *(bf16x8*)&sAl[rw][kb * 8] = *(const bf16x8*)(Agl + (long)(bm + rw) * p.lda + k0 + kb * 8);
        *(bf16x8*)&sBh[rw][kb * 8] = *(const bf16x8*)(Bgh + (long)(bn + rw) * p.ldb + k0 + kb * 8);
        *(bf16x8*)&sBl[rw][kb * 8] = *(const bf16x8*)(Bgl + (long)(bn + rw) * p.ldb + k0 + kb * 8);
        __syncthreads();
        bf16x8 ah[2], al[2], bh[2], bl[2];
        #pragma unroll
        for (int m = 0; m < 2; m++) {
            ah[m] = *(const bf16x8*)&sAh[wm + m * 16 + fr][ko];
            al[m] = *(const bf16x8*)&sAl[wm + m * 16 + fr][ko];
        }
        #pragma unroll
        for (int n = 0; n < 2; n++) {
            bh[n] = *(const bf16x8*)&sBh[wn + n * 16 + fr][ko];
            bl[n] = *(const bf16x8*)&sBl[wn + n * 16 + fr][ko];
        }
        #pragma unroll
        for (int m = 0; m < 2; m++)
            #pragma unroll
            for (int n = 0; n < 2; n++) {
                acc[m][n] = __builtin_amdgcn_mfma_f32_16x16x32_bf16(ah[m], bh[n], acc[m][n], 0, 0, 0);
                acc[m][n] = __builtin_amdgcn_mfma_f32_16x16x32_bf16(ah[m], bl[n], acc[m][n], 0, 0, 0);
                acc[m][n] = __builtin_amdgcn_mfma_f32_16x16x32_bf16(al[m], bh[n], acc[m][n], 0, 0, 0);
            }
        __syncthreads();
    }

    int rq = (lane >> 4) * 4;
    #pragma unroll
    for (int m = 0; m < 2; m++) {
        int row0 = bm + wm + m * 16 + rq;
        #pragma unroll
        for (int n = 0; n < 2; n++) {
            int col = bn + wn + n * 16 + fr;
            float v[4];
            #pragma unroll
            for (int i = 0; i < 4; i++) {
                int r = row0 + i;
                float val = p.alpha * acc[m][n][i];
                if (Df)   val += p.dcoef * p.D[(long)bz * p.sD + (long)r * p.ldc + col];
                if (ACCf) val += p.C[(long)bz * p.sC + (long)r * p.ldc + col];
                if (ADDIf && r == col) val += 1.0f;
                v[i] = val;
            }
            if (OF) {
                #pragma unroll
                for (int i = 0; i < 4; i++)
                    p.C[(long)bz * p.sC + (long)(row0 + i) * p.ldc + col] = v[i];
            }
            if (OP) {
                #pragma unroll
                for (int i = 0; i < 4; i++) {
                    u16 h, l; cvt2(v[i], h, l);
                    p.Ch[(long)bz * p.sP + (long)(row0 + i) * p.ldp + col] = h;
                    p.Cl[(long)bz * p.sP + (long)(row0 + i) * p.ldp + col] = l;
                }
            }
            if (OPT) {
                u16 h0,h1,h2,h3,l0,l1,l2,l3;
                cvt2(v[0],h0,l0); cvt2(v[1],h1,l1); cvt2(v[2],h2,l2); cvt2(v[3],h3,l3);
                ushort4 hv = {h0,h1,h2,h3}, lv = {l0,l1,l2,l3};
                *(ushort4*)&p.ChT[(long)bz * p.sCt + (long)col * p.ldct + row0] = hv;
                *(ushort4*)&p.ClT[(long)bz * p.sCt + (long)col * p.ldct + row0] = lv;
            }
            if (OFT) {
                float4 o4 = make_float4(v[0], v[1], v[2], v[3]);
                *(float4*)&p.CF[(long)bz * p.sCF + (long)col * 256 + row0] = o4;
            }
        }
    }
}

// ---------------- host ----------------

extern "C" void kernel_launch(void* const* d_in, const int* in_sizes, int n_in,
                              void* d_out, int out_size, void* d_ws, size_t ws_size,
                              hipStream_t stream) {
    const float* Kuu       = (const float*)d_in[0];
    const float* Kuf       = (const float*)d_in[1];
    const float* Kff       = (const float*)d_in[2];
    const float* Lloc      = (const float*)d_in[3];
    const float* Lscale    = (const float*)d_in[4];
    const float* u_param   = (const float*)d_in[5];
    const float* noise_inv = (const float*)d_in[6];
    const float* noise_L   = (const float*)d_in[7];
    const float* noise_f   = (const float*)d_in[8];
    float* out = (float*)d_out;
    float* ws  = (float*)d_ws;

    const long BIG = (long)S_ * MM_;     // 1,048,576 elements
    long off = 1024;
    float* part = ws + 16;

    #define PAIR(NAME, E) u16* NAME##h = (u16*)(ws + off); u16* NAME##l = NAME##h + (E); off += (E);
    PAIR(LS, 65536)
    PAIR(LtS, 65536)
    PAIR(upS, 65536)
    PAIR(W1S, 65536)
    float* UPT   = ws + off; off += 65536;
    float* VfAcc = ws + off; off += 65536;
    PAIR(KuuS, BIG)
    PAIR(ninvS, BIG)
    PAIR(nLS, BIG)
    float* cholK = ws + off; off += 2 * BIG;   // 32 matrices contiguous
    float* choll = cholK + BIG;
    PAIR(KuuLS, BIG)
    PAIR(KuuLtS, BIG)
    PAIR(TtS, 2 * BIG)             // T^T pair, 32 matrices  (zeroed in mega)
    PAIR(TKrS, 2 * BIG)            // T row-major pair, 32 matrices (zeroed in mega)
    PAIR(G3TS, BIG)                // (KuuInv @ U)^T pair
    PAIR(KIL, 2 * BIG)             // KuuInv (mats 0..15) | lKl (mats 16..31)
    PAIR(invS, 524288)             // 32 mats x 4 panels x 64x64 D pair
    PAIR(LfS, 2 * BIG)             // L strictly-lower pair, 32 matrices
    PAIR(StTS, 393216)             // S^T scratch pair, 32 x 192x64
    #undef PAIR

    u16* TKth = TtSh;                u16* TKtl = TtSl;
    u16* Tlth = TtSh + (long)S_ * MM_; u16* Tltl = TtSl + (long)S_ * MM_;
    u16* RHSTh   = KuuSh;            u16* RHSTl   = KuuSl;
    u16* UTph    = nLSh;             u16* UTpl    = nLSl;
    float* RHS1T = (float*)KuuLSh;
    u16* Sigmah  = KuuLtSh;          u16* Sigmal  = KuuLtSl;
    u16* KuuInvh = KILh;             u16* KuuInvl = KILl;
    u16* lKlh    = KILh + (long)S_ * MM_; u16* lKll = KILl + (long)S_ * MM_;

    long navail = (long)(ws_size / 4) - off;
    long nfc_l = navail / 4096;                 // only KufT pair per chunk
    int nfc = (int)((nfc_l / 128) * 128);
    if (nfc > NF_) nfc = NF_;
    if (nfc < 128) nfc = 128;
    long Ec = (long)S_ * nfc * 256;
    u16* KufTch = (u16*)(ws + off);      u16* KufTcl = KufTch + Ec;

    dim3 b256(256);

    max1_kernel<<<256, b256, 0, stream>>>(Kuu, S_ * MM_, part);
    max2prep_kernel<<<2, b256, 0, stream>>>(part, Lloc, Lscale, ws);

    splitjit_kernel<<<1024, b256, 0, stream>>>(Kuu, ws, KuuSh, KuuSl, cholK);
    psplit_kernel<<<64, b256, 0, stream>>>(Lloc, LSh, LSl, 65536, ws + 1);
    tsplit_kernel<<<dim3(8, 8, 1), b256, 0, stream>>>(Lloc, 256, 0, LtSh, LtSl, 256, 0, ws + 1);

    PG q;
    auto clr = [&]() {
        q = PG{};
        q.lda = 256; q.ldb = 256; q.ldc = 256; q.ldct = 256; q.ldp = 256;
        q.alpha = 1.f; q.dcoef = 1.f;
        q.M = 256; q.N = 256; q.K = 256;
    };
    dim3 g64(4, 4, S_);
    dim3 g64b1(4, 4, 1);

    // a. KuuL = Kuu @ L -> pair + pairT
    clr(); q.Ah = KuuSh; q.Al = KuuSl; q.sA = MM_;
    q.Bh = LtSh; q.Bl = LtSl; q.sB = 0;
    q.Ch = KuuLSh; q.Cl = KuuLSl; q.sP = MM_;
    q.ChT = KuuLtSh; q.ClT = KuuLtSl; q.sCt = MM_;
    pgemm64_k<0,1,1,0,0,0,0><<<g64, b256, 0, stream>>>(q);

    // b. choll = KuuL^T @ L + I -> fp32
    clr(); q.Ah = KuuLtSh; q.Al = KuuLtSl; q.sA = MM_;
    q.Bh = LtSh; q.Bl = LtSl; q.sB = 0;
    q.C = choll; q.sC = MM_;
    pgemm64_k<1,0,0,0,0,0,1><<<g64, b256, 0, stream>>>(q);

    // MEGA: chol (32 blocks) + aux prep (224 blocks)
    int w0 = nfc;
    MAux ax;
    ax.Kuf = Kuf; ax.KTh = KufTch; ax.KTl = KufTcl; ax.w0 = w0;
    ax.ninv = noise_inv; ax.nih = ninvSh; ax.nil = ninvSl;
    ax.nLp = noise_L; ax.nLh2 = nLSh; ax.nLl2 = nLSl;
    ax.up = u_param; ax.uph2 = upSh; ax.upl2 = upSl;
    ax.z1 = (float*)TtSh; ax.z1n = 4 * BIG;      // Tt pair + TKr pair (contiguous)
    ax.z2 = VfAcc; ax.z2n = 65536;
    megachol_kernel<<<256, dim3(1024), 0, stream>>>(cholK, choll, ax);

    // ---- block-recursive triangular inverse via MFMA ----
    tri64inv_kernel<<<dim3(4, 32), b256, 0, stream>>>(cholK, invSh, invSl,
                                                      TtSh, TtSl, TKrSh, TKrSl);
    lsplit_kernel<<<dim3(3, 32), b256, 0, stream>>>(cholK, LfSh, LfSl);

    for (int i = 1; i < 4; i++) {
        clr(); q.M = 64; q.N = 64 * i; q.K = 64 * i;
        q.Ah = LfSh + (long)64 * i * 256; q.Al = LfSl + (long)64 * i * 256;
        q.lda = 256; q.sA = MM_;
        q.Bh = TtSh; q.Bl = TtSl; q.ldb = 256; q.sB = MM_;
        q.ChT = StTSh; q.ClT = StTSl; q.ldct = 64; q.sCt = 12288;
        pgemm64_k<0,0,1,0,0,0,0><<<dim3(i, 1, 32), b256, 0, stream>>>(q);
        clr(); q.M = 64; q.N = 64 * i; q.K = 64;
        q.Ah = invSh + (long)i * 4096; q.Al = invSl + (long)i * 4096;
        q.lda = 64; q.sA = 16384;
        q.Bh = StTSh; q.Bl = StTSl; q.ldb = 64; q.sB = 12288;
        q.alpha = -1.f;
        q.Ch = TKrSh + (long)64 * i * 256; q.Cl = TKrSl + (long)64 * i * 256;
        q.ldp = 256; q.sP = MM_;
        q.ChT = TtSh + 64 * i; q.ClT = TtSl + 64 * i; q.ldct = 256; q.sCt = MM_;
        pgemm64_k<0,1,1,0,0,0,0><<<dim3(i, 1, 32), b256, 0, stream>>>(q);
    }

    // c2+d merged: [KuuInv | lKl] = Tt @ Tt^T over all 32 matrices
    clr(); q.Ah = TtSh; q.Al = TtSl; q.sA = MM_;
    q.Bh = TtSh; q.Bl = TtSl; q.sB = MM_;
    q.Ch = KILh; q.Cl = KILl; q.sP = MM_;
    pgemm64_k<0,1,0,0,0,0,0><<<dim3(4, 4, 32), b256, 0, stream>>>(q);

    // e. Stmp = KuuL @ lKlpIi -> pair (into Tlt region, dead after c2d)
    u16* Stmph = Tlth; u16* Stmpl = Tltl;
    clr(); q.Ah = KuuLSh; q.Al = KuuLSl; q.sA = MM_;
    q.Bh = lKlh; q.Bl = lKll; q.sB = MM_;
    q.Ch = Stmph; q.Cl = Stmpl; q.sP = MM_;
    pgemm64_k<0,1,0,0,0,0,0><<<g64, b256, 0, stream>>>(q);

    // f. Sigma = Kuu - Stmp @ KuuL^T -> pair
    clr(); q.Ah = Stmph; q.Al = Stmpl; q.sA = MM_;
    q.Bh = KuuLSh; q.Bl = KuuLSl; q.sB = MM_;
    q.Ch = Sigmah; q.Cl = Sigmal; q.sP = MM_;
    q.D = Kuu; q.sD = MM_; q.alpha = -1.f;
    pgemm64_k<0,1,0,0,0,1,0><<<g64, b256, 0, stream>>>(q);

    // g. W1 = up @ L -> pair (batch 1)
    clr(); q.Ah = upSh; q.Al = upSl; q.sA = 0;
    q.Bh = LtSh; q.Bl = LtSl; q.sB = 0;
    q.Ch = W1Sh; q.Cl = W1Sl; q.sP = 0;
    pgemm64_k<0,1,0,0,0,0,0><<<g64b1, b256, 0, stream>>>(q);

    // h. UPT = W1 @ L^T -> fp32 (batch 1)
    clr(); q.Ah = W1Sh; q.Al = W1Sl; q.sA = 0;
    q.Bh = LSh; q.Bl = LSl; q.sB = 0;
    q.C = UPT; q.sC = 0;
    pgemm64_k<1,0,0,0,0,0,0><<<g64b1, b256, 0, stream>>>(q);

    // i. RHS1T = ninv @ TK + UPT -> fp32
    clr(); q.Ah = ninvSh; q.Al = ninvSl; q.sA = 65536;
    q.Bh = TKth; q.Bl = TKtl; q.sB = MM_;
    q.C = RHS1T; q.sC = MM_;
    q.D = UPT; q.sD = 0;
    pgemm64_k<1,0,0,0,0,1,0><<<g64, b256, 0, stream>>>(q);

    // j. RHST = nL @ L^T + RHS1T -> pair
    clr(); q.Ah = nLSh; q.Al = nLSl; q.sA = 65536;
    q.Bh = LSh; q.Bl = LSl; q.sB = 0;
    q.C = RHS1T; q.sC = MM_;
    q.Ch = RHSTh; q.Cl = RHSTl; q.sP = MM_;
    pgemm64_k<0,1,0,0,1,0,0><<<g64, b256, 0, stream>>>(q);

    // k. UT = RHST @ Sigma -> pair + transposed fp32 direct into out rows 0..255
    clr(); q.Ah = RHSTh; q.Al = RHSTl; q.sA = MM_;
    q.Bh = Sigmah; q.Bl = Sigmal; q.sB = MM_;
    q.Ch = UTph; q.Cl = UTpl; q.sP = MM_;
    q.CF = out; q.sCF = (long)ROWS_ * OUT_;
    pgemm64_k<0,1,0,1,0,0,0><<<g64, b256, 0, stream>>>(q);

    // G3T = UTp @ KuuInv -> pair
    clr(); q.Ah = UTph; q.Al = UTpl; q.sA = MM_;
    q.Bh = KuuInvh; q.Bl = KuuInvl; q.sB = MM_;
    q.Ch = G3TSh; q.Cl = G3TSl; q.sP = MM_;
    pgemm64_k<0,1,0,0,0,0,0><<<g64, b256, 0, stream>>>(q);

    for (int f0 = 0; f0 < NF_; f0 += nfc) {
        int w = NF_ - f0; if (w > nfc) w = nfc;
        if (f0 > 0)    // chunk 0 transposed inside megachol
            tsplit_kernel<<<dim3(w / 32, 8, S_), b256, 0, stream>>>(
                Kuf + f0, NF_, (long)M_ * NF_, KufTch, KufTcl, 256, (long)w * 256, nullptr);
        // Vf-GEMM: H' = KufT @ TK^T, no output, only VfAcc row sums of squares
        clr(); q.M = w; q.N = 256;
        q.Ah = KufTch; q.Al = KufTcl; q.sA = (long)w * 256;
        q.Bh = TKrSh; q.Bl = TKrSl; q.sB = MM_;
        q.vfacc = VfAcc + f0; q.sVf = NF_;
        pgemm_k<0,0,0,0,0,0,0,1><<<dim3(2, w / 128, S_), b256, 0, stream>>>(q);
        // Ef-GEMM: out_f = KufT @ G3T^T + sqrt(Kff - VfAcc)*noise_f
        clr(); q.M = w; q.N = 256;
        q.Ah = KufTch; q.Al = KufTcl; q.sA = (long)w * 256;
        q.Bh = G3TSh; q.Bl = G3TSl; q.sB = MM_;
        q.C = out + (long)(M_ + f0) * OUT_; q.sC = (long)ROWS_ * OUT_;
        q.kff = Kff + f0; q.vfacc = VfAcc + f0; q.sVf = NF_;
        q.noise = noise_f + (long)f0 * OUT_; q.sNoise = (long)NF_ * OUT_;
        pgemm_k<1,0,0,0,0,0,1,0><<<dim3(2, w / 128, S_), b256, 0, stream>>>(q);
    }
}

// Round 18
// 439.326 us; speedup vs baseline: 1.2887x; 1.0041x over previous
//
#include <hip/hip_runtime.h>
#include <math.h>

#define S_ 16
#define M_ 256
#define NF_ 4096
#define OUT_ 256
#define ROWS_ (M_ + NF_)     // 4352
#define JITTER_ 1e-8f
#define MM_ (M_ * M_)        // 65536

typedef unsigned short u16;
typedef __attribute__((ext_vector_type(8))) short bf16x8;
typedef __attribute__((ext_vector_type(4))) float f32x4;

__device__ __forceinline__ void cvt2(float x, u16& h, u16& l) {
    unsigned xb = __float_as_uint(x);
    unsigned hb = (xb + 0x7fffu + ((xb >> 16) & 1u)) >> 16;
    float fh = __uint_as_float(hb << 16);
    float rr = x - fh;
    unsigned rb = __float_as_uint(rr);
    unsigned lb = (rb + 0x7fffu + ((rb >> 16) & 1u)) >> 16;
    h = (u16)hb; l = (u16)lb;
}

// ---------------- small prep kernels ----------------

__global__ void max1_kernel(const float* __restrict__ x, int n, float* part) {
    __shared__ float red[256];
    int tid = threadIdx.x;
    float m = -3.4e38f;
    for (int i = blockIdx.x * blockDim.x + tid; i < n; i += gridDim.x * blockDim.x)
        m = fmaxf(m, x[i]);
    red[tid] = m; __syncthreads();
    for (int s = 128; s > 0; s >>= 1) {
        if (tid < s) red[tid] = fmaxf(red[tid], red[tid + s]);
        __syncthreads();
    }
    if (tid == 0) part[blockIdx.x] = red[0];
}

// block 0: global max -> ws[0], ws[2]=jit ; block 1: L scale -> ws[1]
__global__ void max2prep_kernel(const float* part, const float* __restrict__ Lloc,
                                const float* __restrict__ Lscale, float* ws) {
    __shared__ float red[256];
    int tid = threadIdx.x;
    if (blockIdx.x == 0) {
        red[tid] = part[tid]; __syncthreads();
        for (int s = 128; s > 0; s >>= 1) {
            if (tid < s) red[tid] = fmaxf(red[tid], red[tid + s]);
            __syncthreads();
        }
        if (tid == 0) { ws[0] = red[0]; ws[2] = JITTER_ * red[0]; }
    } else {
        red[tid] = Lloc[tid * M_ + tid];
        __syncthreads();
        for (int s = 128; s > 0; s >>= 1) {
            if (tid < s) red[tid] += red[tid + s];
            __syncthreads();
        }
        if (tid == 0) {
            float norm = red[0] / (float)M_;
            ws[1] = expf(Lscale[0]) / norm;
        }
    }
}

// ---- plain split ----
__global__ void psplit_kernel(const float* __restrict__ src, u16* __restrict__ h,
                              u16* __restrict__ l, long n, const float* scaleptr) {
    float sc = scaleptr ? scaleptr[0] : 1.0f;
    long stride = (long)gridDim.x * blockDim.x * 4;
    for (long i = ((long)blockIdx.x * blockDim.x + threadIdx.x) * 4; i < n; i += stride) {
        float4 v = *(const float4*)(src + i);
        u16 h0,h1,h2,h3,l0,l1,l2,l3;
        cvt2(v.x*sc,h0,l0); cvt2(v.y*sc,h1,l1); cvt2(v.z*sc,h2,l2); cvt2(v.w*sc,h3,l3);
        ushort4 hv = {h0,h1,h2,h3}, lv = {l0,l1,l2,l3};
        *(ushort4*)(h + i) = hv;
        *(ushort4*)(l + i) = lv;
    }
}

// ---- fused Kuu split + jittered copy for Cholesky ----
__global__ void splitjit_kernel(const float* __restrict__ Kuu, const float* __restrict__ ws,
                                u16* __restrict__ h, u16* __restrict__ l,
                                float* __restrict__ dst) {
    float jit = ws[2];
    long i = ((long)blockIdx.x * blockDim.x + threadIdx.x) * 4;
    if (i < (long)S_ * MM_) {
        float4 v = *(const float4*)(Kuu + i);
        u16 h0,h1,h2,h3,l0,l1,l2,l3;
        cvt2(v.x,h0,l0); cvt2(v.y,h1,l1); cvt2(v.z,h2,l2); cvt2(v.w,h3,l3);
        ushort4 hv = {h0,h1,h2,h3}, lv = {l0,l1,l2,l3};
        *(ushort4*)(h + i) = hv;
        *(ushort4*)(l + i) = lv;
        int rc = (int)(i & 65535);
        int r = rc >> 8, c0 = rc & 255;
        if (r >= c0 && r < c0 + 4) ((float*)&v)[r - c0] += jit;
        *(float4*)(dst + i) = v;
    }
}

// ---- transpose split (used for L^T and tail chunks beyond chunk 0) ----
__global__ void tsplit_kernel(const float* __restrict__ src, int ldS, long sS,
                              u16* __restrict__ h, u16* __restrict__ l, int ldD, long sD,
                              const float* scaleptr) {
    int b = blockIdx.z;
    src += (long)b * sS; h += (long)b * sD; l += (long)b * sD;
    __shared__ float T[32][33];
    int r0 = blockIdx.y * 32, c0 = blockIdx.x * 32;
    float sc = scaleptr ? scaleptr[0] : 1.0f;
    int tid = threadIdx.x;
    int lrow = tid >> 3, lc4 = (tid & 7) * 4;
    float4 v = *(const float4*)(src + (long)(r0 + lrow) * ldS + c0 + lc4);
    T[lrow][lc4 + 0] = v.x * sc; T[lrow][lc4 + 1] = v.y * sc;
    T[lrow][lc4 + 2] = v.z * sc; T[lrow][lc4 + 3] = v.w * sc;
    __syncthreads();
    int wcol = tid >> 3, wr4 = (tid & 7) * 4;
    u16 h0,h1,h2,h3,l0,l1,l2,l3;
    cvt2(T[wr4+0][wcol],h0,l0); cvt2(T[wr4+1][wcol],h1,l1);
    cvt2(T[wr4+2][wcol],h2,l2); cvt2(T[wr4+3][wcol],h3,l3);
    ushort4 hv = {h0,h1,h2,h3}, lv = {l0,l1,l2,l3};
    *(ushort4*)(h + (long)(c0 + wcol) * ldD + r0 + wr4) = hv;
    *(ushort4*)(l + (long)(c0 + wcol) * ldD + r0 + wr4) = lv;
}

__device__ __forceinline__ void psplit_dev(const float* __restrict__ src, u16* __restrict__ h,
                                           u16* __restrict__ l, long n, long b0, long stp) {
    for (long i = b0 * 4; i < n; i += stp * 4) {
        float4 v = *(const float4*)(src + i);
        u16 h0,h1,h2,h3,l0,l1,l2,l3;
        cvt2(v.x,h0,l0); cvt2(v.y,h1,l1); cvt2(v.z,h2,l2); cvt2(v.w,h3,l3);
        ushort4 hv = {h0,h1,h2,h3}, lv = {l0,l1,l2,l3};
        *(ushort4*)(h + i) = hv;
        *(ushort4*)(l + i) = lv;
    }
}

// ---------------- MEGA: chol (blocks 0..31) + independent prep (blocks 32+) ----------------

struct MAux {
    const float* Kuf; u16 *KTh, *KTl; int w0;
    const float* ninv; u16 *nih, *nil;
    const float* nLp;  u16 *nLh2, *nLl2;
    const float* up;   u16 *uph2, *upl2;
    float* z1; long z1n;       // Tt+TKr zero region (floats)
    float* z2; long z2n;       // VfAcc
};

__global__ __launch_bounds__(1024) void megachol_kernel(float* bufA, float* bufB, MAux ax) {
    __shared__ float P[33280];
    __shared__ float pan2[256 * 20];
    __shared__ float piv[16][20];    // rows 16B-aligned; [j][i<=j]=L, i>j zeroed; [j][16]=1/d

    if (blockIdx.x < 32) {
        // -------- chol body (blk = blockIdx.x) --------
        int blk = blockIdx.x;
        float* Ag = (blk < S_) ? (bufA + (long)blk * MM_) : (bufB + (long)(blk - S_) * MM_);
        float4* P4 = (float4*)P;
        int tid = threadIdx.x;
        int r = tid >> 2, s = tid & 3;
        int lane = tid & 63, wid = tid >> 6;
        int mg = r >> 2, tg = r & 3;
        int b4 = (mg + 1) * (2 * mg + tg);

        for (int i = wid; i < M_; i += 16) {
            int m = i >> 2, t4 = i & 3;
            int rb4 = (m + 1) * (2 * m + t4);
            if (lane <= m) P4[rb4 + lane] = ((const float4*)Ag)[i * 64 + lane];
        }
        __syncthreads();

        float preg[16];
        for (int p = 0; p < 16; p++) {
            int k0 = p << 4;
            int c0 = p << 2;
            #pragma unroll
            for (int rr = 0; rr < 4; rr++) {
                float4 v = make_float4(0.f, 0.f, 0.f, 0.f);
                if (r >= k0 && c0 + rr <= mg) v = P4[b4 + c0 + rr];
                preg[4 * rr + 0] = v.x; preg[4 * rr + 1] = v.y;
                preg[4 * rr + 2] = v.z; preg[4 * rr + 3] = v.w;
            }
            if (wid == p) {
                int dj = lane >> 2;
                float myinv = 0.f;
                #pragma unroll
                for (int j = 0; j < 16; j++) {
                    float app = __shfl(preg[j], 4 * j, 64);
                    float d = sqrtf(app);
                    float inv = 1.0f / d;
                    if (dj == j) { preg[j] = d; myinv = inv; }
                    else if (dj > j) preg[j] *= inv;
                    #pragma unroll
                    for (int j2 = j + 1; j2 < 16; j2++) {
                        float Lj2 = __shfl(preg[j], 4 * j2, 64);
                        if (dj >= j2) preg[j2] -= preg[j] * Lj2;
                    }
                }
                if (s == 0) {
                    #pragma unroll
                    for (int i = 0; i < 16; i++) piv[dj][i] = (i <= dj) ? preg[i] : 0.f;
                    piv[dj][16] = myinv;
                }
            }
            __syncthreads();
            // ---- (B) forward substitution, piv rows via float4 broadcasts ----
            if (r > k0 + 15) {
                float xs[16];
                #pragma unroll
                for (int i = 0; i < 16; i++) xs[i] = 0.f;
                #pragma unroll
                for (int j = 0; j < 16; j++) {
                    const float4* pr = (const float4*)&piv[j][0];
                    float dot = 0.f;
                    if (j > 0)  { float4 p0 = pr[0];
                        dot += p0.x*xs[0] + p0.y*xs[1] + p0.z*xs[2] + p0.w*xs[3]; }
                    if (j > 4)  { float4 p1 = pr[1];
                        dot += p1.x*xs[4] + p1.y*xs[5] + p1.z*xs[6] + p1.w*xs[7]; }
                    if (j > 8)  { float4 p2 = pr[2];
                        dot += p2.x*xs[8] + p2.y*xs[9] + p2.z*xs[10] + p2.w*xs[11]; }
                    if (j > 12) { float4 p3 = pr[3];
                        dot += p3.x*xs[12] + p3.y*xs[13] + p3.z*xs[14] + p3.w*xs[15]; }
                    xs[j] = (preg[j] - dot) * piv[j][16];
                }
                #pragma unroll
                for (int j = 0; j < 16; j++) preg[j] = xs[j];
            }
            if (r >= k0) {
                float4 pv = make_float4(preg[4 * s], preg[4 * s + 1],
                                        preg[4 * s + 2], preg[4 * s + 3]);
                *(float4*)&pan2[r * 20 + 4 * s] = pv;
                int c = c0 + s;
                if (c <= mg) P4[b4 + c] = pv;
            }
            __syncthreads();
            {
                int cs = tid >> 4;
                int j  = tid & 15;
                if (cs >= c0 + 4) {
                    float4 q0[4], q1[4], q2[4], q3[4];
                    #pragma unroll
                    for (int e = 0; e < 4; e++) {
                        const float4* pr = (const float4*)&pan2[(4 * cs + e) * 20];
                        q0[e] = pr[0]; q1[e] = pr[1]; q2[e] = pr[2]; q3[e] = pr[3];
                    }
                    int rr = k0 + 16 + j;
                    int rmin = 4 * cs;
                    while (rr < rmin) rr += 16;
                    for (; rr < 256; rr += 16) {
                        int mgr = rr >> 2, tgr = rr & 3;
                        int rb4 = (mgr + 1) * (2 * mgr + tgr);
                        const float4* ar = (const float4*)&pan2[rr * 20];
                        float4 a0 = ar[0], a1 = ar[1], a2 = ar[2], a3 = ar[3];
                        float rv[4];
                        *(float4*)rv = P4[rb4 + cs];
                        #pragma unroll
                        for (int e = 0; e < 4; e++) {
                            float acc;
                            acc  = a0.x*q0[e].x + a0.y*q0[e].y + a0.z*q0[e].z + a0.w*q0[e].w;
                            acc += a1.x*q1[e].x + a1.y*q1[e].y + a1.z*q1[e].z + a1.w*q1[e].w;
                            acc += a2.x*q2[e].x + a2.y*q2[e].y + a2.z*q2[e].z + a2.w*q2[e].w;
                            acc += a3.x*q3[e].x + a3.y*q3[e].y + a3.z*q3[e].z + a3.w*q3[e].w;
                            rv[e] -= acc;
                        }
                        P4[rb4 + cs] = *(float4*)rv;
                    }
                }
            }
            __syncthreads();
        }

        for (int i = wid; i < M_; i += 16) {
            int m = i >> 2, t4 = i & 3;
            int rb4 = (m + 1) * (2 * m + t4);
            if (lane <= m) ((float4*)Ag)[i * 64 + lane] = P4[rb4 + lane];
        }
        return;
    }

    // -------- aux path: independent prep work on idle CUs --------
    int ab = blockIdx.x - 32, NA = gridDim.x - 32;
    int tid = threadIdx.x;
    long b0 = (long)ab * 1024 + tid, stp = (long)NA * 1024;
    float4 z = make_float4(0.f, 0.f, 0.f, 0.f);
    long n4 = ax.z1n >> 2;
    for (long i = b0; i < n4; i += stp) ((float4*)ax.z1)[i] = z;
    long m4 = ax.z2n >> 2;
    for (long i = b0; i < m4; i += stp) ((float4*)ax.z2)[i] = z;
    psplit_dev(ax.ninv, ax.nih, ax.nil, (long)S_ * MM_, b0, stp);
    psplit_dev(ax.nLp, ax.nLh2, ax.nLl2, (long)S_ * MM_, b0, stp);
    psplit_dev(ax.up, ax.uph2, ax.upl2, 65536, b0, stp);

    int grp = tid >> 8, t = tid & 255;
    float* Tls = P + grp * 1056;
    int nx = ax.w0 >> 5;
    int ntile = nx * 8 * S_;
    int per = NA * 4;
    int iters = (ntile + per - 1) / per;
    long sS = (long)M_ * NF_, sD = (long)ax.w0 * 256;
    for (int it = 0; it < iters; it++) {
        int tile = ab * 4 + grp + it * per;
        bool ok = tile < ntile;
        int r0 = 0, c0 = 0, b = 0;
        if (ok) {
            int cx = tile % nx; int rest = tile / nx;
            int cy = rest & 7; b = rest >> 3;
            r0 = cy * 32; c0 = cx * 32;
        }
        if (ok) {
            int lrow = t >> 3, lc4 = (t & 7) * 4;
            float4 v = *(const float4*)(ax.Kuf + (long)b * sS + (long)(r0 + lrow) * NF_ + c0 + lc4);
            Tls[lrow * 33 + lc4 + 0] = v.x; Tls[lrow * 33 + lc4 + 1] = v.y;
            Tls[lrow * 33 + lc4 + 2] = v.z; Tls[lrow * 33 + lc4 + 3] = v.w;
        }
        __syncthreads();
        if (ok) {
            int wcol = t >> 3, wr4 = (t & 7) * 4;
            u16 h0,h1,h2,h3,l0,l1,l2,l3;
            cvt2(Tls[(wr4+0)*33+wcol],h0,l0); cvt2(Tls[(wr4+1)*33+wcol],h1,l1);
            cvt2(Tls[(wr4+2)*33+wcol],h2,l2); cvt2(Tls[(wr4+3)*33+wcol],h3,l3);
            ushort4 hv = {h0,h1,h2,h3}, lv = {l0,l1,l2,l3};
            long o = (long)b * sD + (long)(c0 + wcol) * 256 + r0 + wr4;
            *(ushort4*)(ax.KTh + o) = hv;
            *(ushort4*)(ax.KTl + o) = lv;
        }
        __syncthreads();
    }
}

// ---------------- merged: 64x64 diag triangular inverse (bx<4) + lsplit (bx>=4) ----------------

__global__ __launch_bounds__(256) void trilsp_kernel(const float* W0,
                                                     u16* invh, u16* invl,
                                                     u16* Tth, u16* Ttl,
                                                     u16* TKrh, u16* TKrl,
                                                     u16* Lh, u16* Ll) {
    __shared__ float X[64 * 65];
    __shared__ float pan[64 * 20];
    int mat = blockIdx.y;      // 0..31
    int tid = threadIdx.x;
    const float* W = W0 + (long)mat * MM_;

    if (blockIdx.x >= 4) {
        // -------- lsplit path --------
        int p = blockIdx.x - 4;        // 0..2
        u16* dh = Lh + (long)mat * MM_;
        u16* dl = Ll + (long)mat * MM_;
        int d0 = 64 * p, nrows = 192 - d0;
        for (int idx = tid; idx < nrows * 16; idx += 256) {
            int r = idx >> 4, c4 = idx & 15;
            long o = (long)(d0 + 64 + r) * 256 + d0 + 4 * c4;
            float4 v = *(const float4*)(W + o);
            u16 h0,h1,h2,h3,l0,l1,l2,l3;
            cvt2(v.x,h0,l0); cvt2(v.y,h1,l1); cvt2(v.z,h2,l2); cvt2(v.w,h3,l3);
            ushort4 hv = {h0,h1,h2,h3}, lv = {l0,l1,l2,l3};
            *(ushort4*)(dh + o) = hv;
            *(ushort4*)(dl + o) = lv;
        }
        return;
    }

    // -------- tri64inv path --------
    int p = blockIdx.x;        // 0..3
    int d0 = p * 64;
    int c = tid & 63, q = tid >> 6;
    for (int idx = tid; idx < 64 * 65; idx += 256) X[idx] = 0.f;
    __syncthreads();
    if (q == 0) X[c * 65 + c] = 1.0f;
    for (int pp = 0; pp < 4; pp++) {
        int t0 = pp << 4;
        for (int idx = tid; idx < 64 * 4; idx += 256) {
            int k = idx >> 2, e = idx & 3;
            if (k >= t0)
                ((float4*)(pan + k * 20))[e] =
                    *(const float4*)(W + (long)(d0 + k) * 256 + d0 + t0 + 4 * e);
        }
        __syncthreads();
        if (q == pp) {
            float xr[16];
            #pragma unroll
            for (int j = 0; j < 16; j++) {
                float xv = X[(t0 + j) * 65 + c];
                #pragma unroll
                for (int i = 0; i < 16; i++)
                    if (i < j) xv -= pan[(t0 + j) * 20 + i] * xr[i];
                xv *= (1.0f / pan[(t0 + j) * 20 + j]);
                xr[j] = xv;
                X[(t0 + j) * 65 + c] = xv;
            }
        }
        __syncthreads();
        int kbeg = q << 4; if (kbeg < t0 + 16) kbeg = t0 + 16;
        int kend = (q << 4) + 16;
        if (kbeg < kend) {
            float xr[16];
            #pragma unroll
            for (int j = 0; j < 16; j++) xr[j] = X[(t0 + j) * 65 + c];
            for (int kk = kbeg; kk < kend; kk++) {
                float rv = X[kk * 65 + c];
                const float4* pr = (const float4*)&pan[kk * 20];
                float4 a = pr[0], b = pr[1], d = pr[2], e = pr[3];
                rv -= a.x * xr[0] + a.y * xr[1] + a.z * xr[2] + a.w * xr[3];
                rv -= b.x * xr[4] + b.y * xr[5] + b.z * xr[6] + b.w * xr[7];
                rv -= d.x * xr[8] + d.y * xr[9] + d.z * xr[10] + d.w * xr[11];
                rv -= e.x * xr[12] + e.y * xr[13] + e.z * xr[14] + e.w * xr[15];
                X[kk * 65 + c] = rv;
            }
        }
        __syncthreads();
    }
    for (int idx = tid; idx < 4096; idx += 256) {
        int r = idx >> 6, k = idx & 63;
        u16 h, l; cvt2(X[r * 65 + k], h, l);
        long io = (long)mat * 16384 + (long)p * 4096 + idx;
        invh[io] = h; invl[io] = l;
        long ro = (long)mat * MM_ + (long)(d0 + r) * 256 + d0 + k;
        TKrh[ro] = h; TKrl[ro] = l;
        long to = (long)mat * MM_ + (long)(d0 + k) * 256 + d0 + r;
        Tth[to] = h; Ttl[to] = l;
    }
}

// ---------------- pair GEMM: C = alpha * A @ B^T(storage) + epilogue ----------------

struct PG {
    const u16 *Ah, *Al, *Bh, *Bl;
    float* C; u16 *Ch, *Cl, *ChT, *ClT;
    float* CF;                      // transposed fp32 out
    const float* D; const float* noise;
    const float* kff; float* vfacc;
    int M, N, K, lda, ldb, ldc, ldct, ldp;
    long sA, sB, sC, sP, sCt, sD, sVf, sNoise, sCF;
    float alpha, dcoef;
};

// 128x128 tile, 4 waves (K = 256; TRIf: K capped at bn+128 for lower-tri B)
template<int OF, int OP, int OPT, int ACCf, int Df, int ADDIf, int EFf, int VFf, int TRIf>
__global__ __launch_bounds__(256) void pgemm_k(PG p) {
    int bz = blockIdx.z;
    const u16* Agh = p.Ah + (long)bz * p.sA;
    const u16* Agl = p.Al + (long)bz * p.sA;
    const u16* Bgh = p.Bh + (long)bz * p.sB;
    const u16* Bgl = p.Bl + (long)bz * p.sB;
    int bm = blockIdx.y * 128, bn = blockIdx.x * 128;
    __shared__ __align__(16) u16 sAh[128][40];
    __shared__ __align__(16) u16 sAl[128][40];
    __shared__ __align__(16) u16 sBh[128][40];
    __shared__ __align__(16) u16 sBl[128][40];
    int tid = threadIdx.x, lane = tid & 63, wid = tid >> 6;
    int wm = (wid >> 1) * 64, wn = (wid & 1) * 64;
    int fr = lane & 15, ko = (lane >> 4) * 8;
    int kb = tid & 3, rw = tid >> 2;
    f32x4 acc[4][4];
    #pragma unroll
    for (int m = 0; m < 4; m++)
        #pragma unroll
        for (int n = 0; n < 4; n++)
            acc[m][n] = (f32x4){0.f, 0.f, 0.f, 0.f};

    int klim = TRIf ? (bn + 128) : 256;
    for (int k0 = 0; k0 < klim; k0 += 32) {
        #define STG(SRC, LD, BASE, DST) \
            *(bf16x8*)&DST[rw][kb * 8] = \
                *(const bf16x8*)(SRC + (long)(BASE + rw) * LD + k0 + kb * 8); \
            *(bf16x8*)&DST[rw + 64][kb * 8] = \
                *(const bf16x8*)(SRC + (long)(BASE + rw + 64) * LD + k0 + kb * 8);
        STG(Agh, p.lda, bm, sAh)
        STG(Agl, p.lda, bm, sAl)
        STG(Bgh, p.ldb, bn, sBh)
        STG(Bgl, p.ldb, bn, sBl)
        #undef STG
        __syncthreads();
        bf16x8 ah[4], al[4], bh[4], bl[4];
        #pragma unroll
        for (int m = 0; m < 4; m++) {
            ah[m] = *(const bf16x8*)&sAh[wm + m * 16 + fr][ko];
            al[m] = *(const bf16x8*)&sAl[wm + m * 16 + fr][ko];
        }
        #pragma unroll
        for (int n = 0; n < 4; n++) {
            bh[n] = *(const bf16x8*)&sBh[wn + n * 16 + fr][ko];
            bl[n] = *(const bf16x8*)&sBl[wn + n * 16 + fr][ko];
        }
        #pragma unroll
        for (int m = 0; m < 4; m++)
            #pragma unroll
            for (int n = 0; n < 4; n++) {
                acc[m][n] = __builtin_amdgcn_mfma_f32_16x16x32_bf16(ah[m], bh[n], acc[m][n], 0, 0, 0);
                acc[m][n] = __builtin_amdgcn_mfma_f32_16x16x32_bf16(ah[m], bl[n], acc[m][n], 0, 0, 0);
                acc[m][n] = __builtin_amdgcn_mfma_f32_16x16x32_bf16(al[m], bh[n], acc[m][n], 0, 0, 0);
            }
        __syncthreads();
    }

    int rq = (lane >> 4) * 4;
    float rs[4][4];
    if (VFf) {
        #pragma unroll
        for (int m = 0; m < 4; m++)
            #pragma unroll
            for (int i = 0; i < 4; i++) rs[m][i] = 0.f;
    }
    #pragma unroll
    for (int m = 0; m < 4; m++) {
        int row0 = bm + wm + m * 16 + rq;
        #pragma unroll
        for (int n = 0; n < 4; n++) {
            int col = bn + wn + n * 16 + fr;
            float v[4];
            #pragma unroll
            for (int i = 0; i < 4; i++) {
                int r = row0 + i;
                float val = p.alpha * acc[m][n][i];
                if (Df)   val += p.dcoef * p.D[(long)bz * p.sD + (long)r * p.ldc + col];
                if (ACCf) val += p.C[(long)bz * p.sC + (long)r * p.ldc + col];
                if (ADDIf && r == col) val += 1.0f;
                if (EFf) {
                    float kf = p.kff[(long)bz * p.sVf + r];
                    float vq = p.vfacc[(long)bz * p.sVf + r];
                    val += sqrtf(fmaxf(kf - vq, 0.f)) *
                           p.noise[(long)bz * p.sNoise + (long)r * 256 + col];
                }
                v[i] = val;
                if (VFf) rs[m][i] += val * val;
            }
            if (OF) {
                #pragma unroll
                for (int i = 0; i < 4; i++)
                    p.C[(long)bz * p.sC + (long)(row0 + i) * p.ldc + col] = v[i];
            }
            if (OP) {
                #pragma unroll
                for (int i = 0; i < 4; i++) {
                    u16 h, l; cvt2(v[i], h, l);
                    p.Ch[(long)bz * p.sP + (long)(row0 + i) * p.ldc + col] = h;
                    p.Cl[(long)bz * p.sP + (long)(row0 + i) * p.ldc + col] = l;
                }
            }
            if (OPT) {
                u16 h0,h1,h2,h3,l0,l1,l2,l3;
                cvt2(v[0],h0,l0); cvt2(v[1],h1,l1); cvt2(v[2],h2,l2); cvt2(v[3],h3,l3);
                ushort4 hv = {h0,h1,h2,h3}, lv = {l0,l1,l2,l3};
                *(ushort4*)&p.ChT[(long)bz * p.sCt + (long)col * p.ldct + row0] = hv;
                *(ushort4*)&p.ClT[(long)bz * p.sCt + (long)col * p.ldct + row0] = lv;
            }
        }
    }
    if (VFf) {
        #pragma unroll
        for (int m = 0; m < 4; m++) {
            int row0 = bm + wm + m * 16 + rq;
            #pragma unroll
            for (int i = 0; i < 4; i++) {
                float t = rs[m][i];
                t += __shfl_xor(t, 1); t += __shfl_xor(t, 2);
                t += __shfl_xor(t, 4); t += __shfl_xor(t, 8);
                if (fr == 0)
                    atomicAdd(&p.vfacc[(long)bz * p.sVf + row0 + i], t);
            }
        }
    }
}

// 64x64 tile, 4 waves, runtime K (multiple of 32); OFT = transposed fp32 out
template<int OF, int OP, int OPT, int OFT, int ACCf, int Df, int ADDIf>
__global__ __launch_bounds__(256) void pgemm64_k(PG p) {
    int bz = blockIdx.z;
    const u16* Agh = p.Ah + (long)bz * p.sA;
    const u16* Agl = p.Al + (long)bz * p.sA;
    const u16* Bgh = p.Bh + (long)bz * p.sB;
    const u16* Bgl = p.Bl + (long)bz * p.sB;
    int bm = blockIdx.y * 64, bn = blockIdx.x * 64;
    __shared__ __align__(16) u16 sAh[64][40];
    __shared__ __align__(16) u16 sAl[64][40];
    __shared__ __align__(16) u16 sBh[64][40];
    __shared__ __align__(16) u16 sBl[64][40];
    int tid = threadIdx.x, lane = tid & 63, wid = tid >> 6;
    int wm = (wid >> 1) * 32, wn = (wid & 1) * 32;
    int fr = lane & 15, ko = (lane >> 4) * 8;
    int kb = tid & 3, rw = tid >> 2;
    f32x4 acc[2][2];
    #pragma unroll
    for (int m = 0; m < 2; m++)
        #pragma unroll
        for (int n = 0; n < 2; n++)
            acc[m][n] = (f32x4){0.f, 0.f, 0.f, 0.f};

    for (int k0 = 0; k0 < p.K; k0 += 32) {
        *(bf16x8*)&sAh[rw][kb * 8] = *(const bf16x8*)(Agh + (long)(bm + rw) * p.lda + k0 + kb * 8);
        *(bf16x8*)&sAl[rw][kb * 8] = *(const bf16x8*)(Agl + (long)(bm + rw) * p.lda + k0 + kb * 8);
        *(bf16x8*)&sBh[rw][kb * 8] = *(const bf16x8*)(Bgh + (long)(bn + rw) * p.ldb + k0 + kb * 8);
        *(bf16x8*)&sBl[rw][kb * 8] = *(const bf16x8*)(Bgl + (long)(bn + rw) * p.ldb + k0 + kb * 8);
        __syncthreads();
        bf16x8 ah[2], al[2], bh[2], bl[2];
        #pragma unroll
        for (int m = 0; m < 2; m++) {
            ah[m] = *(const bf16x8*)&sAh[wm + m * 16 + fr][ko];
            al[m] = *(const bf16x8*)&sAl[wm + m * 16 + fr][ko];
        }
        #pragma unroll
        for (int n = 0; n < 2; n++) {
            bh[n] = *(const bf16x8*)&sBh[wn + n * 16 + fr][ko];
            bl[n] = *(const bf16x8*)&sBl[wn + n * 16 + fr][ko];
        }
        #pragma unroll
        for (int m = 0; m < 2; m++)
            #pragma unroll
            for (int n = 0; n < 2; n++) {
                acc[m][n] = __builtin_amdgcn_mfma_f32_16x16x32_bf16(ah[m], bh[n], acc[m][n], 0, 0, 0);
                acc[m][n] = __builtin_amdgcn_mfma_f32_16x16x32_bf16(ah[m], bl[n], acc[m][n], 0, 0, 0);
                acc[m][n] = __builtin_amdgcn_mfma_f32_16x16x32_bf16(al[m], bh[n], acc[m][n], 0, 0, 0);
            }
        __syncthreads();
    }

    int rq = (lane >> 4) * 4;
    #pragma unroll
    for (int m = 0; m < 2; m++) {
        int row0 = bm + wm + m * 16 + rq;
        #pragma unroll
        for (int n = 0; n < 2; n++) {
            int col = bn + wn + n * 16 + fr;
            float v[4];
            #pragma unroll
            for (int i = 0; i < 4; i++) {
                int r = row0 + i;
                float val = p.alpha * acc[m][n][i];
                if (Df)   val += p.dcoef * p.D[(long)bz * p.sD + (long)r * p.ldc + col];
                if (ACCf) val += p.C[(long)bz * p.sC + (long)r * p.ldc + col];
                if (ADDIf && r == col) val += 1.0f;
                v[i] = val;
            }
            if (OF) {
                #pragma unroll
                for (int i = 0; i < 4; i++)
                    p.C[(long)bz * p.sC + (long)(row0 + i) * p.ldc + col] = v[i];
            }
            if (OP) {
                #pragma unroll
                for (int i = 0; i < 4; i++) {
                    u16 h, l; cvt2(v[i], h, l);
                    p.Ch[(long)bz * p.sP + (long)(row0 + i) * p.ldp + col] = h;
                    p.Cl[(long)bz * p.sP + (long)(row0 + i) * p.ldp + col] = l;
                }
            }
            if (OPT) {
                u16 h0,h1,h2,h3,l0,l1,l2,l3;
                cvt2(v[0],h0,l0); cvt2(v[1],h1,l1); cvt2(v[2],h2,l2); cvt2(v[3],h3,l3);
                ushort4 hv = {h0,h1,h2,h3}, lv = {l0,l1,l2,l3};
                *(ushort4*)&p.ChT[(long)bz * p.sCt + (long)col * p.ldct + row0] = hv;
                *(ushort4*)&p.ClT[(long)bz * p.sCt + (long)col * p.ldct + row0] = lv;
            }
            if (OFT) {
                float4 o4 = make_float4(v[0], v[1], v[2], v[3]);
                *(float4*)&p.CF[(long)bz * p.sCF + (long)col * 256 + row0] = o4;
            }
        }
    }
}

// ---------------- host ----------------

extern "C" void kernel_launch(void* const* d_in, const int* in_sizes, int n_in,
                              void* d_out, int out_size, void* d_ws, size_t ws_size,
                              hipStream_t stream) {
    const float* Kuu       = (const float*)d_in[0];
    const float* Kuf       = (const float*)d_in[1];
    const float* Kff       = (const float*)d_in[2];
    const float* Lloc      = (const float*)d_in[3];
    const float* Lscale    = (const float*)d_in[4];
    const float* u_param   = (const float*)d_in[5];
    const float* noise_inv = (const float*)d_in[6];
    const float* noise_L   = (const float*)d_in[7];
    const float* noise_f   = (const float*)d_in[8];
    float* out = (float*)d_out;
    float* ws  = (float*)d_ws;

    const long BIG = (long)S_ * MM_;     // 1,048,576 elements
    long off = 1024;
    float* part = ws + 16;

    #define PAIR(NAME, E) u16* NAME##h = (u16*)(ws + off); u16* NAME##l = NAME##h + (E); off += (E);
    PAIR(LS, 65536)
    PAIR(LtS, 65536)
    PAIR(upS, 65536)
    PAIR(W1S, 65536)
    float* UPT   = ws + off; off += 65536;
    float* VfAcc = ws + off; off += 65536;
    PAIR(KuuS, BIG)
    PAIR(ninvS, BIG)
    PAIR(nLS, BIG)
    float* cholK = ws + off; off += 2 * BIG;   // 32 matrices contiguous
    float* choll = cholK + BIG;
    PAIR(KuuLS, BIG)
    PAIR(KuuLtS, BIG)
    PAIR(TtS, 2 * BIG)             // T^T pair, 32 matrices  (zeroed in mega)
    PAIR(TKrS, 2 * BIG)            // T row-major pair, 32 matrices (zeroed in mega)
    PAIR(G3TS, BIG)                // (KuuInv @ U)^T pair
    PAIR(KIL, 2 * BIG)             // KuuInv (mats 0..15) | lKl (mats 16..31)
    PAIR(invS, 524288)             // 32 mats x 4 panels x 64x64 D pair
    PAIR(LfS, 2 * BIG)             // L strictly-lower pair, 32 matrices
    PAIR(StTS, 393216)             // S^T scratch pair, 32 x 192x64
    #undef PAIR

    u16* TKth = TtSh;                u16* TKtl = TtSl;
    u16* Tlth = TtSh + (long)S_ * MM_; u16* Tltl = TtSl + (long)S_ * MM_;
    u16* RHSTh   = KuuSh;            u16* RHSTl   = KuuSl;
    u16* UTph    = nLSh;             u16* UTpl    = nLSl;
    float* RHS1T = (float*)KuuLSh;
    u16* Sigmah  = KuuLtSh;          u16* Sigmal  = KuuLtSl;
    u16* KuuInvh = KILh;             u16* KuuInvl = KILl;
    u16* lKlh    = KILh + (long)S_ * MM_; u16* lKll = KILl + (long)S_ * MM_;

    long navail = (long)(ws_size / 4) - off;
    long nfc_l = navail / 4096;                 // only KufT pair per chunk
    int nfc = (int)((nfc_l / 128) * 128);
    if (nfc > NF_) nfc = NF_;
    if (nfc < 128) nfc = 128;
    long Ec = (long)S_ * nfc * 256;
    u16* KufTch = (u16*)(ws + off);      u16* KufTcl = KufTch + Ec;

    dim3 b256(256);

    max1_kernel<<<256, b256, 0, stream>>>(Kuu, S_ * MM_, part);
    max2prep_kernel<<<2, b256, 0, stream>>>(part, Lloc, Lscale, ws);

    splitjit_kernel<<<1024, b256, 0, stream>>>(Kuu, ws, KuuSh, KuuSl, cholK);
    psplit_kernel<<<64, b256, 0, stream>>>(Lloc, LSh, LSl, 65536, ws + 1);
    tsplit_kernel<<<dim3(8, 8, 1), b256, 0, stream>>>(Lloc, 256, 0, LtSh, LtSl, 256, 0, ws + 1);

    PG q;
    auto clr = [&]() {
        q = PG{};
        q.lda = 256; q.ldb = 256; q.ldc = 256; q.ldct = 256; q.ldp = 256;
        q.alpha = 1.f; q.dcoef = 1.f;
        q.M = 256; q.N = 256; q.K = 256;
    };
    dim3 g64(4, 4, S_);
    dim3 g64b1(4, 4, 1);

    // a. KuuL = Kuu @ L -> pair + pairT
    clr(); q.Ah = KuuSh; q.Al = KuuSl; q.sA = MM_;
    q.Bh = LtSh; q.Bl = LtSl; q.sB = 0;
    q.Ch = KuuLSh; q.Cl = KuuLSl; q.sP = MM_;
    q.ChT = KuuLtSh; q.ClT = KuuLtSl; q.sCt = MM_;
    pgemm64_k<0,1,1,0,0,0,0><<<g64, b256, 0, stream>>>(q);

    // b. choll = KuuL^T @ L + I -> fp32
    clr(); q.Ah = KuuLtSh; q.Al = KuuLtSl; q.sA = MM_;
    q.Bh = LtSh; q.Bl = LtSl; q.sB = 0;
    q.C = choll; q.sC = MM_;
    pgemm64_k<1,0,0,0,0,0,1><<<g64, b256, 0, stream>>>(q);

    // MEGA: chol (32 blocks) + aux prep (224 blocks)
    int w0 = nfc;
    MAux ax;
    ax.Kuf = Kuf; ax.KTh = KufTch; ax.KTl = KufTcl; ax.w0 = w0;
    ax.ninv = noise_inv; ax.nih = ninvSh; ax.nil = ninvSl;
    ax.nLp = noise_L; ax.nLh2 = nLSh; ax.nLl2 = nLSl;
    ax.up = u_param; ax.uph2 = upSh; ax.upl2 = upSl;
    ax.z1 = (float*)TtSh; ax.z1n = 4 * BIG;      // Tt pair + TKr pair (contiguous)
    ax.z2 = VfAcc; ax.z2n = 65536;
    megachol_kernel<<<256, dim3(1024), 0, stream>>>(cholK, choll, ax);

    // ---- block-recursive triangular inverse via MFMA (+ lsplit merged) ----
    trilsp_kernel<<<dim3(7, 32), b256, 0, stream>>>(cholK, invSh, invSl,
                                                    TtSh, TtSl, TKrSh, TKrSl,
                                                    LfSh, LfSl);

    for (int i = 1; i < 4; i++) {
        clr(); q.M = 64; q.N = 64 * i; q.K = 64 * i;
        q.Ah = LfSh + (long)64 * i * 256; q.Al = LfSl + (long)64 * i * 256;
        q.lda = 256; q.sA = MM_;
        q.Bh = TtSh; q.Bl = TtSl; q.ldb = 256; q.sB = MM_;
        q.ChT = StTSh; q.ClT = StTSl; q.ldct = 64; q.sCt = 12288;
        pgemm64_k<0,0,1,0,0,0,0><<<dim3(i, 1, 32), b256, 0, stream>>>(q);
        clr(); q.M = 64; q.N = 64 * i; q.K = 64;
        q.Ah = invSh + (long)i * 4096; q.Al = invSl + (long)i * 4096;
        q.lda = 64; q.sA = 16384;
        q.Bh = StTSh; q.Bl = StTSl; q.ldb = 64; q.sB = 12288;
        q.alpha = -1.f;
        q.Ch = TKrSh + (long)64 * i * 256; q.Cl = TKrSl + (long)64 * i * 256;
        q.ldp = 256; q.sP = MM_;
        q.ChT = TtSh + 64 * i; q.ClT = TtSl + 64 * i; q.ldct = 256; q.sCt = MM_;
        pgemm64_k<0,1,1,0,0,0,0><<<dim3(i, 1, 32), b256, 0, stream>>>(q);
    }

    // c2+d merged: [KuuInv | lKl] = Tt @ Tt^T over all 32 matrices
    clr(); q.Ah = TtSh; q.Al = TtSl; q.sA = MM_;
    q.Bh = TtSh; q.Bl = TtSl; q.sB = MM_;
    q.Ch = KILh; q.Cl = KILl; q.sP = MM_;
    pgemm64_k<0,1,0,0,0,0,0><<<dim3(4, 4, 32), b256, 0, stream>>>(q);

    // e. Stmp = KuuL @ lKlpIi -> pair (into Tlt region, dead after c2d)
    u16* Stmph = Tlth; u16* Stmpl = Tltl;
    clr(); q.Ah = KuuLSh; q.Al = KuuLSl; q.sA = MM_;
    q.Bh = lKlh; q.Bl = lKll; q.sB = MM_;
    q.Ch = Stmph; q.Cl = Stmpl; q.sP = MM_;
    pgemm64_k<0,1,0,0,0,0,0><<<g64, b256, 0, stream>>>(q);

    // f. Sigma = Kuu - Stmp @ KuuL^T -> pair
    clr(); q.Ah = Stmph; q.Al = Stmpl; q.sA = MM_;
    q.Bh = KuuLSh; q.Bl = KuuLSl; q.sB = MM_;
    q.Ch = Sigmah; q.Cl = Sigmal; q.sP = MM_;
    q.D = Kuu; q.sD = MM_; q.alpha = -1.f;
    pgemm64_k<0,1,0,0,0,1,0><<<g64, b256, 0, stream>>>(q);

    // g. W1 = up @ L -> pair (batch 1)
    clr(); q.Ah = upSh; q.Al = upSl; q.sA = 0;
    q.Bh = LtSh; q.Bl = LtSl; q.sB = 0;
    q.Ch = W1Sh; q.Cl = W1Sl; q.sP = 0;
    pgemm64_k<0,1,0,0,0,0,0><<<g64b1, b256, 0, stream>>>(q);

    // h. UPT = W1 @ L^T -> fp32 (batch 1)
    clr(); q.Ah = W1Sh; q.Al = W1Sl; q.sA = 0;
    q.Bh = LSh; q.Bl = LSl; q.sB = 0;
    q.C = UPT; q.sC = 0;
    pgemm64_k<1,0,0,0,0,0,0><<<g64b1, b256, 0, stream>>>(q);

    // i. RHS1T = ninv @ TK + UPT -> fp32
    clr(); q.Ah = ninvSh; q.Al = ninvSl; q.sA = 65536;
    q.Bh = TKth; q.Bl = TKtl; q.sB = MM_;
    q.C = RHS1T; q.sC = MM_;
    q.D = UPT; q.sD = 0;
    pgemm64_k<1,0,0,0,0,1,0><<<g64, b256, 0, stream>>>(q);

    // j. RHST = nL @ L^T + RHS1T -> pair
    clr(); q.Ah = nLSh; q.Al = nLSl; q.sA = 65536;
    q.Bh = LSh; q.Bl = LSl; q.sB = 0;
    q.C = RHS1T; q.sC = MM_;
    q.Ch = RHSTh; q.Cl = RHSTl; q.sP = MM_;
    pgemm64_k<0,1,0,0,1,0,0><<<g64, b256, 0, stream>>>(q);

    // k. UT = RHST @ Sigma -> pair + transposed fp32 direct into out rows 0..255
    clr(); q.Ah = RHSTh; q.Al = RHSTl; q.sA = MM_;
    q.Bh = Sigmah; q.Bl = Sigmal; q.sB = MM_;
    q.Ch = UTph; q.Cl = UTpl; q.sP = MM_;
    q.CF = out; q.sCF = (long)ROWS_ * OUT_;
    pgemm64_k<0,1,0,1,0,0,0><<<g64, b256, 0, stream>>>(q);

    // G3T = UTp @ KuuInv -> pair
    clr(); q.Ah = UTph; q.Al = UTpl; q.sA = MM_;
    q.Bh = KuuInvh; q.Bl = KuuInvl; q.sB = MM_;
    q.Ch = G3TSh; q.Cl = G3TSl; q.sP = MM_;
    pgemm64_k<0,1,0,0,0,0,0><<<g64, b256, 0, stream>>>(q);

    for (int f0 = 0; f0 < NF_; f0 += nfc) {
        int w = NF_ - f0; if (w > nfc) w = nfc;
        if (f0 > 0)    // chunk 0 transposed inside megachol
            tsplit_kernel<<<dim3(w / 32, 8, S_), b256, 0, stream>>>(
                Kuf + f0, NF_, (long)M_ * NF_, KufTch, KufTcl, 256, (long)w * 256, nullptr);
        // Vf-GEMM: H' = KufT @ TK^T (lower-tri B: K capped), VfAcc row sums of squares
        clr(); q.M = w; q.N = 256;
        q.Ah = KufTch; q.Al = KufTcl; q.sA = (long)w * 256;
        q.Bh = TKrSh; q.Bl = TKrSl; q.sB = MM_;
        q.vfacc = VfAcc + f0; q.sVf = NF_;
        pgemm_k<0,0,0,0,0,0,0,1,1><<<dim3(2, w / 128, S_), b256, 0, stream>>>(q);
        // Ef-GEMM: out_f = KufT @ G3T^T + sqrt(Kff - VfAcc)*noise_f
        clr(); q.M = w; q.N = 256;
        q.Ah = KufTch; q.Al = KufTcl; q.sA = (long)w * 256;
        q.Bh = G3TSh; q.Bl = G3TSl; q.sB = MM_;
        q.C = out + (long)(M_ + f0) * OUT_; q.sC = (long)ROWS_ * OUT_;
        q.kff = Kff + f0; q.vfacc = VfAcc + f0; q.sVf = NF_;
        q.noise = noise_f + (long)f0 * OUT_; q.sNoise = (long)NF_ * OUT_;
        pgemm_k<1,0,0,0,0,0,1,0,0><<<dim3(2, w / 128, S_), b256, 0, stream>>>(q);
    }
}

// Round 19
// 403.869 us; speedup vs baseline: 1.4019x; 1.0878x over previous
//
#include <hip/hip_runtime.h>
#include <math.h>

#define S_ 16
#define M_ 256
#define NF_ 4096
#define OUT_ 256
#define ROWS_ (M_ + NF_)     // 4352
#define MM_ (M_ * M_)        // 65536

typedef unsigned short u16;
typedef __attribute__((ext_vector_type(8))) short bf16x8;
typedef __attribute__((ext_vector_type(4))) float f32x4;

__device__ __forceinline__ void cvt2(float x, u16& h, u16& l) {
    unsigned xb = __float_as_uint(x);
    unsigned hb = (xb + 0x7fffu + ((xb >> 16) & 1u)) >> 16;
    float fh = __uint_as_float(hb << 16);
    float rr = x - fh;
    unsigned rb = __float_as_uint(rr);
    unsigned lb = (rb + 0x7fffu + ((rb >> 16) & 1u)) >> 16;
    h = (u16)hb; l = (u16)lb;
}

// ---------------- small prep kernels ----------------

// L scale -> ws[1]
__global__ void prep_kernel(const float* __restrict__ Lloc, const float* __restrict__ Lscale,
                            float* ws) {
    __shared__ float red[256];
    int tid = threadIdx.x;
    red[tid] = Lloc[tid * M_ + tid];
    __syncthreads();
    for (int s = 128; s > 0; s >>= 1) {
        if (tid < s) red[tid] += red[tid + s];
        __syncthreads();
    }
    if (tid == 0) {
        float norm = red[0] / (float)M_;
        ws[1] = expf(Lscale[0]) / norm;
    }
}

// ---- plain split ----
__global__ void psplit_kernel(const float* __restrict__ src, u16* __restrict__ h,
                              u16* __restrict__ l, long n, const float* scaleptr) {
    float sc = scaleptr ? scaleptr[0] : 1.0f;
    long stride = (long)gridDim.x * blockDim.x * 4;
    for (long i = ((long)blockIdx.x * blockDim.x + threadIdx.x) * 4; i < n; i += stride) {
        float4 v = *(const float4*)(src + i);
        u16 h0,h1,h2,h3,l0,l1,l2,l3;
        cvt2(v.x*sc,h0,l0); cvt2(v.y*sc,h1,l1); cvt2(v.z*sc,h2,l2); cvt2(v.w*sc,h3,l3);
        ushort4 hv = {h0,h1,h2,h3}, lv = {l0,l1,l2,l3};
        *(ushort4*)(h + i) = hv;
        *(ushort4*)(l + i) = lv;
    }
}

// ---- fused Kuu split + copy for Cholesky (jitter dropped: Kuu has +0.1 I) ----
__global__ void splitjit_kernel(const float* __restrict__ Kuu,
                                u16* __restrict__ h, u16* __restrict__ l,
                                float* __restrict__ dst) {
    long i = ((long)blockIdx.x * blockDim.x + threadIdx.x) * 4;
    if (i < (long)S_ * MM_) {
        float4 v = *(const float4*)(Kuu + i);
        u16 h0,h1,h2,h3,l0,l1,l2,l3;
        cvt2(v.x,h0,l0); cvt2(v.y,h1,l1); cvt2(v.z,h2,l2); cvt2(v.w,h3,l3);
        ushort4 hv = {h0,h1,h2,h3}, lv = {l0,l1,l2,l3};
        *(ushort4*)(h + i) = hv;
        *(ushort4*)(l + i) = lv;
        *(float4*)(dst + i) = v;
    }
}

// ---- transpose split (used for L^T and tail chunks beyond chunk 0) ----
__global__ void tsplit_kernel(const float* __restrict__ src, int ldS, long sS,
                              u16* __restrict__ h, u16* __restrict__ l, int ldD, long sD,
                              const float* scaleptr) {
    int b = blockIdx.z;
    src += (long)b * sS; h += (long)b * sD; l += (long)b * sD;
    __shared__ float T[32][33];
    int r0 = blockIdx.y * 32, c0 = blockIdx.x * 32;
    float sc = scaleptr ? scaleptr[0] : 1.0f;
    int tid = threadIdx.x;
    int lrow = tid >> 3, lc4 = (tid & 7) * 4;
    float4 v = *(const float4*)(src + (long)(r0 + lrow) * ldS + c0 + lc4);
    T[lrow][lc4 + 0] = v.x * sc; T[lrow][lc4 + 1] = v.y * sc;
    T[lrow][lc4 + 2] = v.z * sc; T[lrow][lc4 + 3] = v.w * sc;
    __syncthreads();
    int wcol = tid >> 3, wr4 = (tid & 7) * 4;
    u16 h0,h1,h2,h3,l0,l1,l2,l3;
    cvt2(T[wr4+0][wcol],h0,l0); cvt2(T[wr4+1][wcol],h1,l1);
    cvt2(T[wr4+2][wcol],h2,l2); cvt2(T[wr4+3][wcol],h3,l3);
    ushort4 hv = {h0,h1,h2,h3}, lv = {l0,l1,l2,l3};
    *(ushort4*)(h + (long)(c0 + wcol) * ldD + r0 + wr4) = hv;
    *(ushort4*)(l + (long)(c0 + wcol) * ldD + r0 + wr4) = lv;
}

__device__ __forceinline__ void psplit_dev(const float* __restrict__ src, u16* __restrict__ h,
                                           u16* __restrict__ l, long n, long b0, long stp) {
    for (long i = b0 * 4; i < n; i += stp * 4) {
        float4 v = *(const float4*)(src + i);
        u16 h0,h1,h2,h3,l0,l1,l2,l3;
        cvt2(v.x,h0,l0); cvt2(v.y,h1,l1); cvt2(v.z,h2,l2); cvt2(v.w,h3,l3);
        ushort4 hv = {h0,h1,h2,h3}, lv = {l0,l1,l2,l3};
        *(ushort4*)(h + i) = hv;
        *(ushort4*)(l + i) = lv;
    }
}

// ---------------- MEGA: chol (blocks 0..31) + independent prep (blocks 32+) ----------------

struct MAux {
    const float* Kuf; u16 *KTh, *KTl; int w0;
    const float* ninv; u16 *nih, *nil;
    const float* nLp;  u16 *nLh2, *nLl2;
    const float* up;   u16 *uph2, *upl2;
    float* z1; long z1n;       // Tt+TKr zero region (floats)
    float* z2; long z2n;       // VfAcc
};

__global__ __launch_bounds__(1024) void megachol_kernel(float* bufA, float* bufB, MAux ax) {
    __shared__ float P[33280];
    __shared__ float pan2[256 * 20];
    __shared__ float piv[16][18];

    if (blockIdx.x < 32) {
        // -------- chol body (blk = blockIdx.x) --------
        int blk = blockIdx.x;
        float* Ag = (blk < S_) ? (bufA + (long)blk * MM_) : (bufB + (long)(blk - S_) * MM_);
        float4* P4 = (float4*)P;
        int tid = threadIdx.x;
        int r = tid >> 2, s = tid & 3;
        int lane = tid & 63, wid = tid >> 6;
        int mg = r >> 2, tg = r & 3;
        int b4 = (mg + 1) * (2 * mg + tg);

        for (int i = wid; i < M_; i += 16) {
            int m = i >> 2, t4 = i & 3;
            int rb4 = (m + 1) * (2 * m + t4);
            if (lane <= m) P4[rb4 + lane] = ((const float4*)Ag)[i * 64 + lane];
        }
        __syncthreads();

        float preg[16];
        for (int p = 0; p < 16; p++) {
            int k0 = p << 4;
            int c0 = p << 2;
            #pragma unroll
            for (int rr = 0; rr < 4; rr++) {
                float4 v = make_float4(0.f, 0.f, 0.f, 0.f);
                if (r >= k0 && c0 + rr <= mg) v = P4[b4 + c0 + rr];
                preg[4 * rr + 0] = v.x; preg[4 * rr + 1] = v.y;
                preg[4 * rr + 2] = v.z; preg[4 * rr + 3] = v.w;
            }
            if (wid == p) {
                int dj = lane >> 2;
                float myinv = 0.f;
                #pragma unroll
                for (int j = 0; j < 16; j++) {
                    float app = __shfl(preg[j], 4 * j, 64);
                    float d = sqrtf(app);
                    float inv = 1.0f / d;
                    if (dj == j) { preg[j] = d; myinv = inv; }
                    else if (dj > j) preg[j] *= inv;
                    #pragma unroll
                    for (int j2 = j + 1; j2 < 16; j2++) {
                        float Lj2 = __shfl(preg[j], 4 * j2, 64);
                        if (dj >= j2) preg[j2] -= preg[j] * Lj2;
                    }
                }
                if (s == 0) {
                    #pragma unroll
                    for (int i = 0; i < 16; i++) piv[dj][i] = preg[i];
                    piv[dj][16] = myinv;
                }
            }
            __syncthreads();
            if (r > k0 + 15) {
                float x[16];
                #pragma unroll
                for (int j = 0; j < 16; j++) {
                    float acc = preg[j];
                    #pragma unroll
                    for (int i = 0; i < 16; i++)
                        if (i < j) acc -= x[i] * piv[j][i];
                    x[j] = acc * piv[j][16];
                }
                #pragma unroll
                for (int j = 0; j < 16; j++) preg[j] = x[j];
            }
            if (r >= k0) {
                float4 pv = make_float4(preg[4 * s], preg[4 * s + 1],
                                        preg[4 * s + 2], preg[4 * s + 3]);
                *(float4*)&pan2[r * 20 + 4 * s] = pv;
                int c = c0 + s;
                if (c <= mg) P4[b4 + c] = pv;
            }
            __syncthreads();
            {
                int cs = tid >> 4;
                int j  = tid & 15;
                if (cs >= c0 + 4) {
                    float4 q0[4], q1[4], q2[4], q3[4];
                    #pragma unroll
                    for (int e = 0; e < 4; e++) {
                        const float4* pr = (const float4*)&pan2[(4 * cs + e) * 20];
                        q0[e] = pr[0]; q1[e] = pr[1]; q2[e] = pr[2]; q3[e] = pr[3];
                    }
                    int rr = k0 + 16 + j;
                    int rmin = 4 * cs;
                    while (rr < rmin) rr += 16;
                    for (; rr < 256; rr += 16) {
                        int mgr = rr >> 2, tgr = rr & 3;
                        int rb4 = (mgr + 1) * (2 * mgr + tgr);
                        const float4* ar = (const float4*)&pan2[rr * 20];
                        float4 a0 = ar[0], a1 = ar[1], a2 = ar[2], a3 = ar[3];
                        float rv[4];
                        *(float4*)rv = P4[rb4 + cs];
                        #pragma unroll
                        for (int e = 0; e < 4; e++) {
                            float acc;
                            acc  = a0.x*q0[e].x + a0.y*q0[e].y + a0.z*q0[e].z + a0.w*q0[e].w;
                            acc += a1.x*q1[e].x + a1.y*q1[e].y + a1.z*q1[e].z + a1.w*q1[e].w;
                            acc += a2.x*q2[e].x + a2.y*q2[e].y + a2.z*q2[e].z + a2.w*q2[e].w;
                            acc += a3.x*q3[e].x + a3.y*q3[e].y + a3.z*q3[e].z + a3.w*q3[e].w;
                            rv[e] -= acc;
                        }
                        P4[rb4 + cs] = *(float4*)rv;
                    }
                }
            }
            __syncthreads();
        }

        for (int i = wid; i < M_; i += 16) {
            int m = i >> 2, t4 = i & 3;
            int rb4 = (m + 1) * (2 * m + t4);
            if (lane <= m) ((float4*)Ag)[i * 64 + lane] = P4[rb4 + lane];
        }
        return;
    }

    // -------- aux path: independent prep work on idle CUs --------
    int ab = blockIdx.x - 32, NA = gridDim.x - 32;
    int tid = threadIdx.x;
    long b0 = (long)ab * 1024 + tid, stp = (long)NA * 1024;
    float4 z = make_float4(0.f, 0.f, 0.f, 0.f);
    long n4 = ax.z1n >> 2;
    for (long i = b0; i < n4; i += stp) ((float4*)ax.z1)[i] = z;
    long m4 = ax.z2n >> 2;
    for (long i = b0; i < m4; i += stp) ((float4*)ax.z2)[i] = z;
    psplit_dev(ax.ninv, ax.nih, ax.nil, (long)S_ * MM_, b0, stp);
    psplit_dev(ax.nLp, ax.nLh2, ax.nLl2, (long)S_ * MM_, b0, stp);
    psplit_dev(ax.up, ax.uph2, ax.upl2, 65536, b0, stp);

    int grp = tid >> 8, t = tid & 255;
    float* Tls = P + grp * 1056;
    int nx = ax.w0 >> 5;
    int ntile = nx * 8 * S_;
    int per = NA * 4;
    int iters = (ntile + per - 1) / per;
    long sS = (long)M_ * NF_, sD = (long)ax.w0 * 256;
    for (int it = 0; it < iters; it++) {
        int tile = ab * 4 + grp + it * per;
        bool ok = tile < ntile;
        int r0 = 0, c0 = 0, b = 0;
        if (ok) {
            int cx = tile % nx; int rest = tile / nx;
            int cy = rest & 7; b = rest >> 3;
            r0 = cy * 32; c0 = cx * 32;
        }
        if (ok) {
            int lrow = t >> 3, lc4 = (t & 7) * 4;
            float4 v = *(const float4*)(ax.Kuf + (long)b * sS + (long)(r0 + lrow) * NF_ + c0 + lc4);
            Tls[lrow * 33 + lc4 + 0] = v.x; Tls[lrow * 33 + lc4 + 1] = v.y;
            Tls[lrow * 33 + lc4 + 2] = v.z; Tls[lrow * 33 + lc4 + 3] = v.w;
        }
        __syncthreads();
        if (ok) {
            int wcol = t >> 3, wr4 = (t & 7) * 4;
            u16 h0,h1,h2,h3,l0,l1,l2,l3;
            cvt2(Tls[(wr4+0)*33+wcol],h0,l0); cvt2(Tls[(wr4+1)*33+wcol],h1,l1);
            cvt2(Tls[(wr4+2)*33+wcol],h2,l2); cvt2(Tls[(wr4+3)*33+wcol],h3,l3);
            ushort4 hv = {h0,h1,h2,h3}, lv = {l0,l1,l2,l3};
            long o = (long)b * sD + (long)(c0 + wcol) * 256 + r0 + wr4;
            *(ushort4*)(ax.KTh + o) = hv;
            *(ushort4*)(ax.KTl + o) = lv;
        }
        __syncthreads();
    }
}

// ---------------- merged: 64x64 diag triangular inverse (bx<4) + lsplit (bx>=4) ----------------

__global__ __launch_bounds__(256) void trilsp_kernel(const float* W0,
                                                     u16* invh, u16* invl,
                                                     u16* Tth, u16* Ttl,
                                                     u16* TKrh, u16* TKrl,
                                                     u16* Lh, u16* Ll) {
    __shared__ float X[64 * 65];
    __shared__ float pan[64 * 20];
    int mat = blockIdx.y;      // 0..31
    int tid = threadIdx.x;
    const float* W = W0 + (long)mat * MM_;

    if (blockIdx.x >= 4) {
        int p = blockIdx.x - 4;        // 0..2
        u16* dh = Lh + (long)mat * MM_;
        u16* dl = Ll + (long)mat * MM_;
        int d0 = 64 * p, nrows = 192 - d0;
        for (int idx = tid; idx < nrows * 16; idx += 256) {
            int r = idx >> 4, c4 = idx & 15;
            long o = (long)(d0 + 64 + r) * 256 + d0 + 4 * c4;
            float4 v = *(const float4*)(W + o);
            u16 h0,h1,h2,h3,l0,l1,l2,l3;
            cvt2(v.x,h0,l0); cvt2(v.y,h1,l1); cvt2(v.z,h2,l2); cvt2(v.w,h3,l3);
            ushort4 hv = {h0,h1,h2,h3}, lv = {l0,l1,l2,l3};
            *(ushort4*)(dh + o) = hv;
            *(ushort4*)(dl + o) = lv;
        }
        return;
    }

    int p = blockIdx.x;        // 0..3
    int d0 = p * 64;
    int c = tid & 63, q = tid >> 6;
    for (int idx = tid; idx < 64 * 65; idx += 256) X[idx] = 0.f;
    __syncthreads();
    if (q == 0) X[c * 65 + c] = 1.0f;
    for (int pp = 0; pp < 4; pp++) {
        int t0 = pp << 4;
        for (int idx = tid; idx < 64 * 4; idx += 256) {
            int k = idx >> 2, e = idx & 3;
            if (k >= t0)
                ((float4*)(pan + k * 20))[e] =
                    *(const float4*)(W + (long)(d0 + k) * 256 + d0 + t0 + 4 * e);
        }
        __syncthreads();
        if (q == pp) {
            float xr[16];
            #pragma unroll
            for (int j = 0; j < 16; j++) {
                float xv = X[(t0 + j) * 65 + c];
                #pragma unroll
                for (int i = 0; i < 16; i++)
                    if (i < j) xv -= pan[(t0 + j) * 20 + i] * xr[i];
                xv *= (1.0f / pan[(t0 + j) * 20 + j]);
                xr[j] = xv;
                X[(t0 + j) * 65 + c] = xv;
            }
        }
        __syncthreads();
        int kbeg = q << 4; if (kbeg < t0 + 16) kbeg = t0 + 16;
        int kend = (q << 4) + 16;
        if (kbeg < kend) {
            float xr[16];
            #pragma unroll
            for (int j = 0; j < 16; j++) xr[j] = X[(t0 + j) * 65 + c];
            for (int kk = kbeg; kk < kend; kk++) {
                float rv = X[kk * 65 + c];
                const float4* pr = (const float4*)&pan[kk * 20];
                float4 a = pr[0], b = pr[1], d = pr[2], e = pr[3];
                rv -= a.x * xr[0] + a.y * xr[1] + a.z * xr[2] + a.w * xr[3];
                rv -= b.x * xr[4] + b.y * xr[5] + b.z * xr[6] + b.w * xr[7];
                rv -= d.x * xr[8] + d.y * xr[9] + d.z * xr[10] + d.w * xr[11];
                rv -= e.x * xr[12] + e.y * xr[13] + e.z * xr[14] + e.w * xr[15];
                X[kk * 65 + c] = rv;
            }
        }
        __syncthreads();
    }
    for (int idx = tid; idx < 4096; idx += 256) {
        int r = idx >> 6, k = idx & 63;
        u16 h, l; cvt2(X[r * 65 + k], h, l);
        long io = (long)mat * 16384 + (long)p * 4096 + idx;
        invh[io] = h; invl[io] = l;
        long ro = (long)mat * MM_ + (long)(d0 + r) * 256 + d0 + k;
        TKrh[ro] = h; TKrl[ro] = l;
        long to = (long)mat * MM_ + (long)(d0 + k) * 256 + d0 + r;
        Tth[to] = h; Ttl[to] = l;
    }
}

// ---------------- pair GEMM: C = alpha * A @ B^T(storage) + epilogue ----------------

struct PG {
    const u16 *Ah, *Al, *Bh, *Bl;
    float* C; u16 *Ch, *Cl, *ChT, *ClT;
    float* CF;                      // transposed fp32 out
    const float* D; const float* noise;
    const float* kff; float* vfacc;
    int M, N, K, lda, ldb, ldc, ldct, ldp;
    long sA, sB, sC, sP, sCt, sD, sVf, sNoise, sCF;
    float alpha, dcoef;
};

// 128x128 tile, 4 waves (K = 256; TRIf: K capped at bn+128 for lower-tri B)
template<int OF, int OP, int OPT, int ACCf, int Df, int ADDIf, int EFf, int VFf, int TRIf>
__global__ __launch_bounds__(256) void pgemm_k(PG p) {
    int bz = blockIdx.z;
    const u16* Agh = p.Ah + (long)bz * p.sA;
    const u16* Agl = p.Al + (long)bz * p.sA;
    const u16* Bgh = p.Bh + (long)bz * p.sB;
    const u16* Bgl = p.Bl + (long)bz * p.sB;
    int bm = blockIdx.y * 128, bn = blockIdx.x * 128;
    __shared__ __align__(16) u16 sAh[128][40];
    __shared__ __align__(16) u16 sAl[128][40];
    __shared__ __align__(16) u16 sBh[128][40];
    __shared__ __align__(16) u16 sBl[128][40];
    int tid = threadIdx.x, lane = tid & 63, wid = tid >> 6;
    int wm = (wid >> 1) * 64, wn = (wid & 1) * 64;
    int fr = lane & 15, ko = (lane >> 4) * 8;
    int kb = tid & 3, rw = tid >> 2;
    f32x4 acc[4][4];
    #pragma unroll
    for (int m = 0; m < 4; m++)
        #pragma unroll
        for (int n = 0; n < 4; n++)
            acc[m][n] = (f32x4){0.f, 0.f, 0.f, 0.f};

    int klim = TRIf ? (bn + 128) : 256;
    for (int k0 = 0; k0 < klim; k0 += 32) {
        #define STG(SRC, LD, BASE, DST) \
            *(bf16x8*)&DST[rw][kb * 8] = \
                *(const bf16x8*)(SRC + (long)(BASE + rw) * LD + k0 + kb * 8); \
            *(bf16x8*)&DST[rw + 64][kb * 8] = \
                *(const bf16x8*)(SRC + (long)(BASE + rw + 64) * LD + k0 + kb * 8);
        STG(Agh, p.lda, bm, sAh)
        STG(Agl, p.lda, bm, sAl)
        STG(Bgh, p.ldb, bn, sBh)
        STG(Bgl, p.ldb, bn, sBl)
        #undef STG
        __syncthreads();
        bf16x8 ah[4], al[4], bh[4], bl[4];
        #pragma unroll
        for (int m = 0; m < 4; m++) {
            ah[m] = *(const bf16x8*)&sAh[wm + m * 16 + fr][ko];
            al[m] = *(const bf16x8*)&sAl[wm + m * 16 + fr][ko];
        }
        #pragma unroll
        for (int n = 0; n < 4; n++) {
            bh[n] = *(const bf16x8*)&sBh[wn + n * 16 + fr][ko];
            bl[n] = *(const bf16x8*)&sBl[wn + n * 16 + fr][ko];
        }
        #pragma unroll
        for (int m = 0; m < 4; m++)
            #pragma unroll
            for (int n = 0; n < 4; n++) {
                acc[m][n] = __builtin_amdgcn_mfma_f32_16x16x32_bf16(ah[m], bh[n], acc[m][n], 0, 0, 0);
                acc[m][n] = __builtin_amdgcn_mfma_f32_16x16x32_bf16(ah[m], bl[n], acc[m][n], 0, 0, 0);
                acc[m][n] = __builtin_amdgcn_mfma_f32_16x16x32_bf16(al[m], bh[n], acc[m][n], 0, 0, 0);
            }
        __syncthreads();
    }

    int rq = (lane >> 4) * 4;
    float rs[4][4];
    if (VFf) {
        #pragma unroll
        for (int m = 0; m < 4; m++)
            #pragma unroll
            for (int i = 0; i < 4; i++) rs[m][i] = 0.f;
    }
    #pragma unroll
    for (int m = 0; m < 4; m++) {
        int row0 = bm + wm + m * 16 + rq;
        #pragma unroll
        for (int n = 0; n < 4; n++) {
            int col = bn + wn + n * 16 + fr;
            float v[4];
            #pragma unroll
            for (int i = 0; i < 4; i++) {
                int r = row0 + i;
                float val = p.alpha * acc[m][n][i];
                if (Df)   val += p.dcoef * p.D[(long)bz * p.sD + (long)r * p.ldc + col];
                if (ACCf) val += p.C[(long)bz * p.sC + (long)r * p.ldc + col];
                if (ADDIf && r == col) val += 1.0f;
                if (EFf) {
                    float kf = p.kff[(long)bz * p.sVf + r];
                    float vq = p.vfacc[(long)bz * p.sVf + r];
                    val += sqrtf(fmaxf(kf - vq, 0.f)) *
                           p.noise[(long)bz * p.sNoise + (long)r * 256 + col];
                }
                v[i] = val;
                if (VFf) rs[m][i] += val * val;
            }
            if (OF) {
                #pragma unroll
                for (int i = 0; i < 4; i++)
                    p.C[(long)bz * p.sC + (long)(row0 + i) * p.ldc + col] = v[i];
            }
            if (OP) {
                #pragma unroll
                for (int i = 0; i < 4; i++) {
                    u16 h, l; cvt2(v[i], h, l);
                    p.Ch[(long)bz * p.sP + (long)(row0 + i) * p.ldc + col] = h;
                    p.Cl[(long)bz * p.sP + (long)(row0 + i) * p.ldc + col] = l;
                }
            }
            if (OPT) {
                u16 h0,h1,h2,h3,l0,l1,l2,l3;
                cvt2(v[0],h0,l0); cvt2(v[1],h1,l1); cvt2(v[2],h2,l2); cvt2(v[3],h3,l3);
                ushort4 hv = {h0,h1,h2,h3}, lv = {l0,l1,l2,l3};
                *(ushort4*)&p.ChT[(long)bz * p.sCt + (long)col * p.ldct + row0] = hv;
                *(ushort4*)&p.ClT[(long)bz * p.sCt + (long)col * p.ldct + row0] = lv;
            }
        }
    }
    if (VFf) {
        #pragma unroll
        for (int m = 0; m < 4; m++) {
            int row0 = bm + wm + m * 16 + rq;
            #pragma unroll
            for (int i = 0; i < 4; i++) {
                float t = rs[m][i];
                t += __shfl_xor(t, 1); t += __shfl_xor(t, 2);
                t += __shfl_xor(t, 4); t += __shfl_xor(t, 8);
                if (fr == 0)
                    atomicAdd(&p.vfacc[(long)bz * p.sVf + row0 + i], t);
            }
        }
    }
}

// 64x64 tile, 4 waves, runtime K (multiple of 32); OFT = transposed fp32 out
template<int OF, int OP, int OPT, int OFT, int ACCf, int Df, int ADDIf>
__global__ __launch_bounds__(256) void pgemm64_k(PG p) {
    int bz = blockIdx.z;
    const u16* Agh = p.Ah + (long)bz * p.sA;
    const u16* Agl = p.Al + (long)bz * p.sA;
    const u16* Bgh = p.Bh + (long)bz * p.sB;
    const u16* Bgl = p.Bl + (long)bz * p.sB;
    int bm = blockIdx.y * 64, bn = blockIdx.x * 64;
    __shared__ __align__(16) u16 sAh[64][40];
    __shared__ __align__(16) u16 sAl[64][40];
    __shared__ __align__(16) u16 sBh[64][40];
    __shared__ __align__(16) u16 sBl[64][40];
    int tid = threadIdx.x, lane = tid & 63, wid = tid >> 6;
    int wm = (wid >> 1) * 32, wn = (wid & 1) * 32;
    int fr = lane & 15, ko = (lane >> 4) * 8;
    int kb = tid & 3, rw = tid >> 2;
    f32x4 acc[2][2];
    #pragma unroll
    for (int m = 0; m < 2; m++)
        #pragma unroll
        for (int n = 0; n < 2; n++)
            acc[m][n] = (f32x4){0.f, 0.f, 0.f, 0.f};

    for (int k0 = 0; k0 < p.K; k0 += 32) {
        *(bf16x8*)&sAh[rw][kb * 8] = *(const bf16x8*)(Agh + (long)(bm + rw) * p.lda + k0 + kb * 8);
        *(bf16x8*)&sAl[rw][kb * 8] = *(const bf16x8*)(Agl + (long)(bm + rw) * p.lda + k0 + kb * 8);
        *(bf16x8*)&sBh[rw][kb * 8] = *(const bf16x8*)(Bgh + (long)(bn + rw) * p.ldb + k0 + kb * 8);
        *(bf16x8*)&sBl[rw][kb * 8] = *(const bf16x8*)(Bgl + (long)(bn + rw) * p.ldb + k0 + kb * 8);
        __syncthreads();
        bf16x8 ah[2], al[2], bh[2], bl[2];
        #pragma unroll
        for (int m = 0; m < 2; m++) {
            ah[m] = *(const bf16x8*)&sAh[wm + m * 16 + fr][ko];
            al[m] = *(const bf16x8*)&sAl[wm + m * 16 + fr][ko];
        }
        #pragma unroll
        for (int n = 0; n < 2; n++) {
            bh[n] = *(const bf16x8*)&sBh[wn + n * 16 + fr][ko];
            bl[n] = *(const bf16x8*)&sBl[wn + n * 16 + fr][ko];
        }
        #pragma unroll
        for (int m = 0; m < 2; m++)
            #pragma unroll
            for (int n = 0; n < 2; n++) {
                acc[m][n] = __builtin_amdgcn_mfma_f32_16x16x32_bf16(ah[m], bh[n], acc[m][n], 0, 0, 0);
                acc[m][n] = __builtin_amdgcn_mfma_f32_16x16x32_bf16(ah[m], bl[n], acc[m][n], 0, 0, 0);
                acc[m][n] = __builtin_amdgcn_mfma_f32_16x16x32_bf16(al[m], bh[n], acc[m][n], 0, 0, 0);
            }
        __syncthreads();
    }

    int rq = (lane >> 4) * 4;
    #pragma unroll
    for (int m = 0; m < 2; m++) {
        int row0 = bm + wm + m * 16 + rq;
        #pragma unroll
        for (int n = 0; n < 2; n++) {
            int col = bn + wn + n * 16 + fr;
            float v[4];
            #pragma unroll
            for (int i = 0; i < 4; i++) {
                int r = row0 + i;
                float val = p.alpha * acc[m][n][i];
                if (Df)   val += p.dcoef * p.D[(long)bz * p.sD + (long)r * p.ldc + col];
                if (ACCf) val += p.C[(long)bz * p.sC + (long)r * p.ldc + col];
                if (ADDIf && r == col) val += 1.0f;
                v[i] = val;
            }
            if (OF) {
                #pragma unroll
                for (int i = 0; i < 4; i++)
                    p.C[(long)bz * p.sC + (long)(row0 + i) * p.ldc + col] = v[i];
            }
            if (OP) {
                #pragma unroll
                for (int i = 0; i < 4; i++) {
                    u16 h, l; cvt2(v[i], h, l);
                    p.Ch[(long)bz * p.sP + (long)(row0 + i) * p.ldp + col] = h;
                    p.Cl[(long)bz * p.sP + (long)(row0 + i) * p.ldp + col] = l;
                }
            }
            if (OPT) {
                u16 h0,h1,h2,h3,l0,l1,l2,l3;
                cvt2(v[0],h0,l0); cvt2(v[1],h1,l1); cvt2(v[2],h2,l2); cvt2(v[3],h3,l3);
                ushort4 hv = {h0,h1,h2,h3}, lv = {l0,l1,l2,l3};
                *(ushort4*)&p.ChT[(long)bz * p.sCt + (long)col * p.ldct + row0] = hv;
                *(ushort4*)&p.ClT[(long)bz * p.sCt + (long)col * p.ldct + row0] = lv;
            }
            if (OFT) {
                float4 o4 = make_float4(v[0], v[1], v[2], v[3]);
                *(float4*)&p.CF[(long)bz * p.sCF + (long)col * 256 + row0] = o4;
            }
        }
    }
}

// ---------------- host ----------------

extern "C" void kernel_launch(void* const* d_in, const int* in_sizes, int n_in,
                              void* d_out, int out_size, void* d_ws, size_t ws_size,
                              hipStream_t stream) {
    const float* Kuu       = (const float*)d_in[0];
    const float* Kuf       = (const float*)d_in[1];
    const float* Kff       = (const float*)d_in[2];
    const float* Lloc      = (const float*)d_in[3];
    const float* Lscale    = (const float*)d_in[4];
    const float* u_param   = (const float*)d_in[5];
    const float* noise_inv = (const float*)d_in[6];
    const float* noise_L   = (const float*)d_in[7];
    const float* noise_f   = (const float*)d_in[8];
    float* out = (float*)d_out;
    float* ws  = (float*)d_ws;

    const long BIG = (long)S_ * MM_;     // 1,048,576 elements
    long off = 1024;

    #define PAIR(NAME, E) u16* NAME##h = (u16*)(ws + off); u16* NAME##l = NAME##h + (E); off += (E);
    PAIR(LS, 65536)
    PAIR(LtS, 65536)
    PAIR(upS, 65536)
    PAIR(W1S, 65536)
    float* UPT   = ws + off; off += 65536;
    float* VfAcc = ws + off; off += 65536;
    PAIR(KuuS, BIG)
    PAIR(ninvS, BIG)
    PAIR(nLS, BIG)
    float* cholK = ws + off; off += 2 * BIG;   // 32 matrices contiguous
    float* choll = cholK + BIG;
    PAIR(KuuLS, BIG)
    PAIR(KuuLtS, BIG)
    PAIR(TtS, 2 * BIG)             // T^T pair, 32 matrices  (zeroed in mega)
    PAIR(TKrS, 2 * BIG)            // T row-major pair, 32 matrices (zeroed in mega)
    PAIR(G3TS, BIG)                // (KuuInv @ U)^T pair
    PAIR(KIL, 2 * BIG)             // KuuInv (mats 0..15) | lKl (mats 16..31)
    PAIR(invS, 524288)             // 32 mats x 4 panels x 64x64 D pair
    PAIR(LfS, 2 * BIG)             // L strictly-lower pair, 32 matrices
    PAIR(StTS, 393216)             // S^T scratch pair, 32 x 192x64
    #undef PAIR

    u16* TKth = TtSh;                u16* TKtl = TtSl;
    u16* Tlth = TtSh + (long)S_ * MM_; u16* Tltl = TtSl + (long)S_ * MM_;
    u16* RHSTh   = KuuSh;            u16* RHSTl   = KuuSl;
    u16* UTph    = nLSh;             u16* UTpl    = nLSl;
    float* RHS1T = (float*)KuuLSh;
    u16* Sigmah  = KuuLtSh;          u16* Sigmal  = KuuLtSl;
    u16* KuuInvh = KILh;             u16* KuuInvl = KILl;
    u16* lKlh    = KILh + (long)S_ * MM_; u16* lKll = KILl + (long)S_ * MM_;

    long navail = (long)(ws_size / 4) - off;
    long nfc_l = navail / 4096;                 // only KufT pair per chunk
    int nfc = (int)((nfc_l / 128) * 128);
    if (nfc > NF_) nfc = NF_;
    if (nfc < 128) nfc = 128;
    long Ec = (long)S_ * nfc * 256;
    u16* KufTch = (u16*)(ws + off);      u16* KufTcl = KufTch + Ec;

    dim3 b256(256);

    prep_kernel<<<1, b256, 0, stream>>>(Lloc, Lscale, ws);

    splitjit_kernel<<<1024, b256, 0, stream>>>(Kuu, KuuSh, KuuSl, cholK);
    psplit_kernel<<<64, b256, 0, stream>>>(Lloc, LSh, LSl, 65536, ws + 1);
    tsplit_kernel<<<dim3(8, 8, 1), b256, 0, stream>>>(Lloc, 256, 0, LtSh, LtSl, 256, 0, ws + 1);

    PG q;
    auto clr = [&]() {
        q = PG{};
        q.lda = 256; q.ldb = 256; q.ldc = 256; q.ldct = 256; q.ldp = 256;
        q.alpha = 1.f; q.dcoef = 1.f;
        q.M = 256; q.N = 256; q.K = 256;
    };
    dim3 g64(4, 4, S_);
    dim3 g64b1(4, 4, 1);

    // a. KuuL = Kuu @ L -> pair + pairT
    clr(); q.Ah = KuuSh; q.Al = KuuSl; q.sA = MM_;
    q.Bh = LtSh; q.Bl = LtSl; q.sB = 0;
    q.Ch = KuuLSh; q.Cl = KuuLSl; q.sP = MM_;
    q.ChT = KuuLtSh; q.ClT = KuuLtSl; q.sCt = MM_;
    pgemm64_k<0,1,1,0,0,0,0><<<g64, b256, 0, stream>>>(q);

    // b. choll = KuuL^T @ L + I -> fp32
    clr(); q.Ah = KuuLtSh; q.Al = KuuLtSl; q.sA = MM_;
    q.Bh = LtSh; q.Bl = LtSl; q.sB = 0;
    q.C = choll; q.sC = MM_;
    pgemm64_k<1,0,0,0,0,0,1><<<g64, b256, 0, stream>>>(q);

    // MEGA: chol (32 blocks) + aux prep (224 blocks)
    int w0 = nfc;
    MAux ax;
    ax.Kuf = Kuf; ax.KTh = KufTch; ax.KTl = KufTcl; ax.w0 = w0;
    ax.ninv = noise_inv; ax.nih = ninvSh; ax.nil = ninvSl;
    ax.nLp = noise_L; ax.nLh2 = nLSh; ax.nLl2 = nLSl;
    ax.up = u_param; ax.uph2 = upSh; ax.upl2 = upSl;
    ax.z1 = (float*)TtSh; ax.z1n = 4 * BIG;      // Tt pair + TKr pair (contiguous)
    ax.z2 = VfAcc; ax.z2n = 65536;
    megachol_kernel<<<256, dim3(1024), 0, stream>>>(cholK, choll, ax);

    // ---- block-recursive triangular inverse via MFMA (+ lsplit merged) ----
    trilsp_kernel<<<dim3(7, 32), b256, 0, stream>>>(cholK, invSh, invSl,
                                                    TtSh, TtSl, TKrSh, TKrSl,
                                                    LfSh, LfSl);

    for (int i = 1; i < 4; i++) {
        clr(); q.M = 64; q.N = 64 * i; q.K = 64 * i;
        q.Ah = LfSh + (long)64 * i * 256; q.Al = LfSl + (long)64 * i * 256;
        q.lda = 256; q.sA = MM_;
        q.Bh = TtSh; q.Bl = TtSl; q.ldb = 256; q.sB = MM_;
        q.ChT = StTSh; q.ClT = StTSl; q.ldct = 64; q.sCt = 12288;
        pgemm64_k<0,0,1,0,0,0,0><<<dim3(i, 1, 32), b256, 0, stream>>>(q);
        clr(); q.M = 64; q.N = 64 * i; q.K = 64;
        q.Ah = invSh + (long)i * 4096; q.Al = invSl + (long)i * 4096;
        q.lda = 64; q.sA = 16384;
        q.Bh = StTSh; q.Bl = StTSl; q.ldb = 64; q.sB = 12288;
        q.alpha = -1.f;
        q.Ch = TKrSh + (long)64 * i * 256; q.Cl = TKrSl + (long)64 * i * 256;
        q.ldp = 256; q.sP = MM_;
        q.ChT = TtSh + 64 * i; q.ClT = TtSl + 64 * i; q.ldct = 256; q.sCt = MM_;
        pgemm64_k<0,1,1,0,0,0,0><<<dim3(i, 1, 32), b256, 0, stream>>>(q);
    }

    // c2+d merged: [KuuInv | lKl] = Tt @ Tt^T over all 32 matrices
    clr(); q.Ah = TtSh; q.Al = TtSl; q.sA = MM_;
    q.Bh = TtSh; q.Bl = TtSl; q.sB = MM_;
    q.Ch = KILh; q.Cl = KILl; q.sP = MM_;
    pgemm64_k<0,1,0,0,0,0,0><<<dim3(4, 4, 32), b256, 0, stream>>>(q);

    // e. Stmp = KuuL @ lKlpIi -> pair (into Tlt region, dead after c2d)
    u16* Stmph = Tlth; u16* Stmpl = Tltl;
    clr(); q.Ah = KuuLSh; q.Al = KuuLSl; q.sA = MM_;
    q.Bh = lKlh; q.Bl = lKll; q.sB = MM_;
    q.Ch = Stmph; q.Cl = Stmpl; q.sP = MM_;
    pgemm64_k<0,1,0,0,0,0,0><<<g64, b256, 0, stream>>>(q);

    // f. Sigma = Kuu - Stmp @ KuuL^T -> pair
    clr(); q.Ah = Stmph; q.Al = Stmpl; q.sA = MM_;
    q.Bh = KuuLSh; q.Bl = KuuLSl; q.sB = MM_;
    q.Ch = Sigmah; q.Cl = Sigmal; q.sP = MM_;
    q.D = Kuu; q.sD = MM_; q.alpha = -1.f;
    pgemm64_k<0,1,0,0,0,1,0><<<g64, b256, 0, stream>>>(q);

    // g. W1 = up @ L -> pair (batch 1)
    clr(); q.Ah = upSh; q.Al = upSl; q.sA = 0;
    q.Bh = LtSh; q.Bl = LtSl; q.sB = 0;
    q.Ch = W1Sh; q.Cl = W1Sl; q.sP = 0;
    pgemm64_k<0,1,0,0,0,0,0><<<g64b1, b256, 0, stream>>>(q);

    // h. UPT = W1 @ L^T -> fp32 (batch 1)
    clr(); q.Ah = W1Sh; q.Al = W1Sl; q.sA = 0;
    q.Bh = LSh; q.Bl = LSl; q.sB = 0;
    q.C = UPT; q.sC = 0;
    pgemm64_k<1,0,0,0,0,0,0><<<g64b1, b256, 0, stream>>>(q);

    // i. RHS1T = ninv @ TK + UPT -> fp32
    clr(); q.Ah = ninvSh; q.Al = ninvSl; q.sA = 65536;
    q.Bh = TKth; q.Bl = TKtl; q.sB = MM_;
    q.C = RHS1T; q.sC = MM_;
    q.D = UPT; q.sD = 0;
    pgemm64_k<1,0,0,0,0,1,0><<<g64, b256, 0, stream>>>(q);

    // j. RHST = nL @ L^T + RHS1T -> pair
    clr(); q.Ah = nLSh; q.Al = nLSl; q.sA = 65536;
    q.Bh = LSh; q.Bl = LSl; q.sB = 0;
    q.C = RHS1T; q.sC = MM_;
    q.Ch = RHSTh; q.Cl = RHSTl; q.sP = MM_;
    pgemm64_k<0,1,0,0,1,0,0><<<g64, b256, 0, stream>>>(q);

    // k. UT = RHST @ Sigma -> pair + transposed fp32 direct into out rows 0..255
    clr(); q.Ah = RHSTh; q.Al = RHSTl; q.sA = MM_;
    q.Bh = Sigmah; q.Bl = Sigmal; q.sB = MM_;
    q.Ch = UTph; q.Cl = UTpl; q.sP = MM_;
    q.CF = out; q.sCF = (long)ROWS_ * OUT_;
    pgemm64_k<0,1,0,1,0,0,0><<<g64, b256, 0, stream>>>(q);

    // G3T = UTp @ KuuInv -> pair
    clr(); q.Ah = UTph; q.Al = UTpl; q.sA = MM_;
    q.Bh = KuuInvh; q.Bl = KuuInvl; q.sB = MM_;
    q.Ch = G3TSh; q.Cl = G3TSl; q.sP = MM_;
    pgemm64_k<0,1,0,0,0,0,0><<<g64, b256, 0, stream>>>(q);

    for (int f0 = 0; f0 < NF_; f0 += nfc) {
        int w = NF_ - f0; if (w > nfc) w = nfc;
        if (f0 > 0)    // chunk 0 transposed inside megachol
            tsplit_kernel<<<dim3(w / 32, 8, S_), b256, 0, stream>>>(
                Kuf + f0, NF_, (long)M_ * NF_, KufTch, KufTcl, 256, (long)w * 256, nullptr);
        // Vf-GEMM: H' = KufT @ TK^T (lower-tri B: K capped), VfAcc row sums of squares
        clr(); q.M = w; q.N = 256;
        q.Ah = KufTch; q.Al = KufTcl; q.sA = (long)w * 256;
        q.Bh = TKrSh; q.Bl = TKrSl; q.sB = MM_;
        q.vfacc = VfAcc + f0; q.sVf = NF_;
        pgemm_k<0,0,0,0,0,0,0,1,1><<<dim3(2, w / 128, S_), b256, 0, stream>>>(q);
        // Ef-GEMM: out_f = KufT @ G3T^T + sqrt(Kff - VfAcc)*noise_f
        clr(); q.M = w; q.N = 256;
        q.Ah = KufTch; q.Al = KufTcl; q.sA = (long)w * 256;
        q.Bh = G3TSh; q.Bl = G3TSl; q.sB = MM_;
        q.C = out + (long)(M_ + f0) * OUT_; q.sC = (long)ROWS_ * OUT_;
        q.kff = Kff + f0; q.vfacc = VfAcc + f0; q.sVf = NF_;
        q.noise = noise_f + (long)f0 * OUT_; q.sNoise = (long)NF_ * OUT_;
        pgemm_k<1,0,0,0,0,0,1,0,0><<<dim3(2, w / 128, S_), b256, 0, stream>>>(q);
    }
}

// Round 20
// 395.244 us; speedup vs baseline: 1.4325x; 1.0218x over previous
//
#include <hip/hip_runtime.h>
#include <math.h>

#define S_ 16
#define M_ 256
#define NF_ 4096
#define OUT_ 256
#define ROWS_ (M_ + NF_)     // 4352
#define MM_ (M_ * M_)        // 65536

typedef unsigned short u16;
typedef __attribute__((ext_vector_type(8))) short bf16x8;
typedef __attribute__((ext_vector_type(4))) float f32x4;

__device__ __forceinline__ void cvt2(float x, u16& h, u16& l) {
    unsigned xb = __float_as_uint(x);
    unsigned hb = (xb + 0x7fffu + ((xb >> 16) & 1u)) >> 16;
    float fh = __uint_as_float(hb << 16);
    float rr = x - fh;
    unsigned rb = __float_as_uint(rr);
    unsigned lb = (rb + 0x7fffu + ((rb >> 16) & 1u)) >> 16;
    h = (u16)hb; l = (u16)lb;
}

// ---------------- fused prologue: Kuu split+copy / L split / L^T split ----------------
// blocks 0..1023: Kuu -> pair + fp32 copy (jitter-free: Kuu has +0.1 I).
// blocks 1024..1087: Lloc -> scaled pair (scale computed locally, same tree as prep).
// blocks 1088..1151: Lloc^T -> scaled pair (32x32 LDS tiles).

__global__ void prepall_kernel(const float* __restrict__ Kuu,
                               u16* __restrict__ Kh, u16* __restrict__ Kl,
                               float* __restrict__ cholK,
                               const float* __restrict__ Lloc,
                               const float* __restrict__ Lscale,
                               u16* __restrict__ Lh, u16* __restrict__ Ll,
                               u16* __restrict__ Lth, u16* __restrict__ Ltl) {
    int b = blockIdx.x, tid = threadIdx.x;
    if (b < 1024) {
        long i = ((long)b * 256 + tid) * 4;
        if (i < (long)S_ * MM_) {
            float4 v = *(const float4*)(Kuu + i);
            u16 h0,h1,h2,h3,l0,l1,l2,l3;
            cvt2(v.x,h0,l0); cvt2(v.y,h1,l1); cvt2(v.z,h2,l2); cvt2(v.w,h3,l3);
            ushort4 hv = {h0,h1,h2,h3}, lv = {l0,l1,l2,l3};
            *(ushort4*)(Kh + i) = hv;
            *(ushort4*)(Kl + i) = lv;
            *(float4*)(cholK + i) = v;
        }
        return;
    }
    // local scale = exp(Lscale) / mean(diag(Lloc)), same pairwise tree as before
    __shared__ float red[256];
    __shared__ float T[32][33];
    red[tid] = Lloc[tid * M_ + tid];
    __syncthreads();
    for (int s = 128; s > 0; s >>= 1) {
        if (tid < s) red[tid] += red[tid + s];
        __syncthreads();
    }
    float sc = expf(Lscale[0]) / (red[0] / (float)M_);
    if (b < 1088) {
        long i = ((long)(b - 1024) * 256 + tid) * 4;
        float4 v = *(const float4*)(Lloc + i);
        u16 h0,h1,h2,h3,l0,l1,l2,l3;
        cvt2(v.x*sc,h0,l0); cvt2(v.y*sc,h1,l1); cvt2(v.z*sc,h2,l2); cvt2(v.w*sc,h3,l3);
        ushort4 hv = {h0,h1,h2,h3}, lv = {l0,l1,l2,l3};
        *(ushort4*)(Lh + i) = hv;
        *(ushort4*)(Ll + i) = lv;
        return;
    }
    // L^T tiles
    int t = b - 1088;               // 0..63
    int c0 = (t & 7) * 32, r0 = (t >> 3) * 32;
    int lrow = tid >> 3, lc4 = (tid & 7) * 4;
    float4 v = *(const float4*)(Lloc + (long)(r0 + lrow) * M_ + c0 + lc4);
    T[lrow][lc4 + 0] = v.x * sc; T[lrow][lc4 + 1] = v.y * sc;
    T[lrow][lc4 + 2] = v.z * sc; T[lrow][lc4 + 3] = v.w * sc;
    __syncthreads();
    int wcol = tid >> 3, wr4 = (tid & 7) * 4;
    u16 h0,h1,h2,h3,l0,l1,l2,l3;
    cvt2(T[wr4+0][wcol],h0,l0); cvt2(T[wr4+1][wcol],h1,l1);
    cvt2(T[wr4+2][wcol],h2,l2); cvt2(T[wr4+3][wcol],h3,l3);
    ushort4 hv = {h0,h1,h2,h3}, lv = {l0,l1,l2,l3};
    *(ushort4*)(Lth + (long)(c0 + wcol) * M_ + r0 + wr4) = hv;
    *(ushort4*)(Ltl + (long)(c0 + wcol) * M_ + r0 + wr4) = lv;
}

// ---- transpose split (tail chunks beyond chunk 0) ----
__global__ void tsplit_kernel(const float* __restrict__ src, int ldS, long sS,
                              u16* __restrict__ h, u16* __restrict__ l, int ldD, long sD,
                              const float* scaleptr) {
    int b = blockIdx.z;
    src += (long)b * sS; h += (long)b * sD; l += (long)b * sD;
    __shared__ float T[32][33];
    int r0 = blockIdx.y * 32, c0 = blockIdx.x * 32;
    float sc = scaleptr ? scaleptr[0] : 1.0f;
    int tid = threadIdx.x;
    int lrow = tid >> 3, lc4 = (tid & 7) * 4;
    float4 v = *(const float4*)(src + (long)(r0 + lrow) * ldS + c0 + lc4);
    T[lrow][lc4 + 0] = v.x * sc; T[lrow][lc4 + 1] = v.y * sc;
    T[lrow][lc4 + 2] = v.z * sc; T[lrow][lc4 + 3] = v.w * sc;
    __syncthreads();
    int wcol = tid >> 3, wr4 = (tid & 7) * 4;
    u16 h0,h1,h2,h3,l0,l1,l2,l3;
    cvt2(T[wr4+0][wcol],h0,l0); cvt2(T[wr4+1][wcol],h1,l1);
    cvt2(T[wr4+2][wcol],h2,l2); cvt2(T[wr4+3][wcol],h3,l3);
    ushort4 hv = {h0,h1,h2,h3}, lv = {l0,l1,l2,l3};
    *(ushort4*)(h + (long)(c0 + wcol) * ldD + r0 + wr4) = hv;
    *(ushort4*)(l + (long)(c0 + wcol) * ldD + r0 + wr4) = lv;
}

__device__ __forceinline__ void psplit_dev(const float* __restrict__ src, u16* __restrict__ h,
                                           u16* __restrict__ l, long n, long b0, long stp) {
    for (long i = b0 * 4; i < n; i += stp * 4) {
        float4 v = *(const float4*)(src + i);
        u16 h0,h1,h2,h3,l0,l1,l2,l3;
        cvt2(v.x,h0,l0); cvt2(v.y,h1,l1); cvt2(v.z,h2,l2); cvt2(v.w,h3,l3);
        ushort4 hv = {h0,h1,h2,h3}, lv = {l0,l1,l2,l3};
        *(ushort4*)(h + i) = hv;
        *(ushort4*)(l + i) = lv;
    }
}

// ---------------- MEGA: chol (blocks 0..31) + independent prep (blocks 32+) ----------------

struct MAux {
    const float* Kuf; u16 *KTh, *KTl; int w0;
    const float* ninv; u16 *nih, *nil;
    const float* nLp;  u16 *nLh2, *nLl2;
    const float* up;   u16 *uph2, *upl2;
    float* z1; long z1n;       // Tt+TKr zero region (floats)
    float* z2; long z2n;       // VfAcc
};

__global__ __launch_bounds__(1024) void megachol_kernel(float* bufA, float* bufB, MAux ax) {
    __shared__ float P[33280];
    __shared__ float pan2[256 * 20];
    __shared__ float piv[16][18];

    if (blockIdx.x < 32) {
        // -------- chol body (blk = blockIdx.x) --------
        int blk = blockIdx.x;
        float* Ag = (blk < S_) ? (bufA + (long)blk * MM_) : (bufB + (long)(blk - S_) * MM_);
        float4* P4 = (float4*)P;
        int tid = threadIdx.x;
        int r = tid >> 2, s = tid & 3;
        int lane = tid & 63, wid = tid >> 6;
        int mg = r >> 2, tg = r & 3;
        int b4 = (mg + 1) * (2 * mg + tg);

        for (int i = wid; i < M_; i += 16) {
            int m = i >> 2, t4 = i & 3;
            int rb4 = (m + 1) * (2 * m + t4);
            if (lane <= m) P4[rb4 + lane] = ((const float4*)Ag)[i * 64 + lane];
        }
        __syncthreads();

        float preg[16];
        for (int p = 0; p < 16; p++) {
            int k0 = p << 4;
            int c0 = p << 2;
            #pragma unroll
            for (int rr = 0; rr < 4; rr++) {
                float4 v = make_float4(0.f, 0.f, 0.f, 0.f);
                if (r >= k0 && c0 + rr <= mg) v = P4[b4 + c0 + rr];
                preg[4 * rr + 0] = v.x; preg[4 * rr + 1] = v.y;
                preg[4 * rr + 2] = v.z; preg[4 * rr + 3] = v.w;
            }
            if (wid == p) {
                int dj = lane >> 2;
                float myinv = 0.f;
                #pragma unroll
                for (int j = 0; j < 16; j++) {
                    float app = __shfl(preg[j], 4 * j, 64);
                    float d = sqrtf(app);
                    float inv = 1.0f / d;
                    if (dj == j) { preg[j] = d; myinv = inv; }
                    else if (dj > j) preg[j] *= inv;
                    #pragma unroll
                    for (int j2 = j + 1; j2 < 16; j2++) {
                        float Lj2 = __shfl(preg[j], 4 * j2, 64);
                        if (dj >= j2) preg[j2] -= preg[j] * Lj2;
                    }
                }
                if (s == 0) {
                    #pragma unroll
                    for (int i = 0; i < 16; i++) piv[dj][i] = preg[i];
                    piv[dj][16] = myinv;
                }
            }
            __syncthreads();
            if (r > k0 + 15) {
                float x[16];
                #pragma unroll
                for (int j = 0; j < 16; j++) {
                    float acc = preg[j];
                    #pragma unroll
                    for (int i = 0; i < 16; i++)
                        if (i < j) acc -= x[i] * piv[j][i];
                    x[j] = acc * piv[j][16];
                }
                #pragma unroll
                for (int j = 0; j < 16; j++) preg[j] = x[j];
            }
            if (r >= k0) {
                float4 pv = make_float4(preg[4 * s], preg[4 * s + 1],
                                        preg[4 * s + 2], preg[4 * s + 3]);
                *(float4*)&pan2[r * 20 + 4 * s] = pv;
                int c = c0 + s;
                if (c <= mg) P4[b4 + c] = pv;
            }
            __syncthreads();
            {
                int cs = tid >> 4;
                int j  = tid & 15;
                if (cs >= c0 + 4) {
                    float4 q0[4], q1[4], q2[4], q3[4];
                    #pragma unroll
                    for (int e = 0; e < 4; e++) {
                        const float4* pr = (const float4*)&pan2[(4 * cs + e) * 20];
                        q0[e] = pr[0]; q1[e] = pr[1]; q2[e] = pr[2]; q3[e] = pr[3];
                    }
                    int rr = k0 + 16 + j;
                    int rmin = 4 * cs;
                    while (rr < rmin) rr += 16;
                    for (; rr < 256; rr += 16) {
                        int mgr = rr >> 2, tgr = rr & 3;
                        int rb4 = (mgr + 1) * (2 * mgr + tgr);
                        const float4* ar = (const float4*)&pan2[rr * 20];
                        float4 a0 = ar[0], a1 = ar[1], a2 = ar[2], a3 = ar[3];
                        float rv[4];
                        *(float4*)rv = P4[rb4 + cs];
                        #pragma unroll
                        for (int e = 0; e < 4; e++) {
                            float acc;
                            acc  = a0.x*q0[e].x + a0.y*q0[e].y + a0.z*q0[e].z + a0.w*q0[e].w;
                            acc += a1.x*q1[e].x + a1.y*q1[e].y + a1.z*q1[e].z + a1.w*q1[e].w;
                            acc += a2.x*q2[e].x + a2.y*q2[e].y + a2.z*q2[e].z + a2.w*q2[e].w;
                            acc += a3.x*q3[e].x + a3.y*q3[e].y + a3.z*q3[e].z + a3.w*q3[e].w;
                            rv[e] -= acc;
                        }
                        P4[rb4 + cs] = *(float4*)rv;
                    }
                }
            }
            __syncthreads();
        }

        for (int i = wid; i < M_; i += 16) {
            int m = i >> 2, t4 = i & 3;
            int rb4 = (m + 1) * (2 * m + t4);
            if (lane <= m) ((float4*)Ag)[i * 64 + lane] = P4[rb4 + lane];
        }
        return;
    }

    // -------- aux path: independent prep work on idle CUs --------
    int ab = blockIdx.x - 32, NA = gridDim.x - 32;
    int tid = threadIdx.x;
    long b0 = (long)ab * 1024 + tid, stp = (long)NA * 1024;
    float4 z = make_float4(0.f, 0.f, 0.f, 0.f);
    long n4 = ax.z1n >> 2;
    for (long i = b0; i < n4; i += stp) ((float4*)ax.z1)[i] = z;
    long m4 = ax.z2n >> 2;
    for (long i = b0; i < m4; i += stp) ((float4*)ax.z2)[i] = z;
    psplit_dev(ax.ninv, ax.nih, ax.nil, (long)S_ * MM_, b0, stp);
    psplit_dev(ax.nLp, ax.nLh2, ax.nLl2, (long)S_ * MM_, b0, stp);
    psplit_dev(ax.up, ax.uph2, ax.upl2, 65536, b0, stp);

    int grp = tid >> 8, t = tid & 255;
    float* Tls = P + grp * 1056;
    int nx = ax.w0 >> 5;
    int ntile = nx * 8 * S_;
    int per = NA * 4;
    int iters = (ntile + per - 1) / per;
    long sS = (long)M_ * NF_, sD = (long)ax.w0 * 256;
    for (int it = 0; it < iters; it++) {
        int tile = ab * 4 + grp + it * per;
        bool ok = tile < ntile;
        int r0 = 0, c0 = 0, b = 0;
        if (ok) {
            int cx = tile % nx; int rest = tile / nx;
            int cy = rest & 7; b = rest >> 3;
            r0 = cy * 32; c0 = cx * 32;
        }
        if (ok) {
            int lrow = t >> 3, lc4 = (t & 7) * 4;
            float4 v = *(const float4*)(ax.Kuf + (long)b * sS + (long)(r0 + lrow) * NF_ + c0 + lc4);
            Tls[lrow * 33 + lc4 + 0] = v.x; Tls[lrow * 33 + lc4 + 1] = v.y;
            Tls[lrow * 33 + lc4 + 2] = v.z; Tls[lrow * 33 + lc4 + 3] = v.w;
        }
        __syncthreads();
        if (ok) {
            int wcol = t >> 3, wr4 = (t & 7) * 4;
            u16 h0,h1,h2,h3,l0,l1,l2,l3;
            cvt2(Tls[(wr4+0)*33+wcol],h0,l0); cvt2(Tls[(wr4+1)*33+wcol],h1,l1);
            cvt2(Tls[(wr4+2)*33+wcol],h2,l2); cvt2(Tls[(wr4+3)*33+wcol],h3,l3);
            ushort4 hv = {h0,h1,h2,h3}, lv = {l0,l1,l2,l3};
            long o = (long)b * sD + (long)(c0 + wcol) * 256 + r0 + wr4;
            *(ushort4*)(ax.KTh + o) = hv;
            *(ushort4*)(ax.KTl + o) = lv;
        }
        __syncthreads();
    }
}

// ---------------- merged: 64x64 diag triangular inverse (bx<4) + lsplit (bx>=4) ----------------

__global__ __launch_bounds__(256) void trilsp_kernel(const float* W0,
                                                     u16* invh, u16* invl,
                                                     u16* Tth, u16* Ttl,
                                                     u16* TKrh, u16* TKrl,
                                                     u16* Lh, u16* Ll) {
    __shared__ float X[64 * 65];
    __shared__ float pan[64 * 20];
    int mat = blockIdx.y;      // 0..31
    int tid = threadIdx.x;
    const float* W = W0 + (long)mat * MM_;

    if (blockIdx.x >= 4) {
        int p = blockIdx.x - 4;        // 0..2
        u16* dh = Lh + (long)mat * MM_;
        u16* dl = Ll + (long)mat * MM_;
        int d0 = 64 * p, nrows = 192 - d0;
        for (int idx = tid; idx < nrows * 16; idx += 256) {
            int r = idx >> 4, c4 = idx & 15;
            long o = (long)(d0 + 64 + r) * 256 + d0 + 4 * c4;
            float4 v = *(const float4*)(W + o);
            u16 h0,h1,h2,h3,l0,l1,l2,l3;
            cvt2(v.x,h0,l0); cvt2(v.y,h1,l1); cvt2(v.z,h2,l2); cvt2(v.w,h3,l3);
            ushort4 hv = {h0,h1,h2,h3}, lv = {l0,l1,l2,l3};
            *(ushort4*)(dh + o) = hv;
            *(ushort4*)(dl + o) = lv;
        }
        return;
    }

    int p = blockIdx.x;        // 0..3
    int d0 = p * 64;
    int c = tid & 63, q = tid >> 6;
    for (int idx = tid; idx < 64 * 65; idx += 256) X[idx] = 0.f;
    __syncthreads();
    if (q == 0) X[c * 65 + c] = 1.0f;
    for (int pp = 0; pp < 4; pp++) {
        int t0 = pp << 4;
        for (int idx = tid; idx < 64 * 4; idx += 256) {
            int k = idx >> 2, e = idx & 3;
            if (k >= t0)
                ((float4*)(pan + k * 20))[e] =
                    *(const float4*)(W + (long)(d0 + k) * 256 + d0 + t0 + 4 * e);
        }
        __syncthreads();
        if (q == pp) {
            float xr[16];
            #pragma unroll
            for (int j = 0; j < 16; j++) {
                float xv = X[(t0 + j) * 65 + c];
                #pragma unroll
                for (int i = 0; i < 16; i++)
                    if (i < j) xv -= pan[(t0 + j) * 20 + i] * xr[i];
                xv *= (1.0f / pan[(t0 + j) * 20 + j]);
                xr[j] = xv;
                X[(t0 + j) * 65 + c] = xv;
            }
        }
        __syncthreads();
        int kbeg = q << 4; if (kbeg < t0 + 16) kbeg = t0 + 16;
        int kend = (q << 4) + 16;
        if (kbeg < kend) {
            float xr[16];
            #pragma unroll
            for (int j = 0; j < 16; j++) xr[j] = X[(t0 + j) * 65 + c];
            for (int kk = kbeg; kk < kend; kk++) {
                float rv = X[kk * 65 + c];
                const float4* pr = (const float4*)&pan[kk * 20];
                float4 a = pr[0], b = pr[1], d = pr[2], e = pr[3];
                rv -= a.x * xr[0] + a.y * xr[1] + a.z * xr[2] + a.w * xr[3];
                rv -= b.x * xr[4] + b.y * xr[5] + b.z * xr[6] + b.w * xr[7];
                rv -= d.x * xr[8] + d.y * xr[9] + d.z * xr[10] + d.w * xr[11];
                rv -= e.x * xr[12] + e.y * xr[13] + e.z * xr[14] + e.w * xr[15];
                X[kk * 65 + c] = rv;
            }
        }
        __syncthreads();
    }
    for (int idx = tid; idx < 4096; idx += 256) {
        int r = idx >> 6, k = idx & 63;
        u16 h, l; cvt2(X[r * 65 + k], h, l);
        long io = (long)mat * 16384 + (long)p * 4096 + idx;
        invh[io] = h; invl[io] = l;
        long ro = (long)mat * MM_ + (long)(d0 + r) * 256 + d0 + k;
        TKrh[ro] = h; TKrl[ro] = l;
        long to = (long)mat * MM_ + (long)(d0 + k) * 256 + d0 + r;
        Tth[to] = h; Ttl[to] = l;
    }
}

// ---------------- pair GEMM: C = alpha * A @ B^T(storage) + epilogue ----------------

struct PG {
    const u16 *Ah, *Al, *Bh, *Bl;
    float* C; u16 *Ch, *Cl, *ChT, *ClT;
    float* CF;                      // transposed fp32 out
    const float* D; const float* noise;
    const float* kff; float* vfacc;
    int M, N, K, lda, ldb, ldc, ldct, ldp;
    long sA, sB, sC, sP, sCt, sD, sVf, sNoise, sCF;
    float alpha, dcoef;
};

// 128x128 tile, 4 waves (K = 256; TRIf: K capped at bn+128 for lower-tri B)
template<int OF, int OP, int OPT, int ACCf, int Df, int ADDIf, int EFf, int VFf, int TRIf>
__global__ __launch_bounds__(256) void pgemm_k(PG p) {
    int bz = blockIdx.z;
    const u16* Agh = p.Ah + (long)bz * p.sA;
    const u16* Agl = p.Al + (long)bz * p.sA;
    const u16* Bgh = p.Bh + (long)bz * p.sB;
    const u16* Bgl = p.Bl + (long)bz * p.sB;
    int bm = blockIdx.y * 128, bn = blockIdx.x * 128;
    __shared__ __align__(16) u16 sAh[128][40];
    __shared__ __align__(16) u16 sAl[128][40];
    __shared__ __align__(16) u16 sBh[128][40];
    __shared__ __align__(16) u16 sBl[128][40];
    int tid = threadIdx.x, lane = tid & 63, wid = tid >> 6;
    int wm = (wid >> 1) * 64, wn = (wid & 1) * 64;
    int fr = lane & 15, ko = (lane >> 4) * 8;
    int kb = tid & 3, rw = tid >> 2;
    f32x4 acc[4][4];
    #pragma unroll
    for (int m = 0; m < 4; m++)
        #pragma unroll
        for (int n = 0; n < 4; n++)
            acc[m][n] = (f32x4){0.f, 0.f, 0.f, 0.f};

    int klim = TRIf ? (bn + 128) : 256;
    for (int k0 = 0; k0 < klim; k0 += 32) {
        #define STG(SRC, LD, BASE, DST) \
            *(bf16x8*)&DST[rw][kb * 8] = \
                *(const bf16x8*)(SRC + (long)(BASE + rw) * LD + k0 + kb * 8); \
            *(bf16x8*)&DST[rw + 64][kb * 8] = \
                *(const bf16x8*)(SRC + (long)(BASE + rw + 64) * LD + k0 + kb * 8);
        STG(Agh, p.lda, bm, sAh)
        STG(Agl, p.lda, bm, sAl)
        STG(Bgh, p.ldb, bn, sBh)
        STG(Bgl, p.ldb, bn, sBl)
        #undef STG
        __syncthreads();
        bf16x8 ah[4], al[4], bh[4], bl[4];
        #pragma unroll
        for (int m = 0; m < 4; m++) {
            ah[m] = *(const bf16x8*)&sAh[wm + m * 16 + fr][ko];
            al[m] = *(const bf16x8*)&sAl[wm + m * 16 + fr][ko];
        }
        #pragma unroll
        for (int n = 0; n < 4; n++) {
            bh[n] = *(const bf16x8*)&sBh[wn + n * 16 + fr][ko];
            bl[n] = *(const bf16x8*)&sBl[wn + n * 16 + fr][ko];
        }
        #pragma unroll
        for (int m = 0; m < 4; m++)
            #pragma unroll
            for (int n = 0; n < 4; n++) {
                acc[m][n] = __builtin_amdgcn_mfma_f32_16x16x32_bf16(ah[m], bh[n], acc[m][n], 0, 0, 0);
                acc[m][n] = __builtin_amdgcn_mfma_f32_16x16x32_bf16(ah[m], bl[n], acc[m][n], 0, 0, 0);
                acc[m][n] = __builtin_amdgcn_mfma_f32_16x16x32_bf16(al[m], bh[n], acc[m][n], 0, 0, 0);
            }
        __syncthreads();
    }

    int rq = (lane >> 4) * 4;
    float rs[4][4];
    if (VFf) {
        #pragma unroll
        for (int m = 0; m < 4; m++)
            #pragma unroll
            for (int i = 0; i < 4; i++) rs[m][i] = 0.f;
    }
    #pragma unroll
    for (int m = 0; m < 4; m++) {
        int row0 = bm + wm + m * 16 + rq;
        #pragma unroll
        for (int n = 0; n < 4; n++) {
            int col = bn + wn + n * 16 + fr;
            float v[4];
            #pragma unroll
            for (int i = 0; i < 4; i++) {
                int r = row0 + i;
                float val = p.alpha * acc[m][n][i];
                if (Df)   val += p.dcoef * p.D[(long)bz * p.sD + (long)r * p.ldc + col];
                if (ACCf) val += p.C[(long)bz * p.sC + (long)r * p.ldc + col];
                if (ADDIf && r == col) val += 1.0f;
                if (EFf) {
                    float kf = p.kff[(long)bz * p.sVf + r];
                    float vq = p.vfacc[(long)bz * p.sVf + r];
                    val += sqrtf(fmaxf(kf - vq, 0.f)) *
                           p.noise[(long)bz * p.sNoise + (long)r * 256 + col];
                }
                v[i] = val;
                if (VFf) rs[m][i] += val * val;
            }
            if (OF) {
                #pragma unroll
                for (int i = 0; i < 4; i++)
                    p.C[(long)bz * p.sC + (long)(row0 + i) * p.ldc + col] = v[i];
            }
            if (OP) {
                #pragma unroll
                for (int i = 0; i < 4; i++) {
                    u16 h, l; cvt2(v[i], h, l);
                    p.Ch[(long)bz * p.sP + (long)(row0 + i) * p.ldc + col] = h;
                    p.Cl[(long)bz * p.sP + (long)(row0 + i) * p.ldc + col] = l;
                }
            }
            if (OPT) {
                u16 h0,h1,h2,h3,l0,l1,l2,l3;
                cvt2(v[0],h0,l0); cvt2(v[1],h1,l1); cvt2(v[2],h2,l2); cvt2(v[3],h3,l3);
                ushort4 hv = {h0,h1,h2,h3}, lv = {l0,l1,l2,l3};
                *(ushort4*)&p.ChT[(long)bz * p.sCt + (long)col * p.ldct + row0] = hv;
                *(ushort4*)&p.ClT[(long)bz * p.sCt + (long)col * p.ldct + row0] = lv;
            }
        }
    }
    if (VFf) {
        #pragma unroll
        for (int m = 0; m < 4; m++) {
            int row0 = bm + wm + m * 16 + rq;
            #pragma unroll
            for (int i = 0; i < 4; i++) {
                float t = rs[m][i];
                t += __shfl_xor(t, 1); t += __shfl_xor(t, 2);
                t += __shfl_xor(t, 4); t += __shfl_xor(t, 8);
                if (fr == 0)
                    atomicAdd(&p.vfacc[(long)bz * p.sVf + row0 + i], t);
            }
        }
    }
}

// 64x64 tile, 4 waves, runtime K (multiple of 32); OFT = transposed fp32 out
template<int OF, int OP, int OPT, int OFT, int ACCf, int Df, int ADDIf>
__global__ __launch_bounds__(256) void pgemm64_k(PG p) {
    int bz = blockIdx.z;
    const u16* Agh = p.Ah + (long)bz * p.sA;
    const u16* Agl = p.Al + (long)bz * p.sA;
    const u16* Bgh = p.Bh + (long)bz * p.sB;
    const u16* Bgl = p.Bl + (long)bz * p.sB;
    int bm = blockIdx.y * 64, bn = blockIdx.x * 64;
    __shared__ __align__(16) u16 sAh[64][40];
    __shared__ __align__(16) u16 sAl[64][40];
    __shared__ __align__(16) u16 sBh[64][40];
    __shared__ __align__(16) u16 sBl[64][40];
    int tid = threadIdx.x, lane = tid & 63, wid = tid >> 6;
    int wm = (wid >> 1) * 32, wn = (wid & 1) * 32;
    int fr = lane & 15, ko = (lane >> 4) * 8;
    int kb = tid & 3, rw = tid >> 2;
    f32x4 acc[2][2];
    #pragma unroll
    for (int m = 0; m < 2; m++)
        #pragma unroll
        for (int n = 0; n < 2; n++)
            acc[m][n] = (f32x4){0.f, 0.f, 0.f, 0.f};

    for (int k0 = 0; k0 < p.K; k0 += 32) {
        *(bf16x8*)&sAh[rw][kb * 8] = *(const bf16x8*)(Agh + (long)(bm + rw) * p.lda + k0 + kb * 8);
        *(bf16x8*)&sAl[rw][kb * 8] = *(const bf16x8*)(Agl + (long)(bm + rw) * p.lda + k0 + kb * 8);
        *(bf16x8*)&sBh[rw][kb * 8] = *(const bf16x8*)(Bgh + (long)(bn + rw) * p.ldb + k0 + kb * 8);
        *(bf16x8*)&sBl[rw][kb * 8] = *(const bf16x8*)(Bgl + (long)(bn + rw) * p.ldb + k0 + kb * 8);
        __syncthreads();
        bf16x8 ah[2], al[2], bh[2], bl[2];
        #pragma unroll
        for (int m = 0; m < 2; m++) {
            ah[m] = *(const bf16x8*)&sAh[wm + m * 16 + fr][ko];
            al[m] = *(const bf16x8*)&sAl[wm + m * 16 + fr][ko];
        }
        #pragma unroll
        for (int n = 0; n < 2; n++) {
            bh[n] = *(const bf16x8*)&sBh[wn + n * 16 + fr][ko];
            bl[n] = *(const bf16x8*)&sBl[wn + n * 16 + fr][ko];
        }
        #pragma unroll
        for (int m = 0; m < 2; m++)
            #pragma unroll
            for (int n = 0; n < 2; n++) {
                acc[m][n] = __builtin_amdgcn_mfma_f32_16x16x32_bf16(ah[m], bh[n], acc[m][n], 0, 0, 0);
                acc[m][n] = __builtin_amdgcn_mfma_f32_16x16x32_bf16(ah[m], bl[n], acc[m][n], 0, 0, 0);
                acc[m][n] = __builtin_amdgcn_mfma_f32_16x16x32_bf16(al[m], bh[n], acc[m][n], 0, 0, 0);
            }
        __syncthreads();
    }

    int rq = (lane >> 4) * 4;
    #pragma unroll
    for (int m = 0; m < 2; m++) {
        int row0 = bm + wm + m * 16 + rq;
        #pragma unroll
        for (int n = 0; n < 2; n++) {
            int col = bn + wn + n * 16 + fr;
            float v[4];
            #pragma unroll
            for (int i = 0; i < 4; i++) {
                int r = row0 + i;
                float val = p.alpha * acc[m][n][i];
                if (Df)   val += p.dcoef * p.D[(long)bz * p.sD + (long)r * p.ldc + col];
                if (ACCf) val += p.C[(long)bz * p.sC + (long)r * p.ldc + col];
                if (ADDIf && r == col) val += 1.0f;
                v[i] = val;
            }
            if (OF) {
                #pragma unroll
                for (int i = 0; i < 4; i++)
                    p.C[(long)bz * p.sC + (long)(row0 + i) * p.ldc + col] = v[i];
            }
            if (OP) {
                #pragma unroll
                for (int i = 0; i < 4; i++) {
                    u16 h, l; cvt2(v[i], h, l);
                    p.Ch[(long)bz * p.sP + (long)(row0 + i) * p.ldp + col] = h;
                    p.Cl[(long)bz * p.sP + (long)(row0 + i) * p.ldp + col] = l;
                }
            }
            if (OPT) {
                u16 h0,h1,h2,h3,l0,l1,l2,l3;
                cvt2(v[0],h0,l0); cvt2(v[1],h1,l1); cvt2(v[2],h2,l2); cvt2(v[3],h3,l3);
                ushort4 hv = {h0,h1,h2,h3}, lv = {l0,l1,l2,l3};
                *(ushort4*)&p.ChT[(long)bz * p.sCt + (long)col * p.ldct + row0] = hv;
                *(ushort4*)&p.ClT[(long)bz * p.sCt + (long)col * p.ldct + row0] = lv;
            }
            if (OFT) {
                float4 o4 = make_float4(v[0], v[1], v[2], v[3]);
                *(float4*)&p.CF[(long)bz * p.sCF + (long)col * 256 + row0] = o4;
            }
        }
    }
}

// ---------------- host ----------------

extern "C" void kernel_launch(void* const* d_in, const int* in_sizes, int n_in,
                              void* d_out, int out_size, void* d_ws, size_t ws_size,
                              hipStream_t stream) {
    const float* Kuu       = (const float*)d_in[0];
    const float* Kuf       = (const float*)d_in[1];
    const float* Kff       = (const float*)d_in[2];
    const float* Lloc      = (const float*)d_in[3];
    const float* Lscale    = (const float*)d_in[4];
    const float* u_param   = (const float*)d_in[5];
    const float* noise_inv = (const float*)d_in[6];
    const float* noise_L   = (const float*)d_in[7];
    const float* noise_f   = (const float*)d_in[8];
    float* out = (float*)d_out;
    float* ws  = (float*)d_ws;

    const long BIG = (long)S_ * MM_;     // 1,048,576 elements
    long off = 1024;

    #define PAIR(NAME, E) u16* NAME##h = (u16*)(ws + off); u16* NAME##l = NAME##h + (E); off += (E);
    PAIR(LS, 65536)
    PAIR(LtS, 65536)
    PAIR(upS, 65536)
    PAIR(W1S, 65536)
    float* UPT   = ws + off; off += 65536;
    float* VfAcc = ws + off; off += 65536;
    PAIR(KuuS, BIG)
    PAIR(ninvS, BIG)
    PAIR(nLS, BIG)
    float* cholK = ws + off; off += 2 * BIG;   // 32 matrices contiguous
    float* choll = cholK + BIG;
    PAIR(KuuLS, BIG)
    PAIR(KuuLtS, BIG)
    PAIR(TtS, 2 * BIG)             // T^T pair, 32 matrices  (zeroed in mega)
    PAIR(TKrS, 2 * BIG)            // T row-major pair, 32 matrices (zeroed in mega)
    PAIR(G3TS, BIG)                // (KuuInv @ U)^T pair
    PAIR(KIL, 2 * BIG)             // KuuInv (mats 0..15) | lKl (mats 16..31)
    PAIR(invS, 524288)             // 32 mats x 4 panels x 64x64 D pair
    PAIR(LfS, 2 * BIG)             // L strictly-lower pair, 32 matrices
    PAIR(StTS, 393216)             // S^T scratch pair, 32 x 192x64
    #undef PAIR

    u16* TKth = TtSh;                u16* TKtl = TtSl;
    u16* Tlth = TtSh + (long)S_ * MM_; u16* Tltl = TtSl + (long)S_ * MM_;
    u16* RHSTh   = KuuSh;            u16* RHSTl   = KuuSl;
    u16* UTph    = nLSh;             u16* UTpl    = nLSl;
    float* RHS1T = (float*)KuuLSh;
    u16* Sigmah  = KuuLtSh;          u16* Sigmal  = KuuLtSl;
    u16* KuuInvh = KILh;             u16* KuuInvl = KILl;
    u16* lKlh    = KILh + (long)S_ * MM_; u16* lKll = KILl + (long)S_ * MM_;

    long navail = (long)(ws_size / 4) - off;
    long nfc_l = navail / 4096;                 // only KufT pair per chunk
    int nfc = (int)((nfc_l / 128) * 128);
    if (nfc > NF_) nfc = NF_;
    if (nfc < 128) nfc = 128;
    long Ec = (long)S_ * nfc * 256;
    u16* KufTch = (u16*)(ws + off);      u16* KufTcl = KufTch + Ec;

    dim3 b256(256);

    // fused prologue (replaces prep + splitjit + psplit(L) + tsplit(L))
    prepall_kernel<<<1152, b256, 0, stream>>>(Kuu, KuuSh, KuuSl, cholK,
                                              Lloc, Lscale,
                                              LSh, LSl, LtSh, LtSl);

    PG q;
    auto clr = [&]() {
        q = PG{};
        q.lda = 256; q.ldb = 256; q.ldc = 256; q.ldct = 256; q.ldp = 256;
        q.alpha = 1.f; q.dcoef = 1.f;
        q.M = 256; q.N = 256; q.K = 256;
    };
    dim3 g64(4, 4, S_);
    dim3 g64b1(4, 4, 1);

    // a. KuuL = Kuu @ L -> pair + pairT
    clr(); q.Ah = KuuSh; q.Al = KuuSl; q.sA = MM_;
    q.Bh = LtSh; q.Bl = LtSl; q.sB = 0;
    q.Ch = KuuLSh; q.Cl = KuuLSl; q.sP = MM_;
    q.ChT = KuuLtSh; q.ClT = KuuLtSl; q.sCt = MM_;
    pgemm64_k<0,1,1,0,0,0,0><<<g64, b256, 0, stream>>>(q);

    // b. choll = KuuL^T @ L + I -> fp32
    clr(); q.Ah = KuuLtSh; q.Al = KuuLtSl; q.sA = MM_;
    q.Bh = LtSh; q.Bl = LtSl; q.sB = 0;
    q.C = choll; q.sC = MM_;
    pgemm64_k<1,0,0,0,0,0,1><<<g64, b256, 0, stream>>>(q);

    // MEGA: chol (32 blocks) + aux prep (224 blocks)
    int w0 = nfc;
    MAux ax;
    ax.Kuf = Kuf; ax.KTh = KufTch; ax.KTl = KufTcl; ax.w0 = w0;
    ax.ninv = noise_inv; ax.nih = ninvSh; ax.nil = ninvSl;
    ax.nLp = noise_L; ax.nLh2 = nLSh; ax.nLl2 = nLSl;
    ax.up = u_param; ax.uph2 = upSh; ax.upl2 = upSl;
    ax.z1 = (float*)TtSh; ax.z1n = 4 * BIG;      // Tt pair + TKr pair (contiguous)
    ax.z2 = VfAcc; ax.z2n = 65536;
    megachol_kernel<<<256, dim3(1024), 0, stream>>>(cholK, choll, ax);

    // ---- block-recursive triangular inverse via MFMA (+ lsplit merged) ----
    trilsp_kernel<<<dim3(7, 32), b256, 0, stream>>>(cholK, invSh, invSl,
                                                    TtSh, TtSl, TKrSh, TKrSl,
                                                    LfSh, LfSl);

    for (int i = 1; i < 4; i++) {
        clr(); q.M = 64; q.N = 64 * i; q.K = 64 * i;
        q.Ah = LfSh + (long)64 * i * 256; q.Al = LfSl + (long)64 * i * 256;
        q.lda = 256; q.sA = MM_;
        q.Bh = TtSh; q.Bl = TtSl; q.ldb = 256; q.sB = MM_;
        q.ChT = StTSh; q.ClT = StTSl; q.ldct = 64; q.sCt = 12288;
        pgemm64_k<0,0,1,0,0,0,0><<<dim3(i, 1, 32), b256, 0, stream>>>(q);
        clr(); q.M = 64; q.N = 64 * i; q.K = 64;
        q.Ah = invSh + (long)i * 4096; q.Al = invSl + (long)i * 4096;
        q.lda = 64; q.sA = 16384;
        q.Bh = StTSh; q.Bl = StTSl; q.ldb = 64; q.sB = 12288;
        q.alpha = -1.f;
        q.Ch = TKrSh + (long)64 * i * 256; q.Cl = TKrSl + (long)64 * i * 256;
        q.ldp = 256; q.sP = MM_;
        q.ChT = TtSh + 64 * i; q.ClT = TtSl + 64 * i; q.ldct = 256; q.sCt = MM_;
        pgemm64_k<0,1,1,0,0,0,0><<<dim3(i, 1, 32), b256, 0, stream>>>(q);
    }

    // c2+d merged: [KuuInv | lKl] = Tt @ Tt^T over all 32 matrices
    clr(); q.Ah = TtSh; q.Al = TtSl; q.sA = MM_;
    q.Bh = TtSh; q.Bl = TtSl; q.sB = MM_;
    q.Ch = KILh; q.Cl = KILl; q.sP = MM_;
    pgemm64_k<0,1,0,0,0,0,0><<<dim3(4, 4, 32), b256, 0, stream>>>(q);

    // e. Stmp = KuuL @ lKlpIi -> pair (into Tlt region, dead after c2d)
    u16* Stmph = Tlth; u16* Stmpl = Tltl;
    clr(); q.Ah = KuuLSh; q.Al = KuuLSl; q.sA = MM_;
    q.Bh = lKlh; q.Bl = lKll; q.sB = MM_;
    q.Ch = Stmph; q.Cl = Stmpl; q.sP = MM_;
    pgemm64_k<0,1,0,0,0,0,0><<<g64, b256, 0, stream>>>(q);

    // f. Sigma = Kuu - Stmp @ KuuL^T -> pair
    clr(); q.Ah = Stmph; q.Al = Stmpl; q.sA = MM_;
    q.Bh = KuuLSh; q.Bl = KuuLSl; q.sB = MM_;
    q.Ch = Sigmah; q.Cl = Sigmal; q.sP = MM_;
    q.D = Kuu; q.sD = MM_; q.alpha = -1.f;
    pgemm64_k<0,1,0,0,0,1,0><<<g64, b256, 0, stream>>>(q);

    // g. W1 = up @ L -> pair (batch 1)
    clr(); q.Ah = upSh; q.Al = upSl; q.sA = 0;
    q.Bh = LtSh; q.Bl = LtSl; q.sB = 0;
    q.Ch = W1Sh; q.Cl = W1Sl; q.sP = 0;
    pgemm64_k<0,1,0,0,0,0,0><<<g64b1, b256, 0, stream>>>(q);

    // h. UPT = W1 @ L^T -> fp32 (batch 1)
    clr(); q.Ah = W1Sh; q.Al = W1Sl; q.sA = 0;
    q.Bh = LSh; q.Bl = LSl; q.sB = 0;
    q.C = UPT; q.sC = 0;
    pgemm64_k<1,0,0,0,0,0,0><<<g64b1, b256, 0, stream>>>(q);

    // i. RHS1T = ninv @ TK + UPT -> fp32
    clr(); q.Ah = ninvSh; q.Al = ninvSl; q.sA = 65536;
    q.Bh = TKth; q.Bl = TKtl; q.sB = MM_;
    q.C = RHS1T; q.sC = MM_;
    q.D = UPT; q.sD = 0;
    pgemm64_k<1,0,0,0,0,1,0><<<g64, b256, 0, stream>>>(q);

    // j. RHST = nL @ L^T + RHS1T -> pair
    clr(); q.Ah = nLSh; q.Al = nLSl; q.sA = 65536;
    q.Bh = LSh; q.Bl = LSl; q.sB = 0;
    q.C = RHS1T; q.sC = MM_;
    q.Ch = RHSTh; q.Cl = RHSTl; q.sP = MM_;
    pgemm64_k<0,1,0,0,1,0,0><<<g64, b256, 0, stream>>>(q);

    // k. UT = RHST @ Sigma -> pair + transposed fp32 direct into out rows 0..255
    clr(); q.Ah = RHSTh; q.Al = RHSTl; q.sA = MM_;
    q.Bh = Sigmah; q.Bl = Sigmal; q.sB = MM_;
    q.Ch = UTph; q.Cl = UTpl; q.sP = MM_;
    q.CF = out; q.sCF = (long)ROWS_ * OUT_;
    pgemm64_k<0,1,0,1,0,0,0><<<g64, b256, 0, stream>>>(q);

    // G3T = UTp @ KuuInv -> pair
    clr(); q.Ah = UTph; q.Al = UTpl; q.sA = MM_;
    q.Bh = KuuInvh; q.Bl = KuuInvl; q.sB = MM_;
    q.Ch = G3TSh; q.Cl = G3TSl; q.sP = MM_;
    pgemm64_k<0,1,0,0,0,0,0><<<g64, b256, 0, stream>>>(q);

    for (int f0 = 0; f0 < NF_; f0 += nfc) {
        int w = NF_ - f0; if (w > nfc) w = nfc;
        if (f0 > 0)    // chunk 0 transposed inside megachol
            tsplit_kernel<<<dim3(w / 32, 8, S_), b256, 0, stream>>>(
                Kuf + f0, NF_, (long)M_ * NF_, KufTch, KufTcl, 256, (long)w * 256, nullptr);
        // Vf-GEMM: H' = KufT @ TK^T (lower-tri B: K capped), VfAcc row sums of squares
        clr(); q.M = w; q.N = 256;
        q.Ah = KufTch; q.Al = KufTcl; q.sA = (long)w * 256;
        q.Bh = TKrSh; q.Bl = TKrSl; q.sB = MM_;
        q.vfacc = VfAcc + f0; q.sVf = NF_;
        pgemm_k<0,0,0,0,0,0,0,1,1><<<dim3(2, w / 128, S_), b256, 0, stream>>>(q);
        // Ef-GEMM: out_f = KufT @ G3T^T + sqrt(Kff - VfAcc)*noise_f
        clr(); q.M = w; q.N = 256;
        q.Ah = KufTch; q.Al = KufTcl; q.sA = (long)w * 256;
        q.Bh = G3TSh; q.Bl = G3TSl; q.sB = MM_;
        q.C = out + (long)(M_ + f0) * OUT_; q.sC = (long)ROWS_ * OUT_;
        q.kff = Kff + f0; q.vfacc = VfAcc + f0; q.sVf = NF_;
        q.noise = noise_f + (long)f0 * OUT_; q.sNoise = (long)NF_ * OUT_;
        pgemm_k<1,0,0,0,0,0,1,0,0><<<dim3(2, w / 128, S_), b256, 0, stream>>>(q);
    }
}

// Round 21
// 381.701 us; speedup vs baseline: 1.4833x; 1.0355x over previous
//
#include <hip/hip_runtime.h>
#include <math.h>

#define S_ 16
#define M_ 256
#define NF_ 4096
#define OUT_ 256
#define ROWS_ (M_ + NF_)     // 4352
#define MM_ (M_ * M_)        // 65536

typedef unsigned short u16;
typedef __attribute__((ext_vector_type(8))) short bf16x8;
typedef __attribute__((ext_vector_type(4))) float f32x4;

__device__ __forceinline__ void cvt2(float x, u16& h, u16& l) {
    unsigned xb = __float_as_uint(x);
    unsigned hb = (xb + 0x7fffu + ((xb >> 16) & 1u)) >> 16;
    float fh = __uint_as_float(hb << 16);
    float rr = x - fh;
    unsigned rb = __float_as_uint(rr);
    unsigned lb = (rb + 0x7fffu + ((rb >> 16) & 1u)) >> 16;
    h = (u16)hb; l = (u16)lb;
}

// ---------------- fused prologue: Kuu split+copy / L split / L^T split ----------------

__global__ void prepall_kernel(const float* __restrict__ Kuu,
                               u16* __restrict__ Kh, u16* __restrict__ Kl,
                               float* __restrict__ cholK,
                               const float* __restrict__ Lloc,
                               const float* __restrict__ Lscale,
                               u16* __restrict__ Lh, u16* __restrict__ Ll,
                               u16* __restrict__ Lth, u16* __restrict__ Ltl) {
    int b = blockIdx.x, tid = threadIdx.x;
    if (b < 1024) {
        long i = ((long)b * 256 + tid) * 4;
        if (i < (long)S_ * MM_) {
            float4 v = *(const float4*)(Kuu + i);
            u16 h0,h1,h2,h3,l0,l1,l2,l3;
            cvt2(v.x,h0,l0); cvt2(v.y,h1,l1); cvt2(v.z,h2,l2); cvt2(v.w,h3,l3);
            ushort4 hv = {h0,h1,h2,h3}, lv = {l0,l1,l2,l3};
            *(ushort4*)(Kh + i) = hv;
            *(ushort4*)(Kl + i) = lv;
            *(float4*)(cholK + i) = v;
        }
        return;
    }
    __shared__ float red[256];
    __shared__ float T[32][33];
    red[tid] = Lloc[tid * M_ + tid];
    __syncthreads();
    for (int s = 128; s > 0; s >>= 1) {
        if (tid < s) red[tid] += red[tid + s];
        __syncthreads();
    }
    float sc = expf(Lscale[0]) / (red[0] / (float)M_);
    if (b < 1088) {
        long i = ((long)(b - 1024) * 256 + tid) * 4;
        float4 v = *(const float4*)(Lloc + i);
        u16 h0,h1,h2,h3,l0,l1,l2,l3;
        cvt2(v.x*sc,h0,l0); cvt2(v.y*sc,h1,l1); cvt2(v.z*sc,h2,l2); cvt2(v.w*sc,h3,l3);
        ushort4 hv = {h0,h1,h2,h3}, lv = {l0,l1,l2,l3};
        *(ushort4*)(Lh + i) = hv;
        *(ushort4*)(Ll + i) = lv;
        return;
    }
    int t = b - 1088;               // 0..63
    int c0 = (t & 7) * 32, r0 = (t >> 3) * 32;
    int lrow = tid >> 3, lc4 = (tid & 7) * 4;
    float4 v = *(const float4*)(Lloc + (long)(r0 + lrow) * M_ + c0 + lc4);
    T[lrow][lc4 + 0] = v.x * sc; T[lrow][lc4 + 1] = v.y * sc;
    T[lrow][lc4 + 2] = v.z * sc; T[lrow][lc4 + 3] = v.w * sc;
    __syncthreads();
    int wcol = tid >> 3, wr4 = (tid & 7) * 4;
    u16 h0,h1,h2,h3,l0,l1,l2,l3;
    cvt2(T[wr4+0][wcol],h0,l0); cvt2(T[wr4+1][wcol],h1,l1);
    cvt2(T[wr4+2][wcol],h2,l2); cvt2(T[wr4+3][wcol],h3,l3);
    ushort4 hv = {h0,h1,h2,h3}, lv = {l0,l1,l2,l3};
    *(ushort4*)(Lth + (long)(c0 + wcol) * M_ + r0 + wr4) = hv;
    *(ushort4*)(Ltl + (long)(c0 + wcol) * M_ + r0 + wr4) = lv;
}

// ---- transpose split (tail chunks beyond chunk 0) ----
__global__ void tsplit_kernel(const float* __restrict__ src, int ldS, long sS,
                              u16* __restrict__ h, u16* __restrict__ l, int ldD, long sD,
                              const float* scaleptr) {
    int b = blockIdx.z;
    src += (long)b * sS; h += (long)b * sD; l += (long)b * sD;
    __shared__ float T[32][33];
    int r0 = blockIdx.y * 32, c0 = blockIdx.x * 32;
    float sc = scaleptr ? scaleptr[0] : 1.0f;
    int tid = threadIdx.x;
    int lrow = tid >> 3, lc4 = (tid & 7) * 4;
    float4 v = *(const float4*)(src + (long)(r0 + lrow) * ldS + c0 + lc4);
    T[lrow][lc4 + 0] = v.x * sc; T[lrow][lc4 + 1] = v.y * sc;
    T[lrow][lc4 + 2] = v.z * sc; T[lrow][lc4 + 3] = v.w * sc;
    __syncthreads();
    int wcol = tid >> 3, wr4 = (tid & 7) * 4;
    u16 h0,h1,h2,h3,l0,l1,l2,l3;
    cvt2(T[wr4+0][wcol],h0,l0); cvt2(T[wr4+1][wcol],h1,l1);
    cvt2(T[wr4+2][wcol],h2,l2); cvt2(T[wr4+3][wcol],h3,l3);
    ushort4 hv = {h0,h1,h2,h3}, lv = {l0,l1,l2,l3};
    *(ushort4*)(h + (long)(c0 + wcol) * ldD + r0 + wr4) = hv;
    *(ushort4*)(l + (long)(c0 + wcol) * ldD + r0 + wr4) = lv;
}

__device__ __forceinline__ void psplit_dev(const float* __restrict__ src, u16* __restrict__ h,
                                           u16* __restrict__ l, long n, long b0, long stp) {
    for (long i = b0 * 4; i < n; i += stp * 4) {
        float4 v = *(const float4*)(src + i);
        u16 h0,h1,h2,h3,l0,l1,l2,l3;
        cvt2(v.x,h0,l0); cvt2(v.y,h1,l1); cvt2(v.z,h2,l2); cvt2(v.w,h3,l3);
        ushort4 hv = {h0,h1,h2,h3}, lv = {l0,l1,l2,l3};
        *(ushort4*)(h + i) = hv;
        *(ushort4*)(l + i) = lv;
    }
}

// ---------------- MEGA: chol (blocks 0..31) + independent prep (blocks 32+) ----------------

struct MAux {
    const float* Kuf; u16 *KTh, *KTl; int w0;
    const float* ninv; u16 *nih, *nil;
    const float* nLp;  u16 *nLh2, *nLl2;
    const float* up;   u16 *uph2, *upl2;
    float* z1; long z1n;
    float* z2; long z2n;
};

__global__ __launch_bounds__(1024) void megachol_kernel(float* bufA, float* bufB, MAux ax) {
    __shared__ float P[33280];
    __shared__ float pan2[256 * 20];
    __shared__ float piv[16][18];

    if (blockIdx.x < 32) {
        int blk = blockIdx.x;
        float* Ag = (blk < S_) ? (bufA + (long)blk * MM_) : (bufB + (long)(blk - S_) * MM_);
        float4* P4 = (float4*)P;
        int tid = threadIdx.x;
        int r = tid >> 2, s = tid & 3;
        int lane = tid & 63, wid = tid >> 6;
        int mg = r >> 2, tg = r & 3;
        int b4 = (mg + 1) * (2 * mg + tg);

        for (int i = wid; i < M_; i += 16) {
            int m = i >> 2, t4 = i & 3;
            int rb4 = (m + 1) * (2 * m + t4);
            if (lane <= m) P4[rb4 + lane] = ((const float4*)Ag)[i * 64 + lane];
        }
        __syncthreads();

        float preg[16];
        for (int p = 0; p < 16; p++) {
            int k0 = p << 4;
            int c0 = p << 2;
            #pragma unroll
            for (int rr = 0; rr < 4; rr++) {
                float4 v = make_float4(0.f, 0.f, 0.f, 0.f);
                if (r >= k0 && c0 + rr <= mg) v = P4[b4 + c0 + rr];
                preg[4 * rr + 0] = v.x; preg[4 * rr + 1] = v.y;
                preg[4 * rr + 2] = v.z; preg[4 * rr + 3] = v.w;
            }
            if (wid == p) {
                int dj = lane >> 2;
                float myinv = 0.f;
                #pragma unroll
                for (int j = 0; j < 16; j++) {
                    float app = __shfl(preg[j], 4 * j, 64);
                    float d = sqrtf(app);
                    float inv = 1.0f / d;
                    if (dj == j) { preg[j] = d; myinv = inv; }
                    else if (dj > j) preg[j] *= inv;
                    #pragma unroll
                    for (int j2 = j + 1; j2 < 16; j2++) {
                        float Lj2 = __shfl(preg[j], 4 * j2, 64);
                        if (dj >= j2) preg[j2] -= preg[j] * Lj2;
                    }
                }
                if (s == 0) {
                    #pragma unroll
                    for (int i = 0; i < 16; i++) piv[dj][i] = preg[i];
                    piv[dj][16] = myinv;
                }
            }
            __syncthreads();
            if (r > k0 + 15) {
                float x[16];
                #pragma unroll
                for (int j = 0; j < 16; j++) {
                    float acc = preg[j];
                    #pragma unroll
                    for (int i = 0; i < 16; i++)
                        if (i < j) acc -= x[i] * piv[j][i];
                    x[j] = acc * piv[j][16];
                }
                #pragma unroll
                for (int j = 0; j < 16; j++) preg[j] = x[j];
            }
            if (r >= k0) {
                float4 pv = make_float4(preg[4 * s], preg[4 * s + 1],
                                        preg[4 * s + 2], preg[4 * s + 3]);
                *(float4*)&pan2[r * 20 + 4 * s] = pv;
                int c = c0 + s;
                if (c <= mg) P4[b4 + c] = pv;
            }
            __syncthreads();
            {
                int cs = tid >> 4;
                int j  = tid & 15;
                if (cs >= c0 + 4) {
                    float4 q0[4], q1[4], q2[4], q3[4];
                    #pragma unroll
                    for (int e = 0; e < 4; e++) {
                        const float4* pr = (const float4*)&pan2[(4 * cs + e) * 20];
                        q0[e] = pr[0]; q1[e] = pr[1]; q2[e] = pr[2]; q3[e] = pr[3];
                    }
                    int rr = k0 + 16 + j;
                    int rmin = 4 * cs;
                    while (rr < rmin) rr += 16;
                    for (; rr < 256; rr += 16) {
                        int mgr = rr >> 2, tgr = rr & 3;
                        int rb4 = (mgr + 1) * (2 * mgr + tgr);
                        const float4* ar = (const float4*)&pan2[rr * 20];
                        float4 a0 = ar[0], a1 = ar[1], a2 = ar[2], a3 = ar[3];
                        float rv[4];
                        *(float4*)rv = P4[rb4 + cs];
                        #pragma unroll
                        for (int e = 0; e < 4; e++) {
                            float acc;
                            acc  = a0.x*q0[e].x + a0.y*q0[e].y + a0.z*q0[e].z + a0.w*q0[e].w;
                            acc += a1.x*q1[e].x + a1.y*q1[e].y + a1.z*q1[e].z + a1.w*q1[e].w;
                            acc += a2.x*q2[e].x + a2.y*q2[e].y + a2.z*q2[e].z + a2.w*q2[e].w;
                            acc += a3.x*q3[e].x + a3.y*q3[e].y + a3.z*q3[e].z + a3.w*q3[e].w;
                            rv[e] -= acc;
                        }
                        P4[rb4 + cs] = *(float4*)rv;
                    }
                }
            }
            __syncthreads();
        }

        for (int i = wid; i < M_; i += 16) {
            int m = i >> 2, t4 = i & 3;
            int rb4 = (m + 1) * (2 * m + t4);
            if (lane <= m) ((float4*)Ag)[i * 64 + lane] = P4[rb4 + lane];
        }
        return;
    }

    int ab = blockIdx.x - 32, NA = gridDim.x - 32;
    int tid = threadIdx.x;
    long b0 = (long)ab * 1024 + tid, stp = (long)NA * 1024;
    float4 z = make_float4(0.f, 0.f, 0.f, 0.f);
    long n4 = ax.z1n >> 2;
    for (long i = b0; i < n4; i += stp) ((float4*)ax.z1)[i] = z;
    long m4 = ax.z2n >> 2;
    for (long i = b0; i < m4; i += stp) ((float4*)ax.z2)[i] = z;
    psplit_dev(ax.ninv, ax.nih, ax.nil, (long)S_ * MM_, b0, stp);
    psplit_dev(ax.nLp, ax.nLh2, ax.nLl2, (long)S_ * MM_, b0, stp);
    psplit_dev(ax.up, ax.uph2, ax.upl2, 65536, b0, stp);

    int grp = tid >> 8, t = tid & 255;
    float* Tls = P + grp * 1056;
    int nx = ax.w0 >> 5;
    int ntile = nx * 8 * S_;
    int per = NA * 4;
    int iters = (ntile + per - 1) / per;
    long sS = (long)M_ * NF_, sD = (long)ax.w0 * 256;
    for (int it = 0; it < iters; it++) {
        int tile = ab * 4 + grp + it * per;
        bool ok = tile < ntile;
        int r0 = 0, c0 = 0, b = 0;
        if (ok) {
            int cx = tile % nx; int rest = tile / nx;
            int cy = rest & 7; b = rest >> 3;
            r0 = cy * 32; c0 = cx * 32;
        }
        if (ok) {
            int lrow = t >> 3, lc4 = (t & 7) * 4;
            float4 v = *(const float4*)(ax.Kuf + (long)b * sS + (long)(r0 + lrow) * NF_ + c0 + lc4);
            Tls[lrow * 33 + lc4 + 0] = v.x; Tls[lrow * 33 + lc4 + 1] = v.y;
            Tls[lrow * 33 + lc4 + 2] = v.z; Tls[lrow * 33 + lc4 + 3] = v.w;
        }
        __syncthreads();
        if (ok) {
            int wcol = t >> 3, wr4 = (t & 7) * 4;
            u16 h0,h1,h2,h3,l0,l1,l2,l3;
            cvt2(Tls[(wr4+0)*33+wcol],h0,l0); cvt2(Tls[(wr4+1)*33+wcol],h1,l1);
            cvt2(Tls[(wr4+2)*33+wcol],h2,l2); cvt2(Tls[(wr4+3)*33+wcol],h3,l3);
            ushort4 hv = {h0,h1,h2,h3}, lv = {l0,l1,l2,l3};
            long o = (long)b * sD + (long)(c0 + wcol) * 256 + r0 + wr4;
            *(ushort4*)(ax.KTh + o) = hv;
            *(ushort4*)(ax.KTl + o) = lv;
        }
        __syncthreads();
    }
}

// ---------------- merged: 64x64 diag triangular inverse (bx<4) + lsplit (bx>=4) ----------------

__global__ __launch_bounds__(256) void trilsp_kernel(const float* W0,
                                                     u16* invh, u16* invl,
                                                     u16* Tth, u16* Ttl,
                                                     u16* TKrh, u16* TKrl,
                                                     u16* Lh, u16* Ll) {
    __shared__ float X[64 * 65];
    __shared__ float pan[64 * 20];
    int mat = blockIdx.y;      // 0..31
    int tid = threadIdx.x;
    const float* W = W0 + (long)mat * MM_;

    if (blockIdx.x >= 4) {
        int p = blockIdx.x - 4;        // 0..2
        u16* dh = Lh + (long)mat * MM_;
        u16* dl = Ll + (long)mat * MM_;
        int d0 = 64 * p, nrows = 192 - d0;
        for (int idx = tid; idx < nrows * 16; idx += 256) {
            int r = idx >> 4, c4 = idx & 15;
            long o = (long)(d0 + 64 + r) * 256 + d0 + 4 * c4;
            float4 v = *(const float4*)(W + o);
            u16 h0,h1,h2,h3,l0,l1,l2,l3;
            cvt2(v.x,h0,l0); cvt2(v.y,h1,l1); cvt2(v.z,h2,l2); cvt2(v.w,h3,l3);
            ushort4 hv = {h0,h1,h2,h3}, lv = {l0,l1,l2,l3};
            *(ushort4*)(dh + o) = hv;
            *(ushort4*)(dl + o) = lv;
        }
        return;
    }

    int p = blockIdx.x;        // 0..3
    int d0 = p * 64;
    int c = tid & 63, q = tid >> 6;
    for (int idx = tid; idx < 64 * 65; idx += 256) X[idx] = 0.f;
    __syncthreads();
    if (q == 0) X[c * 65 + c] = 1.0f;
    for (int pp = 0; pp < 4; pp++) {
        int t0 = pp << 4;
        for (int idx = tid; idx < 64 * 4; idx += 256) {
            int k = idx >> 2, e = idx & 3;
            if (k >= t0)
                ((float4*)(pan + k * 20))[e] =
                    *(const float4*)(W + (long)(d0 + k) * 256 + d0 + t0 + 4 * e);
        }
        __syncthreads();
        if (q == pp) {
            float xr[16];
            #pragma unroll
            for (int j = 0; j < 16; j++) {
                float xv = X[(t0 + j) * 65 + c];
                #pragma unroll
                for (int i = 0; i < 16; i++)
                    if (i < j) xv -= pan[(t0 + j) * 20 + i] * xr[i];
                xv *= (1.0f / pan[(t0 + j) * 20 + j]);
                xr[j] = xv;
                X[(t0 + j) * 65 + c] = xv;
            }
        }
        __syncthreads();
        int kbeg = q << 4; if (kbeg < t0 + 16) kbeg = t0 + 16;
        int kend = (q << 4) + 16;
        if (kbeg < kend) {
            float xr[16];
            #pragma unroll
            for (int j = 0; j < 16; j++) xr[j] = X[(t0 + j) * 65 + c];
            for (int kk = kbeg; kk < kend; kk++) {
                float rv = X[kk * 65 + c];
                const float4* pr = (const float4*)&pan[kk * 20];
                float4 a = pr[0], b = pr[1], d = pr[2], e = pr[3];
                rv -= a.x * xr[0] + a.y * xr[1] + a.z * xr[2] + a.w * xr[3];
                rv -= b.x * xr[4] + b.y * xr[5] + b.z * xr[6] + b.w * xr[7];
                rv -= d.x * xr[8] + d.y * xr[9] + d.z * xr[10] + d.w * xr[11];
                rv -= e.x * xr[12] + e.y * xr[13] + e.z * xr[14] + e.w * xr[15];
                X[kk * 65 + c] = rv;
            }
        }
        __syncthreads();
    }
    for (int idx = tid; idx < 4096; idx += 256) {
        int r = idx >> 6, k = idx & 63;
        u16 h, l; cvt2(X[r * 65 + k], h, l);
        long io = (long)mat * 16384 + (long)p * 4096 + idx;
        invh[io] = h; invl[io] = l;
        long ro = (long)mat * MM_ + (long)(d0 + r) * 256 + d0 + k;
        TKrh[ro] = h; TKrl[ro] = l;
        long to = (long)mat * MM_ + (long)(d0 + k) * 256 + d0 + r;
        Tth[to] = h; Ttl[to] = l;
    }
}

// ---------------- pair GEMM structures ----------------

struct PG {
    const u16 *Ah, *Al, *Bh, *Bl;
    float* C; u16 *Ch, *Cl, *ChT, *ClT;
    float* CF;
    const float* D; const float* noise;
    const float* kff; float* vfacc;
    int M, N, K, lda, ldb, ldc, ldct, ldp;
    long sA, sB, sC, sP, sCt, sD, sVf, sNoise, sCF;
    float alpha, dcoef;
};

// 128x128 tile, 4 waves (K = 256; TRIf: K capped at bn+128 for lower-tri B)
template<int OF, int OP, int OPT, int ACCf, int Df, int ADDIf, int EFf, int VFf, int TRIf>
__global__ __launch_bounds__(256) void pgemm_k(PG p) {
    int bz = blockIdx.z;
    const u16* Agh = p.Ah + (long)bz * p.sA;
    const u16* Agl = p.Al + (long)bz * p.sA;
    const u16* Bgh = p.Bh + (long)bz * p.sB;
    const u16* Bgl = p.Bl + (long)bz * p.sB;
    int bm = blockIdx.y * 128, bn = blockIdx.x * 128;
    __shared__ __align__(16) u16 sAh[128][40];
    __shared__ __align__(16) u16 sAl[128][40];
    __shared__ __align__(16) u16 sBh[128][40];
    __shared__ __align__(16) u16 sBl[128][40];
    int tid = threadIdx.x, lane = tid & 63, wid = tid >> 6;
    int wm = (wid >> 1) * 64, wn = (wid & 1) * 64;
    int fr = lane & 15, ko = (lane >> 4) * 8;
    int kb = tid & 3, rw = tid >> 2;
    f32x4 acc[4][4];
    #pragma unroll
    for (int m = 0; m < 4; m++)
        #pragma unroll
        for (int n = 0; n < 4; n++)
            acc[m][n] = (f32x4){0.f, 0.f, 0.f, 0.f};

    int klim = TRIf ? (bn + 128) : 256;
    for (int k0 = 0; k0 < klim; k0 += 32) {
        #define STG(SRC, LD, BASE, DST) \
            *(bf16x8*)&DST[rw][kb * 8] = \
                *(const bf16x8*)(SRC + (long)(BASE + rw) * LD + k0 + kb * 8); \
            *(bf16x8*)&DST[rw + 64][kb * 8] = \
                *(const bf16x8*)(SRC + (long)(BASE + rw + 64) * LD + k0 + kb * 8);
        STG(Agh, p.lda, bm, sAh)
        STG(Agl, p.lda, bm, sAl)
        STG(Bgh, p.ldb, bn, sBh)
        STG(Bgl, p.ldb, bn, sBl)
        #undef STG
        __syncthreads();
        bf16x8 ah[4], al[4], bh[4], bl[4];
        #pragma unroll
        for (int m = 0; m < 4; m++) {
            ah[m] = *(const bf16x8*)&sAh[wm + m * 16 + fr][ko];
            al[m] = *(const bf16x8*)&sAl[wm + m * 16 + fr][ko];
        }
        #pragma unroll
        for (int n = 0; n < 4; n++) {
            bh[n] = *(const bf16x8*)&sBh[wn + n * 16 + fr][ko];
            bl[n] = *(const bf16x8*)&sBl[wn + n * 16 + fr][ko];
        }
        #pragma unroll
        for (int m = 0; m < 4; m++)
            #pragma unroll
            for (int n = 0; n < 4; n++) {
                acc[m][n] = __builtin_amdgcn_mfma_f32_16x16x32_bf16(ah[m], bh[n], acc[m][n], 0, 0, 0);
                acc[m][n] = __builtin_amdgcn_mfma_f32_16x16x32_bf16(ah[m], bl[n], acc[m][n], 0, 0, 0);
                acc[m][n] = __builtin_amdgcn_mfma_f32_16x16x32_bf16(al[m], bh[n], acc[m][n], 0, 0, 0);
            }
        __syncthreads();
    }

    int rq = (lane >> 4) * 4;
    float rs[4][4];
    if (VFf) {
        #pragma unroll
        for (int m = 0; m < 4; m++)
            #pragma unroll
            for (int i = 0; i < 4; i++) rs[m][i] = 0.f;
    }
    #pragma unroll
    for (int m = 0; m < 4; m++) {
        int row0 = bm + wm + m * 16 + rq;
        #pragma unroll
        for (int n = 0; n < 4; n++) {
            int col = bn + wn + n * 16 + fr;
            float v[4];
            #pragma unroll
            for (int i = 0; i < 4; i++) {
                int r = row0 + i;
                float val = p.alpha * acc[m][n][i];
                if (Df)   val += p.dcoef * p.D[(long)bz * p.sD + (long)r * p.ldc + col];
                if (ACCf) val += p.C[(long)bz * p.sC + (long)r * p.ldc + col];
                if (ADDIf && r == col) val += 1.0f;
                if (EFf) {
                    float kf = p.kff[(long)bz * p.sVf + r];
                    float vq = p.vfacc[(long)bz * p.sVf + r];
                    val += sqrtf(fmaxf(kf - vq, 0.f)) *
                           p.noise[(long)bz * p.sNoise + (long)r * 256 + col];
                }
                v[i] = val;
                if (VFf) rs[m][i] += val * val;
            }
            if (OF) {
                #pragma unroll
                for (int i = 0; i < 4; i++)
                    p.C[(long)bz * p.sC + (long)(row0 + i) * p.ldc + col] = v[i];
            }
            if (OP) {
                #pragma unroll
                for (int i = 0; i < 4; i++) {
                    u16 h, l; cvt2(v[i], h, l);
                    p.Ch[(long)bz * p.sP + (long)(row0 + i) * p.ldc + col] = h;
                    p.Cl[(long)bz * p.sP + (long)(row0 + i) * p.ldc + col] = l;
                }
            }
            if (OPT) {
                u16 h0,h1,h2,h3,l0,l1,l2,l3;
                cvt2(v[0],h0,l0); cvt2(v[1],h1,l1); cvt2(v[2],h2,l2); cvt2(v[3],h3,l3);
                ushort4 hv = {h0,h1,h2,h3}, lv = {l0,l1,l2,l3};
                *(ushort4*)&p.ChT[(long)bz * p.sCt + (long)col * p.ldct + row0] = hv;
                *(ushort4*)&p.ClT[(long)bz * p.sCt + (long)col * p.ldct + row0] = lv;
            }
        }
    }
    if (VFf) {
        #pragma unroll
        for (int m = 0; m < 4; m++) {
            int row0 = bm + wm + m * 16 + rq;
            #pragma unroll
            for (int i = 0; i < 4; i++) {
                float t = rs[m][i];
                t += __shfl_xor(t, 1); t += __shfl_xor(t, 2);
                t += __shfl_xor(t, 4); t += __shfl_xor(t, 8);
                if (fr == 0)
                    atomicAdd(&p.vfacc[(long)bz * p.sVf + row0 + i], t);
            }
        }
    }
}

// ---- 64x64 tile body (shared by single and dual kernels) ----
template<int OF, int OP, int OPT, int OFT, int ACCf, int Df, int ADDIf>
__device__ __forceinline__ void pg64_body(const PG& p, int bz,
                                          u16 (*sAh)[40], u16 (*sAl)[40],
                                          u16 (*sBh)[40], u16 (*sBl)[40]) {
    const u16* Agh = p.Ah + (long)bz * p.sA;
    const u16* Agl = p.Al + (long)bz * p.sA;
    const u16* Bgh = p.Bh + (long)bz * p.sB;
    const u16* Bgl = p.Bl + (long)bz * p.sB;
    int bm = blockIdx.y * 64, bn = blockIdx.x * 64;
    int tid = threadIdx.x, lane = tid & 63, wid = tid >> 6;
    int wm = (wid >> 1) * 32, wn = (wid & 1) * 32;
    int fr = lane & 15, ko = (lane >> 4) * 8;
    int kb = tid & 3, rw = tid >> 2;
    f32x4 acc[2][2];
    #pragma unroll
    for (int m = 0; m < 2; m++)
        #pragma unroll
        for (int n = 0; n < 2; n++)
            acc[m][n] = (f32x4){0.f, 0.f, 0.f, 0.f};

    for (int k0 = 0; k0 < p.K; k0 += 32) {
        *(bf16x8*)&sAh[rw][kb * 8] = *(const bf16x8*)(Agh + (long)(bm + rw) * p.lda + k0 + kb * 8);
        *(bf16x8*)&sAl[rw][kb * 8] = *(const bf16x8*)(Agl + (long)(bm + rw) * p.lda + k0 + kb * 8);
        *(bf16x8*)&sBh[rw][kb * 8] = *(const bf16x8*)(Bgh + (long)(bn + rw) * p.ldb + k0 + kb * 8);
        *(bf16x8*)&sBl[rw][kb * 8] = *(const bf16x8*)(Bgl + (long)(bn + rw) * p.ldb + k0 + kb * 8);
        __syncthreads();
        bf16x8 ah[2], al[2], bh[2], bl[2];
        #pragma unroll
        for (int m = 0; m < 2; m++) {
            ah[m] = *(const bf16x8*)&sAh[wm + m * 16 + fr][ko];
            al[m] = *(const bf16x8*)&sAl[wm + m * 16 + fr][ko];
        }
        #pragma unroll
        for (int n = 0; n < 2; n++) {
            bh[n] = *(const bf16x8*)&sBh[wn + n * 16 + fr][ko];
            bl[n] = *(const bf16x8*)&sBl[wn + n * 16 + fr][ko];
        }
        #pragma unroll
        for (int m = 0; m < 2; m++)
            #pragma unroll
            for (int n = 0; n < 2; n++) {
                acc[m][n] = __builtin_amdgcn_mfma_f32_16x16x32_bf16(ah[m], bh[n], acc[m][n], 0, 0, 0);
                acc[m][n] = __builtin_amdgcn_mfma_f32_16x16x32_bf16(ah[m], bl[n], acc[m][n], 0, 0, 0);
                acc[m][n] = __builtin_amdgcn_mfma_f32_16x16x32_bf16(al[m], bh[n], acc[m][n], 0, 0, 0);
            }
        __syncthreads();
    }

    int rq = (lane >> 4) * 4;
    #pragma unroll
    for (int m = 0; m < 2; m++) {
        int row0 = bm + wm + m * 16 + rq;
        #pragma unroll
        for (int n = 0; n < 2; n++) {
            int col = bn + wn + n * 16 + fr;
            float v[4];
            #pragma unroll
            for (int i = 0; i < 4; i++) {
                int r = row0 + i;
                float val = p.alpha * acc[m][n][i];
                if (Df)   val += p.dcoef * p.D[(long)bz * p.sD + (long)r * p.ldc + col];
                if (ACCf) val += p.C[(long)bz * p.sC + (long)r * p.ldc + col];
                if (ADDIf && r == col) val += 1.0f;
                v[i] = val;
            }
            if (OF) {
                #pragma unroll
                for (int i = 0; i < 4; i++)
                    p.C[(long)bz * p.sC + (long)(row0 + i) * p.ldc + col] = v[i];
            }
            if (OP) {
                #pragma unroll
                for (int i = 0; i < 4; i++) {
                    u16 h, l; cvt2(v[i], h, l);
                    p.Ch[(long)bz * p.sP + (long)(row0 + i) * p.ldp + col] = h;
                    p.Cl[(long)bz * p.sP + (long)(row0 + i) * p.ldp + col] = l;
                }
            }
            if (OPT) {
                u16 h0,h1,h2,h3,l0,l1,l2,l3;
                cvt2(v[0],h0,l0); cvt2(v[1],h1,l1); cvt2(v[2],h2,l2); cvt2(v[3],h3,l3);
                ushort4 hv = {h0,h1,h2,h3}, lv = {l0,l1,l2,l3};
                *(ushort4*)&p.ChT[(long)bz * p.sCt + (long)col * p.ldct + row0] = hv;
                *(ushort4*)&p.ClT[(long)bz * p.sCt + (long)col * p.ldct + row0] = lv;
            }
            if (OFT) {
                float4 o4 = make_float4(v[0], v[1], v[2], v[3]);
                *(float4*)&p.CF[(long)bz * p.sCF + (long)col * 256 + row0] = o4;
            }
        }
    }
}

template<int OF, int OP, int OPT, int OFT, int ACCf, int Df, int ADDIf>
__global__ __launch_bounds__(256) void pgemm64_k(PG p) {
    __shared__ __align__(16) u16 sAh[64][40];
    __shared__ __align__(16) u16 sAl[64][40];
    __shared__ __align__(16) u16 sBh[64][40];
    __shared__ __align__(16) u16 sBl[64][40];
    pg64_body<OF,OP,OPT,OFT,ACCf,Df,ADDIf>(p, blockIdx.z, sAh, sAl, sBh, sBl);
}

// dual-descriptor: blocks z < zs run A's GEMM (flags1), others run B's (flags2)
template<int OF1,int OP1,int OPT1,int OFT1,int ACC1,int D1,int ADDI1,
         int OF2,int OP2,int OPT2,int OFT2,int ACC2,int D2,int ADDI2>
__global__ __launch_bounds__(256) void pgemm64d_k(PG a, PG b, int zs) {
    __shared__ __align__(16) u16 sAh[64][40];
    __shared__ __align__(16) u16 sAl[64][40];
    __shared__ __align__(16) u16 sBh[64][40];
    __shared__ __align__(16) u16 sBl[64][40];
    int z = blockIdx.z;
    if (z < zs) pg64_body<OF1,OP1,OPT1,OFT1,ACC1,D1,ADDI1>(a, z, sAh, sAl, sBh, sBl);
    else        pg64_body<OF2,OP2,OPT2,OFT2,ACC2,D2,ADDI2>(b, z - zs, sAh, sAl, sBh, sBl);
}

// ---------------- host ----------------

extern "C" void kernel_launch(void* const* d_in, const int* in_sizes, int n_in,
                              void* d_out, int out_size, void* d_ws, size_t ws_size,
                              hipStream_t stream) {
    const float* Kuu       = (const float*)d_in[0];
    const float* Kuf       = (const float*)d_in[1];
    const float* Kff       = (const float*)d_in[2];
    const float* Lloc      = (const float*)d_in[3];
    const float* Lscale    = (const float*)d_in[4];
    const float* u_param   = (const float*)d_in[5];
    const float* noise_inv = (const float*)d_in[6];
    const float* noise_L   = (const float*)d_in[7];
    const float* noise_f   = (const float*)d_in[8];
    float* out = (float*)d_out;
    float* ws  = (float*)d_ws;

    const long BIG = (long)S_ * MM_;     // 1,048,576 elements
    long off = 1024;

    #define PAIR(NAME, E) u16* NAME##h = (u16*)(ws + off); u16* NAME##l = NAME##h + (E); off += (E);
    PAIR(LS, 65536)
    PAIR(LtS, 65536)
    PAIR(upS, 65536)
    PAIR(W1S, 65536)
    float* UPT   = ws + off; off += 65536;
    float* VfAcc = ws + off; off += 65536;
    PAIR(KuuS, BIG)
    PAIR(ninvS, BIG)
    PAIR(nLS, BIG)
    float* cholK = ws + off; off += 2 * BIG;   // 32 matrices contiguous
    float* choll = cholK + BIG;
    PAIR(KuuLS, BIG)
    PAIR(KuuLtS, BIG)
    PAIR(TtS, 2 * BIG)             // T^T pair, 32 matrices  (zeroed in mega)
    PAIR(TKrS, 2 * BIG)            // T row-major pair, 32 matrices (zeroed in mega)
    PAIR(G3TS, BIG)                // (KuuInv @ U)^T pair
    PAIR(KIL, 2 * BIG)             // KuuInv (mats 0..15) | lKl (mats 16..31)
    PAIR(invS, 524288)             // 32 mats x 4 panels x 64x64 D pair
    PAIR(LfS, 2 * BIG)             // L strictly-lower pair, 32 matrices
    PAIR(StTS, 393216)             // S^T scratch pair, 32 x 192x64
    #undef PAIR

    u16* TKth = TtSh;                u16* TKtl = TtSl;
    u16* Tlth = TtSh + (long)S_ * MM_; u16* Tltl = TtSl + (long)S_ * MM_;
    u16* RHSTh   = KuuSh;            u16* RHSTl   = KuuSl;
    u16* UTph    = nLSh;             u16* UTpl    = nLSl;
    float* RHS1T = (float*)KuuLSh;
    u16* Sigmah  = KuuLtSh;          u16* Sigmal  = KuuLtSl;
    u16* KuuInvh = KILh;             u16* KuuInvl = KILl;
    u16* lKlh    = KILh + (long)S_ * MM_; u16* lKll = KILl + (long)S_ * MM_;

    long navail = (long)(ws_size / 4) - off;
    long nfc_l = navail / 4096;                 // only KufT pair per chunk
    int nfc = (int)((nfc_l / 128) * 128);
    if (nfc > NF_) nfc = NF_;
    if (nfc < 128) nfc = 128;
    long Ec = (long)S_ * nfc * 256;
    u16* KufTch = (u16*)(ws + off);      u16* KufTcl = KufTch + Ec;

    dim3 b256(256);

    prepall_kernel<<<1152, b256, 0, stream>>>(Kuu, KuuSh, KuuSl, cholK,
                                              Lloc, Lscale,
                                              LSh, LSl, LtSh, LtSl);

    PG q;
    auto clr = [&]() {
        q = PG{};
        q.lda = 256; q.ldb = 256; q.ldc = 256; q.ldct = 256; q.ldp = 256;
        q.alpha = 1.f; q.dcoef = 1.f;
        q.M = 256; q.N = 256; q.K = 256;
    };
    dim3 g64(4, 4, S_);
    dim3 g64b1(4, 4, 1);

    // a. KuuL = Kuu @ L -> pair + pairT
    clr(); q.Ah = KuuSh; q.Al = KuuSl; q.sA = MM_;
    q.Bh = LtSh; q.Bl = LtSl; q.sB = 0;
    q.Ch = KuuLSh; q.Cl = KuuLSl; q.sP = MM_;
    q.ChT = KuuLtSh; q.ClT = KuuLtSl; q.sCt = MM_;
    pgemm64_k<0,1,1,0,0,0,0><<<g64, b256, 0, stream>>>(q);

    // b. choll = KuuL^T @ L + I -> fp32
    clr(); q.Ah = KuuLtSh; q.Al = KuuLtSl; q.sA = MM_;
    q.Bh = LtSh; q.Bl = LtSl; q.sB = 0;
    q.C = choll; q.sC = MM_;
    pgemm64_k<1,0,0,0,0,0,1><<<g64, b256, 0, stream>>>(q);

    // MEGA: chol (32 blocks) + aux prep (224 blocks)
    int w0 = nfc;
    MAux ax;
    ax.Kuf = Kuf; ax.KTh = KufTch; ax.KTl = KufTcl; ax.w0 = w0;
    ax.ninv = noise_inv; ax.nih = ninvSh; ax.nil = ninvSl;
    ax.nLp = noise_L; ax.nLh2 = nLSh; ax.nLl2 = nLSl;
    ax.up = u_param; ax.uph2 = upSh; ax.upl2 = upSl;
    ax.z1 = (float*)TtSh; ax.z1n = 4 * BIG;
    ax.z2 = VfAcc; ax.z2n = 65536;
    megachol_kernel<<<256, dim3(1024), 0, stream>>>(cholK, choll, ax);

    // ---- block-recursive triangular inverse via MFMA (+ lsplit merged) ----
    trilsp_kernel<<<dim3(7, 32), b256, 0, stream>>>(cholK, invSh, invSl,
                                                    TtSh, TtSl, TKrSh, TKrSl,
                                                    LfSh, LfSl);

    for (int i = 1; i < 4; i++) {
        clr(); q.M = 64; q.N = 64 * i; q.K = 64 * i;
        q.Ah = LfSh + (long)64 * i * 256; q.Al = LfSl + (long)64 * i * 256;
        q.lda = 256; q.sA = MM_;
        q.Bh = TtSh; q.Bl = TtSl; q.ldb = 256; q.sB = MM_;
        q.ChT = StTSh; q.ClT = StTSl; q.ldct = 64; q.sCt = 12288;
        pgemm64_k<0,0,1,0,0,0,0><<<dim3(i, 1, 32), b256, 0, stream>>>(q);
        clr(); q.M = 64; q.N = 64 * i; q.K = 64;
        q.Ah = invSh + (long)i * 4096; q.Al = invSl + (long)i * 4096;
        q.lda = 64; q.sA = 16384;
        q.Bh = StTSh; q.Bl = StTSl; q.ldb = 64; q.sB = 12288;
        q.alpha = -1.f;
        q.Ch = TKrSh + (long)64 * i * 256; q.Cl = TKrSl + (long)64 * i * 256;
        q.ldp = 256; q.sP = MM_;
        q.ChT = TtSh + 64 * i; q.ClT = TtSl + 64 * i; q.ldct = 256; q.sCt = MM_;
        pgemm64_k<0,1,1,0,0,0,0><<<dim3(i, 1, 32), b256, 0, stream>>>(q);
    }

    // L1: {c2d: [KuuInv|lKl] = Tt@Tt^T (z 0..31)} + {g: W1 = up@L (z 32)}
    PG q1, q2;
    clr(); q.Ah = TtSh; q.Al = TtSl; q.sA = MM_;
    q.Bh = TtSh; q.Bl = TtSl; q.sB = MM_;
    q.Ch = KILh; q.Cl = KILl; q.sP = MM_;
    q1 = q;
    clr(); q.Ah = upSh; q.Al = upSl; q.sA = 0;
    q.Bh = LtSh; q.Bl = LtSl; q.sB = 0;
    q.Ch = W1Sh; q.Cl = W1Sl; q.sP = 0;
    q2 = q;
    pgemm64d_k<0,1,0,0,0,0,0, 0,1,0,0,0,0,0><<<dim3(4, 4, 33), b256, 0, stream>>>(q1, q2, 32);

    // L2: {e: Stmp = KuuL@lKl (z 0..15)} + {h: UPT = W1@L^T fp32 (z 16)}
    u16* Stmph = Tlth; u16* Stmpl = Tltl;
    clr(); q.Ah = KuuLSh; q.Al = KuuLSl; q.sA = MM_;
    q.Bh = lKlh; q.Bl = lKll; q.sB = MM_;
    q.Ch = Stmph; q.Cl = Stmpl; q.sP = MM_;
    q1 = q;
    clr(); q.Ah = W1Sh; q.Al = W1Sl; q.sA = 0;
    q.Bh = LSh; q.Bl = LSl; q.sB = 0;
    q.C = UPT; q.sC = 0;
    q2 = q;
    pgemm64d_k<0,1,0,0,0,0,0, 1,0,0,0,0,0,0><<<dim3(4, 4, 17), b256, 0, stream>>>(q1, q2, 16);

    // L3: {f: Sigma = Kuu - Stmp@KuuL^T (z 0..15)} + {i: RHS1T = ninv@TK + UPT (z 16..31)}
    clr(); q.Ah = Stmph; q.Al = Stmpl; q.sA = MM_;
    q.Bh = KuuLSh; q.Bl = KuuLSl; q.sB = MM_;
    q.Ch = Sigmah; q.Cl = Sigmal; q.sP = MM_;
    q.D = Kuu; q.sD = MM_; q.alpha = -1.f;
    q1 = q;
    clr(); q.Ah = ninvSh; q.Al = ninvSl; q.sA = 65536;
    q.Bh = TKth; q.Bl = TKtl; q.sB = MM_;
    q.C = RHS1T; q.sC = MM_;
    q.D = UPT; q.sD = 0;
    q2 = q;
    pgemm64d_k<0,1,0,0,0,1,0, 1,0,0,0,0,1,0><<<dim3(4, 4, 32), b256, 0, stream>>>(q1, q2, 16);

    // j. RHST = nL @ L^T + RHS1T -> pair
    clr(); q.Ah = nLSh; q.Al = nLSl; q.sA = 65536;
    q.Bh = LSh; q.Bl = LSl; q.sB = 0;
    q.C = RHS1T; q.sC = MM_;
    q.Ch = RHSTh; q.Cl = RHSTl; q.sP = MM_;
    pgemm64_k<0,1,0,0,1,0,0><<<g64, b256, 0, stream>>>(q);

    // k. UT = RHST @ Sigma -> pair + transposed fp32 direct into out rows 0..255
    clr(); q.Ah = RHSTh; q.Al = RHSTl; q.sA = MM_;
    q.Bh = Sigmah; q.Bl = Sigmal; q.sB = MM_;
    q.Ch = UTph; q.Cl = UTpl; q.sP = MM_;
    q.CF = out; q.sCF = (long)ROWS_ * OUT_;
    pgemm64_k<0,1,0,1,0,0,0><<<g64, b256, 0, stream>>>(q);

    // G3T = UTp @ KuuInv -> pair
    clr(); q.Ah = UTph; q.Al = UTpl; q.sA = MM_;
    q.Bh = KuuInvh; q.Bl = KuuInvl; q.sB = MM_;
    q.Ch = G3TSh; q.Cl = G3TSl; q.sP = MM_;
    pgemm64_k<0,1,0,0,0,0,0><<<g64, b256, 0, stream>>>(q);

    for (int f0 = 0; f0 < NF_; f0 += nfc) {
        int w = NF_ - f0; if (w > nfc) w = nfc;
        if (f0 > 0)    // chunk 0 transposed inside megachol
            tsplit_kernel<<<dim3(w / 32, 8, S_), b256, 0, stream>>>(
                Kuf + f0, NF_, (long)M_ * NF_, KufTch, KufTcl, 256, (long)w * 256, nullptr);
        // Vf-GEMM: H' = KufT @ TK^T (lower-tri B: K capped), VfAcc row sums of squares
        clr(); q.M = w; q.N = 256;
        q.Ah = KufTch; q.Al = KufTcl; q.sA = (long)w * 256;
        q.Bh = TKrSh; q.Bl = TKrSl; q.sB = MM_;
        q.vfacc = VfAcc + f0; q.sVf = NF_;
        pgemm_k<0,0,0,0,0,0,0,1,1><<<dim3(2, w / 128, S_), b256, 0, stream>>>(q);
        // Ef-GEMM: out_f = KufT @ G3T^T + sqrt(Kff - VfAcc)*noise_f
        clr(); q.M = w; q.N = 256;
        q.Ah = KufTch; q.Al = KufTcl; q.sA = (long)w * 256;
        q.Bh = G3TSh; q.Bl = G3TSl; q.sB = MM_;
        q.C = out + (long)(M_ + f0) * OUT_; q.sC = (long)ROWS_ * OUT_;
        q.kff = Kff + f0; q.vfacc = VfAcc + f0; q.sVf = NF_;
        q.noise = noise_f + (long)f0 * OUT_; q.sNoise = (long)NF_ * OUT_;
        pgemm_k<1,0,0,0,0,0,1,0,0><<<dim3(2, w / 128, S_), b256, 0, stream>>>(q);
    }
}